// Round 3
// baseline (2097.867 us; speedup 1.0000x reference)
//
#include <hip/hip_runtime.h>
#include <math.h>

typedef __attribute__((ext_vector_type(8))) short short8;
typedef __attribute__((ext_vector_type(4))) float f32x4;

__device__ __forceinline__ unsigned short f2bf(float f) {
  unsigned u = __builtin_bit_cast(unsigned, f);
  u += 0x7fff + ((u >> 16) & 1);
  return (unsigned short)(u >> 16);
}
__device__ __forceinline__ float bf2f(unsigned short h) {
  unsigned u = ((unsigned)h) << 16;
  return __builtin_bit_cast(float, u);
}
__device__ __forceinline__ float gelu_f(float x) {
  const float c0 = 0.7978845608028654f;
  return 0.5f * x * (1.0f + tanhf(c0 * (x + 0.044715f * x * x * x)));
}

// ============ bf16 MFMA GEMM: C = A(bf16,[M][lda]) @ BT(bf16,[N][K]) ============
// Epilogue: col < S -> f32 Cf[row*ldf+col]; col >= S -> bf16 Cb[row*ldb+col-S]
template<bool BIAS, bool GELU>
__global__ __launch_bounds__(256)
void gemm_mfma_k(const unsigned short* __restrict__ A, int lda,
                 const unsigned short* __restrict__ BT,
                 const float* __restrict__ bias, float* __restrict__ Cf,
                 unsigned short* __restrict__ Cb,
                 int M, int N, int K, int S, int ldf, int ldb)
{
  __shared__ __align__(16) unsigned short As[128 * 32];
  __shared__ __align__(16) unsigned short Bs[128 * 32];
  const int tid = threadIdx.x;
  const int bm = blockIdx.x * 128, bn = blockIdx.y * 128;
  const int lane = tid & 63, w = tid >> 6;
  const int wr = w >> 1, wc = w & 1;
  const int l15 = lane & 15, kg = lane >> 4;
  const int sr = tid >> 1, kh = tid & 1;
  const unsigned short* ap = A + (size_t)(bm + sr) * lda + kh * 16;
  const unsigned short* bp = BT + (size_t)(bn + sr) * K + kh * 16;
  const int ph0 = ((kh * 2 + 0) + (sr >> 1)) & 3;   // k-slot swizzle (2-way free)
  const int ph1 = ((kh * 2 + 1) + (sr >> 1)) & 3;
  unsigned short* wa0 = As + sr * 32 + ph0 * 8;
  unsigned short* wa1 = As + sr * 32 + ph1 * 8;
  unsigned short* wb0 = Bs + sr * 32 + ph0 * 8;
  unsigned short* wb1 = Bs + sr * 32 + ph1 * 8;

  f32x4 acc[4][4] = {};

  for (int k0 = 0; k0 < K; k0 += 32) {
    uint4 a0 = *(const uint4*)(ap + k0);
    uint4 a1 = *(const uint4*)(ap + k0 + 8);
    uint4 b0 = *(const uint4*)(bp + k0);
    uint4 b1 = *(const uint4*)(bp + k0 + 8);
    *(uint4*)wa0 = a0;
    *(uint4*)wa1 = a1;
    *(uint4*)wb0 = b0;
    *(uint4*)wb1 = b1;
    __syncthreads();
    short8 af[4], bfr[4];
#pragma unroll
    for (int m = 0; m < 4; ++m) {
      int row = wr * 64 + m * 16 + l15;
      int ph = (kg + (row >> 1)) & 3;
      af[m] = *(const short8*)(As + row * 32 + ph * 8);
    }
#pragma unroll
    for (int n = 0; n < 4; ++n) {
      int col = wc * 64 + n * 16 + l15;
      int ph = (kg + (col >> 1)) & 3;
      bfr[n] = *(const short8*)(Bs + col * 32 + ph * 8);
    }
#pragma unroll
    for (int m = 0; m < 4; ++m)
#pragma unroll
      for (int n = 0; n < 4; ++n)
        acc[m][n] = __builtin_amdgcn_mfma_f32_16x16x32_bf16(af[m], bfr[n], acc[m][n], 0, 0, 0);
    __syncthreads();
  }

#pragma unroll
  for (int m = 0; m < 4; ++m) {
#pragma unroll
    for (int n = 0; n < 4; ++n) {
      int col = bn + wc * 64 + n * 16 + l15;
      float bv = BIAS ? bias[col] : 0.f;
      f32x4 v = acc[m][n];
#pragma unroll
      for (int r2 = 0; r2 < 4; ++r2) {
        int row = bm + wr * 64 + m * 16 + kg * 4 + r2;
        float val = v[r2] + bv;
        if (GELU) val = gelu_f(val);
        if (col < S) {
          Cf[(size_t)row * ldf + col] = val;
        } else {
          Cb[(size_t)row * ldb + (col - S)] = f2bf(val);
        }
      }
    }
  }
}

// ============ f32 GEMM (tiny N=7 head2 only) ============
template<bool BIAS>
__global__ __launch_bounds__(256)
void gemm_k(const float* __restrict__ A, const float* __restrict__ B,
            const float* __restrict__ bias, float* __restrict__ C,
            int M, int N, int K)
{
  __shared__ float As[16][132];
  __shared__ float Bs[16][132];
  const int tid = threadIdx.x;
  const int tx = tid & 15, ty = tid >> 4;
  const int bm = blockIdx.x * 128, bn = blockIdx.y * 128;
  float acc[8][8];
#pragma unroll
  for (int i = 0; i < 8; ++i)
#pragma unroll
    for (int j = 0; j < 8; ++j) acc[i][j] = 0.f;
  const int ar = tid >> 1;
  const int ac = (tid & 1) * 8;
  const int br = tid >> 4;
  const int bc = (tid & 15) * 8;
  for (int k0 = 0; k0 < K; k0 += 16) {
    {
      float av[8] = {0,0,0,0,0,0,0,0};
      if (bm + ar < M) {
        const float* app = A + (size_t)(bm + ar) * K + (k0 + ac);
        float4 a0 = *(const float4*)app;
        float4 a1 = *(const float4*)(app + 4);
        av[0]=a0.x; av[1]=a0.y; av[2]=a0.z; av[3]=a0.w;
        av[4]=a1.x; av[5]=a1.y; av[6]=a1.z; av[7]=a1.w;
      }
#pragma unroll
      for (int i = 0; i < 8; ++i) As[ac + i][ar] = av[i];
    }
    {
      float bv[8] = {0,0,0,0,0,0,0,0};
      const float* bpp = B + (size_t)(k0 + br) * N + (bn + bc);
#pragma unroll
      for (int i = 0; i < 8; ++i) { if (bn + bc + i < N) bv[i] = bpp[i]; }
#pragma unroll
      for (int i = 0; i < 8; ++i) Bs[br][bc + i] = bv[i];
    }
    __syncthreads();
#pragma unroll
    for (int kk = 0; kk < 16; ++kk) {
      float a[8], b[8];
      float4 t0 = *(const float4*)&As[kk][ty * 8];
      float4 t1 = *(const float4*)&As[kk][ty * 8 + 4];
      float4 u0 = *(const float4*)&Bs[kk][tx * 8];
      float4 u1 = *(const float4*)&Bs[kk][tx * 8 + 4];
      a[0]=t0.x;a[1]=t0.y;a[2]=t0.z;a[3]=t0.w;a[4]=t1.x;a[5]=t1.y;a[6]=t1.z;a[7]=t1.w;
      b[0]=u0.x;b[1]=u0.y;b[2]=u0.z;b[3]=u0.w;b[4]=u1.x;b[5]=u1.y;b[6]=u1.z;b[7]=u1.w;
#pragma unroll
      for (int i = 0; i < 8; ++i)
#pragma unroll
        for (int j = 0; j < 8; ++j)
          acc[i][j] = fmaf(a[i], b[j], acc[i][j]);
    }
    __syncthreads();
  }
#pragma unroll
  for (int i = 0; i < 8; ++i) {
    int row = bm + ty * 8 + i;
    if (row >= M) continue;
    int colg = bn + tx * 8;
    float* cp = C + (size_t)row * N + colg;
#pragma unroll
    for (int j = 0; j < 8; ++j) {
      int cc = colg + j;
      if (cc < N) {
        float val = acc[i][j];
        if (BIAS) val += bias[cc];
        cp[j] = val;
      }
    }
  }
}

// ============ transpose+convert: out[(rowOff+n)*totK + kOff + k] = bf16(in[k*N + n]) ============
__global__ void tc_k(const float* __restrict__ in, unsigned short* __restrict__ out,
                     int K, int N, int inStride, int outStride, int rowOff, int totK, int kOff)
{
  const int mat = blockIdx.y;
  const int idx = blockIdx.x * 256 + threadIdx.x;
  if (idx >= N * K) return;
  const int n = idx / K, k = idx - n * K;
  out[(size_t)mat * outStride + (size_t)(rowOff + n) * totK + kOff + k] =
      f2bf(in[(size_t)mat * inStride + (size_t)k * N + n]);
}

// ============ fused T-weight: BT rows 256..767 = (Wq @ WeBD)^T ============
// BT[256+oc][kin] = sum_d Wq[kin, g*32+d] * We[cc, g*32+d],  oc = g*64+cc
__global__ __launch_bounds__(256)
void wqe_k(unsigned short* __restrict__ BT, const float* __restrict__ We, int matStride)
{
  const int mat = blockIdx.y;
  const int oc = blockIdx.x;           // 0..511
  const int g = oc >> 6, cc = oc & 63;
  const int kin = threadIdx.x;         // 0..255
  const float* wrow = We + (size_t)mat * 16384 + (size_t)cc * 256 + g * 32;
  const unsigned short* bq = BT + (size_t)mat * matStride + (size_t)(g * 32) * 256 + kin;
  float acc = 0.f;
#pragma unroll 8
  for (int d = 0; d < 32; ++d)
    acc += bf2f(bq[(size_t)d * 256]) * wrow[d];
  BT[(size_t)mat * matStride + (size_t)(256 + oc) * 256 + kin] = f2bf(acc);
}

// ============ per-dst online-softmax edge aggregation (pair list, 4-edge ILP) ============
__global__ __launch_bounds__(256)
void edge_attn_k(const int* __restrict__ offs, const int2* __restrict__ pairs,
                 const float* __restrict__ ea, const float* __restrict__ qT,
                 const unsigned short* __restrict__ kv, const float* __restrict__ We,
                 unsigned short* __restrict__ msg, int moff, int Nn)
{
  const int wv = (blockIdx.x * blockDim.x + threadIdx.x) >> 6;
  if (wv >= Nn) return;
  const int lane = threadIdx.x & 63;
  const int g = lane >> 3, p = lane & 7;
  const float scale = 0.17677669529663687f;
  const float4 q4 = *(const float4*)(qT + (size_t)wv * 768 + lane * 4);
  const float* Trow = qT + (size_t)wv * 768 + 256 + g * 64 + p * 8;
  const float4 Ta = *(const float4*)Trow;
  const float4 Tc = *(const float4*)(Trow + 4);
  float m = -INFINITY, den = 0.f;
  float ax = 0.f, ay = 0.f, az = 0.f, aw = 0.f;
  float G[8] = {0,0,0,0,0,0,0,0};
  const int e0 = offs[wv], e1 = offs[wv + 1];
  for (int base = e0; base < e1; base += 64) {
    const int cnt = min(64, e1 - base);
    const int2 pr = pairs[base + (lane < cnt ? lane : cnt - 1)];
    for (int c = 0; c < cnt; c += 4) {
      float4 ea0[4], ea1[4];
      ushort4 ku[4], vu[4];
#pragma unroll
      for (int u = 0; u < 4; ++u) {
        const int eid = __shfl(pr.x, c + u, 64);
        const int src = __shfl(pr.y, c + u, 64);
        const float* ep = ea + (size_t)eid * 64 + p * 8;
        ea0[u] = *(const float4*)ep;
        ea1[u] = *(const float4*)(ep + 4);
        const unsigned short* kp = kv + (size_t)src * 512 + lane * 4;
        ku[u] = *(const ushort4*)kp;
        vu[u] = *(const ushort4*)(kp + 256);
      }
      float s[4];
#pragma unroll
      for (int u = 0; u < 4; ++u) {
        float t = q4.x * bf2f(ku[u].x) + q4.y * bf2f(ku[u].y)
                + q4.z * bf2f(ku[u].z) + q4.w * bf2f(ku[u].w);
        t += ea0[u].x * Ta.x + ea0[u].y * Ta.y + ea0[u].z * Ta.z + ea0[u].w * Ta.w;
        t += ea1[u].x * Tc.x + ea1[u].y * Tc.y + ea1[u].z * Tc.z + ea1[u].w * Tc.w;
        t += __shfl_xor(t, 1, 64);
        t += __shfl_xor(t, 2, 64);
        t += __shfl_xor(t, 4, 64);
        s[u] = (c + u < cnt) ? t * scale : -INFINITY;
      }
      const float mn = fmaxf(m, fmaxf(fmaxf(s[0], s[1]), fmaxf(s[2], s[3])));
      const float corr = __expf(m - mn);      // exp(-inf)=0 on first group
      m = mn;
      float w0 = __expf(s[0] - mn), w1 = __expf(s[1] - mn);
      float w2 = __expf(s[2] - mn), w3 = __expf(s[3] - mn);
      den = den * corr + w0 + w1 + w2 + w3;
      ax = ax * corr + w0*bf2f(vu[0].x) + w1*bf2f(vu[1].x) + w2*bf2f(vu[2].x) + w3*bf2f(vu[3].x);
      ay = ay * corr + w0*bf2f(vu[0].y) + w1*bf2f(vu[1].y) + w2*bf2f(vu[2].y) + w3*bf2f(vu[3].y);
      az = az * corr + w0*bf2f(vu[0].z) + w1*bf2f(vu[1].z) + w2*bf2f(vu[2].z) + w3*bf2f(vu[3].z);
      aw = aw * corr + w0*bf2f(vu[0].w) + w1*bf2f(vu[1].w) + w2*bf2f(vu[2].w) + w3*bf2f(vu[3].w);
      G[0] = G[0]*corr + w0*ea0[0].x + w1*ea0[1].x + w2*ea0[2].x + w3*ea0[3].x;
      G[1] = G[1]*corr + w0*ea0[0].y + w1*ea0[1].y + w2*ea0[2].y + w3*ea0[3].y;
      G[2] = G[2]*corr + w0*ea0[0].z + w1*ea0[1].z + w2*ea0[2].z + w3*ea0[3].z;
      G[3] = G[3]*corr + w0*ea0[0].w + w1*ea0[1].w + w2*ea0[2].w + w3*ea0[3].w;
      G[4] = G[4]*corr + w0*ea1[0].x + w1*ea1[1].x + w2*ea1[2].x + w3*ea1[3].x;
      G[5] = G[5]*corr + w0*ea1[0].y + w1*ea1[1].y + w2*ea1[2].y + w3*ea1[3].y;
      G[6] = G[6]*corr + w0*ea1[0].z + w1*ea1[1].z + w2*ea1[2].z + w3*ea1[3].z;
      G[7] = G[7]*corr + w0*ea1[0].w + w1*ea1[1].w + w2*ea1[2].w + w3*ea1[3].w;
    }
  }
  float ex = 0.f, ey = 0.f, ez = 0.f, ew = 0.f;
#pragma unroll
  for (int c8 = 0; c8 < 8; ++c8) {
#pragma unroll
    for (int i = 0; i < 8; ++i) {
      const float Gc = __shfl(G[i], g * 8 + c8, 64);
      const int c = c8 * 8 + i;
      const float4 w4 = *(const float4*)(We + (size_t)c * 256 + lane * 4);
      ex = fmaf(Gc, w4.x, ex); ey = fmaf(Gc, w4.y, ey);
      ez = fmaf(Gc, w4.z, ez); ew = fmaf(Gc, w4.w, ew);
    }
  }
  const float inv = 1.f / (den + 1e-9f);
  ushort4 o;
  o.x = f2bf((ax + ex) * inv); o.y = f2bf((ay + ey) * inv);
  o.z = f2bf((az + ez) * inv); o.w = f2bf((aw + ew) * inv);
  *(ushort4*)(msg + (size_t)wv * 512 + moff + lane * 4) = o;
}

// ============ residual add + LayerNorm, writes f32 + bf16 mirror ============
__global__ __launch_bounds__(256)
void add_ln_k(float* __restrict__ x, unsigned short* __restrict__ xb,
              const float* __restrict__ add, int Nn)
{
  const int wv = (blockIdx.x * blockDim.x + threadIdx.x) >> 6;
  if (wv >= Nn) return;
  const int lane = threadIdx.x & 63;
  float4 xv = *(const float4*)(x + (size_t)wv * 256 + lane * 4);
  float4 av = *(const float4*)(add + (size_t)wv * 256 + lane * 4);
  float4 y;
  y.x = xv.x + av.x; y.y = xv.y + av.y; y.z = xv.z + av.z; y.w = xv.w + av.w;
  float s = y.x + y.y + y.z + y.w;
#pragma unroll
  for (int msk = 1; msk < 64; msk <<= 1) s += __shfl_xor(s, msk, 64);
  const float mean = s * (1.f / 256.f);
  float4 d;
  d.x = y.x - mean; d.y = y.y - mean; d.z = y.z - mean; d.w = y.w - mean;
  float sq = d.x*d.x + d.y*d.y + d.z*d.z + d.w*d.w;
#pragma unroll
  for (int msk = 1; msk < 64; msk <<= 1) sq += __shfl_xor(sq, msk, 64);
  const float r = rsqrtf(sq * (1.f / 256.f) + 1e-5f);
  float4 o;
  o.x = d.x * r; o.y = d.y * r; o.z = d.z * r; o.w = d.w * r;
  *(float4*)(x + (size_t)wv * 256 + lane * 4) = o;
  ushort4 ob;
  ob.x = f2bf(o.x); ob.y = f2bf(o.y); ob.z = f2bf(o.z); ob.w = f2bf(o.w);
  *(ushort4*)(xb + (size_t)wv * 256 + lane * 4) = ob;
}

// ============ init: copy f32 + bf16 mirror ============
__global__ void cvt_x_k(const float* __restrict__ a, float* __restrict__ x,
                        unsigned short* __restrict__ xb, int n4)
{
  int i = blockIdx.x * 256 + threadIdx.x;
  if (i >= n4) return;
  float4 v = ((const float4*)a)[i];
  ((float4*)x)[i] = v;
  ushort4 b;
  b.x = f2bf(v.x); b.y = f2bf(v.y); b.z = f2bf(v.z); b.w = f2bf(v.w);
  ((ushort4*)xb)[i] = b;
}

// ============ CSR kernels ============
__global__ void zero4_k(int* p, int n) {
  int i = blockIdx.x * 256 + threadIdx.x;
  if (i < n) p[i] = 0;
}
__global__ void hist4_k(const int* d0, const int* d1, const int* d2, const int* d3,
                        int E0, int E1, int E2, int E3, int* cnt, int Nn) {
  const int s = blockIdx.y;
  const int* d = (s == 0) ? d0 : (s == 1) ? d1 : (s == 2) ? d2 : d3;
  const int E = (s == 0) ? E0 : (s == 1) ? E1 : (s == 2) ? E2 : E3;
  int e = blockIdx.x * 256 + threadIdx.x;
  if (e < E) atomicAdd(&cnt[s * Nn + d[e]], 1);
}
__global__ __launch_bounds__(256)
void scan4_k(const int* __restrict__ cnt, int* __restrict__ offs, int* __restrict__ cursor, int Nn)
{
  __shared__ int sums[256];
  const int s = blockIdx.x;
  const int t = threadIdx.x;
  const int* c = cnt + (size_t)s * Nn;
  int* o = offs + (size_t)s * (Nn + 1);
  int* cur = cursor + (size_t)s * Nn;
  const int chunk = (Nn + 255) / 256;
  const int base = t * chunk;
  int sl = 0;
  for (int i = 0; i < chunk; ++i) {
    int idx = base + i;
    if (idx < Nn) sl += c[idx];
  }
  sums[t] = sl;
  __syncthreads();
  for (int off = 1; off < 256; off <<= 1) {
    int val = (t >= off) ? sums[t - off] : 0;
    __syncthreads();
    sums[t] += val;
    __syncthreads();
  }
  int run = (t == 0) ? 0 : sums[t - 1];
  for (int i = 0; i < chunk; ++i) {
    int idx = base + i;
    if (idx < Nn) { o[idx] = run; cur[idx] = run; run += c[idx]; }
  }
  if (t == 255) o[Nn] = run;
}
// emits (eid, src) packed pairs in CSR order
__global__ void scatter4_k(const int* e0p, const int* e1p, const int* e2p, const int* e3p,
                           int E0, int E1, int E2, int E3, int* cursor,
                           int2* p0, int2* p1, int2* p2, int2* p3, int Nn) {
  const int s = blockIdx.y;
  const int* ei = (s == 0) ? e0p : (s == 1) ? e1p : (s == 2) ? e2p : e3p;
  int2* po = (s == 0) ? p0 : (s == 1) ? p1 : (s == 2) ? p2 : p3;
  const int E = (s == 0) ? E0 : (s == 1) ? E1 : (s == 2) ? E2 : E3;
  int e = blockIdx.x * 256 + threadIdx.x;
  if (e < E) {
    int pos = atomicAdd(&cursor[s * Nn + ei[E + e]], 1);
    po[pos] = make_int2(e, ei[e]);
  }
}

// ============ host orchestration ============
extern "C" void kernel_launch(void* const* d_in, const int* in_sizes, int n_in,
                              void* d_out, int out_size, void* d_ws, size_t ws_size,
                              hipStream_t stream)
{
  (void)n_in; (void)ws_size;
  const float* afl = (const float*)d_in[0];
  const float* afr = (const float*)d_in[1];
  const float* eaA[4] = {(const float*)d_in[2], (const float*)d_in[3],
                         (const float*)d_in[4], (const float*)d_in[5]};
  const int* eiA[4] = {(const int*)d_in[6], (const int*)d_in[7],
                       (const int*)d_in[8], (const int*)d_in[9]};
  const float* Wq  = (const float*)d_in[10];
  const float* Wk  = (const float*)d_in[11];
  const float* Wv  = (const float*)d_in[12];
  const float* We  = (const float*)d_in[13];
  const float* Wo  = (const float*)d_in[14];
  const float* fw1 = (const float*)d_in[15];
  const float* fb1 = (const float*)d_in[16];
  const float* fw2 = (const float*)d_in[17];
  const float* fb2 = (const float*)d_in[18];
  const float* hw1 = (const float*)d_in[19];
  const float* hb1 = (const float*)d_in[20];
  const float* hw2 = (const float*)d_in[21];
  const float* hb2 = (const float*)d_in[22];

  const int Nn = in_sizes[0] / 256;
  const int E[4] = {in_sizes[2] / 64, in_sizes[3] / 64, in_sizes[4] / 64, in_sizes[5] / 64};
  const int Mh = out_size / 14;
  const int astart = Nn - Mh;
  float* out = (float*)d_out;

  char* wsp = (char*)d_ws;
  auto alloc = [&](size_t bytes) -> void* {
    void* pp = (void*)wsp;
    wsp += (bytes + 255) & ~(size_t)255;
    return pp;
  };
  float* xl   = (float*)alloc((size_t)Nn * 256 * 4);
  float* xr   = (float*)alloc((size_t)Nn * 256 * 4);
  unsigned short* xlb = (unsigned short*)alloc((size_t)Nn * 256 * 2);
  unsigned short* xrb = (unsigned short*)alloc((size_t)Nn * 256 * 2);
  float* agg  = (float*)alloc((size_t)Nn * 256 * 4);
  float* qT   = (float*)alloc((size_t)Nn * 768 * 4);
  unsigned short* kvb  = (unsigned short*)alloc((size_t)Nn * 512 * 2);
  unsigned short* msgL = (unsigned short*)alloc((size_t)Nn * 512 * 2);
  unsigned short* msgR = (unsigned short*)alloc((size_t)Nn * 512 * 2);
  unsigned short* BTqkvT = (unsigned short*)alloc((size_t)8 * 1280 * 256 * 2);
  unsigned short* BTo    = (unsigned short*)alloc((size_t)4 * 256 * 512 * 2);
  unsigned short* BTf1   = (unsigned short*)alloc((size_t)4 * 512 * 256 * 2);
  unsigned short* BTf2   = (unsigned short*)alloc((size_t)4 * 256 * 512 * 2);
  unsigned short* BTh1   = (unsigned short*)alloc((size_t)256 * 256 * 2);
  int* offs4 = (int*)alloc((size_t)4 * (Nn + 1) * 4);
  int* cnt4  = (int*)alloc((size_t)4 * Nn * 4);
  int* cur4  = (int*)alloc((size_t)4 * Nn * 4);
  int2* pairs[4];
  for (int s = 0; s < 4; ++s) pairs[s] = (int2*)alloc((size_t)E[s] * 8);

  const dim3 B256(256);
  const int wgNodes = (Nn * 64 + 255) / 256;
  int maxE = E[0];
  for (int s = 1; s < 4; ++s) if (E[s] > maxE) maxE = E[s];

  // ---- init x (+bf16 mirrors), CSR pair lists ----
  cvt_x_k<<<dim3((Nn * 64 + 255) / 256), B256, 0, stream>>>(afl, xl, xlb, Nn * 64);
  cvt_x_k<<<dim3((Nn * 64 + 255) / 256), B256, 0, stream>>>(afr, xr, xrb, Nn * 64);
  zero4_k<<<dim3((4 * Nn + 255) / 256), B256, 0, stream>>>(cnt4, 4 * Nn);
  {
    dim3 gh((maxE + 255) / 256, 4);
    hist4_k<<<gh, B256, 0, stream>>>(eiA[0] + E[0], eiA[1] + E[1], eiA[2] + E[2], eiA[3] + E[3],
                                     E[0], E[1], E[2], E[3], cnt4, Nn);
    scan4_k<<<dim3(4), B256, 0, stream>>>(cnt4, offs4, cur4, Nn);
    scatter4_k<<<gh, B256, 0, stream>>>(eiA[0], eiA[1], eiA[2], eiA[3],
                                        E[0], E[1], E[2], E[3], cur4,
                                        pairs[0], pairs[1], pairs[2], pairs[3], Nn);
  }
  // ---- weight conversion ----
  {
    dim3 g8((65536 + 255) / 256, 8);
    tc_k<<<g8, B256, 0, stream>>>(Wq, BTqkvT, 256, 256, 65536, 327680, 0,    256, 0);
    tc_k<<<g8, B256, 0, stream>>>(Wk, BTqkvT, 256, 256, 65536, 327680, 768,  256, 0);
    tc_k<<<g8, B256, 0, stream>>>(Wv, BTqkvT, 256, 256, 65536, 327680, 1024, 256, 0);
    wqe_k<<<dim3(512, 8), B256, 0, stream>>>(BTqkvT, We, 327680);
    dim3 g1((65536 + 255) / 256, 1);
    for (int l = 0; l < 2; ++l) {
      tc_k<<<g1, B256, 0, stream>>>(Wo + (size_t)(l*4+0)*65536, BTo + (size_t)(l*2+0)*131072, 256, 256, 0, 0, 0, 512, 0);
      tc_k<<<g1, B256, 0, stream>>>(Wo + (size_t)(l*4+3)*65536, BTo + (size_t)(l*2+0)*131072, 256, 256, 0, 0, 0, 512, 256);
      tc_k<<<g1, B256, 0, stream>>>(Wo + (size_t)(l*4+1)*65536, BTo + (size_t)(l*2+1)*131072, 256, 256, 0, 0, 0, 512, 0);
      tc_k<<<g1, B256, 0, stream>>>(Wo + (size_t)(l*4+2)*65536, BTo + (size_t)(l*2+1)*131072, 256, 256, 0, 0, 0, 512, 256);
    }
    tc_k<<<dim3((131072 + 255) / 256, 4), B256, 0, stream>>>(fw1, BTf1, 256, 512, 131072, 131072, 0, 256, 0);
    tc_k<<<dim3((131072 + 255) / 256, 4), B256, 0, stream>>>(fw2, BTf2, 512, 256, 131072, 131072, 0, 512, 0);
    tc_k<<<g1, B256, 0, stream>>>(hw1, BTh1, 256, 256, 0, 0, 0, 256, 0);
  }

  auto mfma = [&](const unsigned short* A, int lda, const unsigned short* BT,
                  const float* bias, float* Cf, unsigned short* Cb,
                  int M, int N, int K, int S, int ldf, int ldb, bool biasf, bool gelu) {
    dim3 g(M / 128, N / 128);
    if (biasf && gelu) gemm_mfma_k<true, true ><<<g, B256, 0, stream>>>(A, lda, BT, bias, Cf, Cb, M, N, K, S, ldf, ldb);
    else if (biasf)    gemm_mfma_k<true, false><<<g, B256, 0, stream>>>(A, lda, BT, bias, Cf, Cb, M, N, K, S, ldf, ldb);
    else               gemm_mfma_k<false,false><<<g, B256, 0, stream>>>(A, lda, BT, bias, Cf, Cb, M, N, K, S, ldf, ldb);
  };

  // attn: weights index i, edge set s, writes msg[...moff]
  auto run_attn = [&](int l, int i, int s, const unsigned short* xqb, const unsigned short* xkb,
                      unsigned short* msg, int moff) {
    const int idx = l * 4 + i;
    const unsigned short* bt = BTqkvT + (size_t)idx * 327680;
    if (xqb == xkb) {
      mfma(xqb, 256, bt, nullptr, qT, kvb, Nn, 1280, 256, 768, 768, 512, false, false);
    } else {
      mfma(xqb, 256, bt, nullptr, qT, nullptr, Nn, 768, 256, 768, 768, 0, false, false);
      mfma(xkb, 256, bt + (size_t)768 * 256, nullptr, nullptr, kvb, Nn, 512, 256, 0, 0, 512, false, false);
    }
    edge_attn_k<<<dim3(wgNodes), B256, 0, stream>>>(offs4 + (size_t)s * (Nn + 1), pairs[s],
                                                    eaA[s], qT, kvb,
                                                    We + (size_t)idx * 16384, msg, moff, Nn);
  };

  for (int l = 0; l < 2; ++l) {
    run_attn(l, 0, 0, xlb, xlb, msgL, 0);    // ll
    run_attn(l, 3, 3, xlb, xrb, msgL, 256);  // rl (q from xl, kv from xr)
    run_attn(l, 1, 1, xrb, xrb, msgR, 0);    // rr
    run_attn(l, 2, 2, xrb, xlb, msgR, 256);  // lr (q from xr, kv from xl)
    // fused Wo pair GEMMs + add+LN
    mfma(msgL, 512, BTo + (size_t)(l*2+0)*131072, nullptr, agg, nullptr, Nn, 256, 512, 256, 256, 0, false, false);
    add_ln_k<<<dim3(wgNodes), B256, 0, stream>>>(xl, xlb, agg, Nn);
    mfma(msgR, 512, BTo + (size_t)(l*2+1)*131072, nullptr, agg, nullptr, Nn, 256, 512, 256, 256, 0, false, false);
    add_ln_k<<<dim3(wgNodes), B256, 0, stream>>>(xr, xrb, agg, Nn);
    // FFN per side
    for (int s2 = 0; s2 < 2; ++s2) {
      float* x = s2 ? xr : xl;
      unsigned short* xb = s2 ? xrb : xlb;
      const int fi = l * 2 + s2;
      mfma(xb, 256, BTf1 + (size_t)fi * 131072, fb1 + (size_t)fi * 512, nullptr, kvb,
           Nn, 512, 256, 0, 0, 512, true, true);
      mfma(kvb, 512, BTf2 + (size_t)fi * 131072, fb2 + (size_t)fi * 256, agg, nullptr,
           Nn, 256, 512, 256, 256, 0, true, false);
      add_ln_k<<<dim3(wgNodes), B256, 0, stream>>>(x, xb, agg, Nn);
    }
  }
  // heads
  mfma(xlb + (size_t)astart * 256, 256, BTh1, hb1, qT, nullptr, Mh, 256, 256, 256, 256, 0, true, true);
  gemm_k<true><<<dim3(Mh / 128, 1), B256, 0, stream>>>(qT, hw2, hb2, out, Mh, 7, 256);
  mfma(xrb + (size_t)astart * 256, 256, BTh1, hb1, qT, nullptr, Mh, 256, 256, 256, 256, 0, true, true);
  gemm_k<true><<<dim3(Mh / 128, 1), B256, 0, stream>>>(qT, hw2, hb2, out + (size_t)Mh * 7, Mh, 7, 256);
}

// Round 4
// 1660.523 us; speedup vs baseline: 1.2634x; 1.2634x over previous
//
#include <hip/hip_runtime.h>
#include <math.h>

typedef __attribute__((ext_vector_type(8))) short short8;
typedef __attribute__((ext_vector_type(4))) float f32x4;

__device__ __forceinline__ unsigned short f2bf(float f) {
  unsigned u = __builtin_bit_cast(unsigned, f);
  u += 0x7fff + ((u >> 16) & 1);
  return (unsigned short)(u >> 16);
}
__device__ __forceinline__ float bf2f(unsigned short h) {
  unsigned u = ((unsigned)h) << 16;
  return __builtin_bit_cast(float, u);
}
__device__ __forceinline__ float gelu_f(float x) {
  const float c0 = 0.7978845608028654f;
  return 0.5f * x * (1.0f + tanhf(c0 * (x + 0.044715f * x * x * x)));
}

// ============ bf16 MFMA GEMM: C = A(bf16,[M][lda]) @ BT(bf16,[N][K]) ============
// 3-way epilogue split by col: [0,Sf) -> f32 Cf ; [Sf,S2) -> bf16 Cb1 ; [S2,N) -> bf16 Cb2
template<bool BIAS, bool GELU>
__global__ __launch_bounds__(256)
void gemm_mfma_k(const unsigned short* __restrict__ A, int lda,
                 const unsigned short* __restrict__ BT,
                 const float* __restrict__ bias,
                 float* __restrict__ Cf, int Sf, int ldf,
                 unsigned short* __restrict__ Cb1, int S2, int ldb1,
                 unsigned short* __restrict__ Cb2, int ldb2,
                 int M, int N, int K)
{
  __shared__ __align__(16) unsigned short As[128 * 32];
  __shared__ __align__(16) unsigned short Bs[128 * 32];
  const int tid = threadIdx.x;
  const int bm = blockIdx.x * 128, bn = blockIdx.y * 128;
  const int lane = tid & 63, w = tid >> 6;
  const int wr = w >> 1, wc = w & 1;
  const int l15 = lane & 15, kg = lane >> 4;
  const int sr = tid >> 1, kh = tid & 1;
  const unsigned short* ap = A + (size_t)(bm + sr) * lda + kh * 16;
  const unsigned short* bp = BT + (size_t)(bn + sr) * K + kh * 16;
  const int ph0 = ((kh * 2 + 0) + (sr >> 1)) & 3;   // k-slot swizzle (2-way free)
  const int ph1 = ((kh * 2 + 1) + (sr >> 1)) & 3;
  unsigned short* wa0 = As + sr * 32 + ph0 * 8;
  unsigned short* wa1 = As + sr * 32 + ph1 * 8;
  unsigned short* wb0 = Bs + sr * 32 + ph0 * 8;
  unsigned short* wb1 = Bs + sr * 32 + ph1 * 8;

  f32x4 acc[4][4] = {};

  for (int k0 = 0; k0 < K; k0 += 32) {
    uint4 a0 = *(const uint4*)(ap + k0);
    uint4 a1 = *(const uint4*)(ap + k0 + 8);
    uint4 b0 = *(const uint4*)(bp + k0);
    uint4 b1 = *(const uint4*)(bp + k0 + 8);
    *(uint4*)wa0 = a0;
    *(uint4*)wa1 = a1;
    *(uint4*)wb0 = b0;
    *(uint4*)wb1 = b1;
    __syncthreads();
    short8 af[4], bfr[4];
#pragma unroll
    for (int m = 0; m < 4; ++m) {
      int row = wr * 64 + m * 16 + l15;
      int ph = (kg + (row >> 1)) & 3;
      af[m] = *(const short8*)(As + row * 32 + ph * 8);
    }
#pragma unroll
    for (int n = 0; n < 4; ++n) {
      int col = wc * 64 + n * 16 + l15;
      int ph = (kg + (col >> 1)) & 3;
      bfr[n] = *(const short8*)(Bs + col * 32 + ph * 8);
    }
#pragma unroll
    for (int m = 0; m < 4; ++m)
#pragma unroll
      for (int n = 0; n < 4; ++n)
        acc[m][n] = __builtin_amdgcn_mfma_f32_16x16x32_bf16(af[m], bfr[n], acc[m][n], 0, 0, 0);
    __syncthreads();
  }

#pragma unroll
  for (int m = 0; m < 4; ++m) {
#pragma unroll
    for (int n = 0; n < 4; ++n) {
      int col = bn + wc * 64 + n * 16 + l15;
      float bv = BIAS ? bias[col] : 0.f;
      f32x4 v = acc[m][n];
#pragma unroll
      for (int r2 = 0; r2 < 4; ++r2) {
        int row = bm + wr * 64 + m * 16 + kg * 4 + r2;
        float val = v[r2] + bv;
        if (GELU) val = gelu_f(val);
        if (col < Sf) {
          Cf[(size_t)row * ldf + col] = val;
        } else if (col < S2) {
          Cb1[(size_t)row * ldb1 + (col - Sf)] = f2bf(val);
        } else {
          Cb2[(size_t)row * ldb2 + (col - S2)] = f2bf(val);
        }
      }
    }
  }
}

// ============ f32 GEMM (tiny N=7 head2 only) ============
template<bool BIAS>
__global__ __launch_bounds__(256)
void gemm_k(const float* __restrict__ A, const float* __restrict__ B,
            const float* __restrict__ bias, float* __restrict__ C,
            int M, int N, int K)
{
  __shared__ float As[16][132];
  __shared__ float Bs[16][132];
  const int tid = threadIdx.x;
  const int tx = tid & 15, ty = tid >> 4;
  const int bm = blockIdx.x * 128, bn = blockIdx.y * 128;
  float acc[8][8];
#pragma unroll
  for (int i = 0; i < 8; ++i)
#pragma unroll
    for (int j = 0; j < 8; ++j) acc[i][j] = 0.f;
  const int ar = tid >> 1;
  const int ac = (tid & 1) * 8;
  const int br = tid >> 4;
  const int bc = (tid & 15) * 8;
  for (int k0 = 0; k0 < K; k0 += 16) {
    {
      float av[8] = {0,0,0,0,0,0,0,0};
      if (bm + ar < M) {
        const float* app = A + (size_t)(bm + ar) * K + (k0 + ac);
        float4 a0 = *(const float4*)app;
        float4 a1 = *(const float4*)(app + 4);
        av[0]=a0.x; av[1]=a0.y; av[2]=a0.z; av[3]=a0.w;
        av[4]=a1.x; av[5]=a1.y; av[6]=a1.z; av[7]=a1.w;
      }
#pragma unroll
      for (int i = 0; i < 8; ++i) As[ac + i][ar] = av[i];
    }
    {
      float bv[8] = {0,0,0,0,0,0,0,0};
      const float* bpp = B + (size_t)(k0 + br) * N + (bn + bc);
#pragma unroll
      for (int i = 0; i < 8; ++i) { if (bn + bc + i < N) bv[i] = bpp[i]; }
#pragma unroll
      for (int i = 0; i < 8; ++i) Bs[br][bc + i] = bv[i];
    }
    __syncthreads();
#pragma unroll
    for (int kk = 0; kk < 16; ++kk) {
      float a[8], b[8];
      float4 t0 = *(const float4*)&As[kk][ty * 8];
      float4 t1 = *(const float4*)&As[kk][ty * 8 + 4];
      float4 u0 = *(const float4*)&Bs[kk][tx * 8];
      float4 u1 = *(const float4*)&Bs[kk][tx * 8 + 4];
      a[0]=t0.x;a[1]=t0.y;a[2]=t0.z;a[3]=t0.w;a[4]=t1.x;a[5]=t1.y;a[6]=t1.z;a[7]=t1.w;
      b[0]=u0.x;b[1]=u0.y;b[2]=u0.z;b[3]=u0.w;b[4]=u1.x;b[5]=u1.y;b[6]=u1.z;b[7]=u1.w;
#pragma unroll
      for (int i = 0; i < 8; ++i)
#pragma unroll
        for (int j = 0; j < 8; ++j)
          acc[i][j] = fmaf(a[i], b[j], acc[i][j]);
    }
    __syncthreads();
  }
#pragma unroll
  for (int i = 0; i < 8; ++i) {
    int row = bm + ty * 8 + i;
    if (row >= M) continue;
    int colg = bn + tx * 8;
    float* cp = C + (size_t)row * N + colg;
#pragma unroll
    for (int j = 0; j < 8; ++j) {
      int cc = colg + j;
      if (cc < N) {
        float val = acc[i][j];
        if (BIAS) val += bias[cc];
        cp[j] = val;
      }
    }
  }
}

// ============ transpose+convert: out[(rowOff+n)*totK + kOff + k] = bf16(in[k*N + n]) ============
__global__ void tc_k(const float* __restrict__ in, unsigned short* __restrict__ out,
                     int K, int N, int inStride, int outStride, int rowOff, int totK, int kOff)
{
  const int mat = blockIdx.y;
  const int idx = blockIdx.x * 256 + threadIdx.x;
  if (idx >= N * K) return;
  const int n = idx / K, k = idx - n * K;
  out[(size_t)mat * outStride + (size_t)(rowOff + n) * totK + kOff + k] =
      f2bf(in[(size_t)mat * inStride + (size_t)k * N + n]);
}

// ============ fused T-weight: BT rows 256..767 = (Wq @ WeBD)^T ============
__global__ __launch_bounds__(256)
void wqe_k(unsigned short* __restrict__ BT, const float* __restrict__ We, int matStride)
{
  const int mat = blockIdx.y;
  const int oc = blockIdx.x;           // 0..511
  const int g = oc >> 6, cc = oc & 63;
  const int kin = threadIdx.x;         // 0..255
  const float* wrow = We + (size_t)mat * 16384 + (size_t)cc * 256 + g * 32;
  const unsigned short* bq = BT + (size_t)mat * matStride + (size_t)(g * 32) * 256 + kin;
  float acc = 0.f;
#pragma unroll 8
  for (int d = 0; d < 32; ++d)
    acc += bf2f(bq[(size_t)d * 256]) * wrow[d];
  BT[(size_t)mat * matStride + (size_t)(256 + oc) * 256 + kin] = f2bf(acc);
}

// ============ per-dst online-softmax edge aggregation (scalar pair stream) ============
__global__ __launch_bounds__(256)
void edge_attn_k(const int* __restrict__ offs, const int2* __restrict__ pairs,
                 const float* __restrict__ ea, const unsigned short* __restrict__ qTb,
                 const unsigned short* __restrict__ kv, const float* __restrict__ We,
                 unsigned short* __restrict__ msg, int moff, int Nn)
{
  const int wv = (blockIdx.x * blockDim.x + threadIdx.x) >> 6;
  if (wv >= Nn) return;
  const int lane = threadIdx.x & 63;
  const int g = lane >> 3, p = lane & 7;
  const float scale = 0.17677669529663687f;
  const ushort4 qu = *(const ushort4*)(qTb + (size_t)wv * 768 + lane * 4);
  const float qx = bf2f(qu.x), qy = bf2f(qu.y), qz = bf2f(qu.z), qw = bf2f(qu.w);
  const unsigned short* Tp = qTb + (size_t)wv * 768 + 256 + g * 64 + p * 8;
  const ushort4 tu0 = *(const ushort4*)Tp;
  const ushort4 tu1 = *(const ushort4*)(Tp + 4);
  const float Ta0 = bf2f(tu0.x), Ta1 = bf2f(tu0.y), Ta2 = bf2f(tu0.z), Ta3 = bf2f(tu0.w);
  const float Tc0 = bf2f(tu1.x), Tc1 = bf2f(tu1.y), Tc2 = bf2f(tu1.z), Tc3 = bf2f(tu1.w);
  float m = -INFINITY, den = 0.f;
  float ax = 0.f, ay = 0.f, az = 0.f, aw = 0.f;
  float G[8] = {0,0,0,0,0,0,0,0};
  // wave-uniform loop bounds -> scalar pair loads, SGPR eid/src
  const int e0 = __builtin_amdgcn_readfirstlane(offs[wv]);
  const int e1 = __builtin_amdgcn_readfirstlane(offs[wv + 1]);
  for (int j = e0; j < e1; j += 2) {
    const bool hasB = (j + 1) < e1;
    const int2 prA = pairs[j];
    const int2 prB = hasB ? pairs[j + 1] : prA;
    const float* epA = ea + (size_t)prA.x * 64 + p * 8;
    const float* epB = ea + (size_t)prB.x * 64 + p * 8;
    const unsigned short* kpA = kv + (size_t)prA.y * 512 + lane * 4;
    const unsigned short* kpB = kv + (size_t)prB.y * 512 + lane * 4;
    const float4 eA0 = *(const float4*)epA;
    const float4 eA1 = *(const float4*)(epA + 4);
    const float4 eB0 = *(const float4*)epB;
    const float4 eB1 = *(const float4*)(epB + 4);
    const ushort4 kAu = *(const ushort4*)kpA;
    const ushort4 vAu = *(const ushort4*)(kpA + 256);
    const ushort4 kBu = *(const ushort4*)kpB;
    const ushort4 vBu = *(const ushort4*)(kpB + 256);
    float pA = qx * bf2f(kAu.x) + qy * bf2f(kAu.y) + qz * bf2f(kAu.z) + qw * bf2f(kAu.w);
    pA += eA0.x * Ta0 + eA0.y * Ta1 + eA0.z * Ta2 + eA0.w * Ta3;
    pA += eA1.x * Tc0 + eA1.y * Tc1 + eA1.z * Tc2 + eA1.w * Tc3;
    float pB = qx * bf2f(kBu.x) + qy * bf2f(kBu.y) + qz * bf2f(kBu.z) + qw * bf2f(kBu.w);
    pB += eB0.x * Ta0 + eB0.y * Ta1 + eB0.z * Ta2 + eB0.w * Ta3;
    pB += eB1.x * Tc0 + eB1.y * Tc1 + eB1.z * Tc2 + eB1.w * Tc3;
    pA += __shfl_xor(pA, 1, 64); pA += __shfl_xor(pA, 2, 64); pA += __shfl_xor(pA, 4, 64);
    pB += __shfl_xor(pB, 1, 64); pB += __shfl_xor(pB, 2, 64); pB += __shfl_xor(pB, 4, 64);
    const float sA = pA * scale;
    const float sB = hasB ? pB * scale : -INFINITY;
    const float mn = fmaxf(m, fmaxf(sA, sB));
    const float corr = __expf(m - mn);   // exp(-inf)=0 on first iteration
    const float wA = __expf(sA - mn);
    const float wB = __expf(sB - mn);
    m = mn;
    den = den * corr + wA + wB;
    ax = ax * corr + wA * bf2f(vAu.x) + wB * bf2f(vBu.x);
    ay = ay * corr + wA * bf2f(vAu.y) + wB * bf2f(vBu.y);
    az = az * corr + wA * bf2f(vAu.z) + wB * bf2f(vBu.z);
    aw = aw * corr + wA * bf2f(vAu.w) + wB * bf2f(vBu.w);
    G[0] = G[0] * corr + wA * eA0.x + wB * eB0.x;
    G[1] = G[1] * corr + wA * eA0.y + wB * eB0.y;
    G[2] = G[2] * corr + wA * eA0.z + wB * eB0.z;
    G[3] = G[3] * corr + wA * eA0.w + wB * eB0.w;
    G[4] = G[4] * corr + wA * eA1.x + wB * eB1.x;
    G[5] = G[5] * corr + wA * eA1.y + wB * eB1.y;
    G[6] = G[6] * corr + wA * eA1.z + wB * eB1.z;
    G[7] = G[7] * corr + wA * eA1.w + wB * eB1.w;
  }
  float ex = 0.f, ey = 0.f, ez = 0.f, ew = 0.f;
#pragma unroll
  for (int c8 = 0; c8 < 8; ++c8) {
#pragma unroll
    for (int i = 0; i < 8; ++i) {
      const float Gc = __shfl(G[i], g * 8 + c8, 64);
      const int c = c8 * 8 + i;
      const float4 w4 = *(const float4*)(We + (size_t)c * 256 + lane * 4);
      ex = fmaf(Gc, w4.x, ex); ey = fmaf(Gc, w4.y, ey);
      ez = fmaf(Gc, w4.z, ez); ew = fmaf(Gc, w4.w, ew);
    }
  }
  const float inv = 1.f / (den + 1e-9f);
  ushort4 o;
  o.x = f2bf((ax + ex) * inv); o.y = f2bf((ay + ey) * inv);
  o.z = f2bf((az + ez) * inv); o.w = f2bf((aw + ew) * inv);
  *(ushort4*)(msg + (size_t)wv * 512 + moff + lane * 4) = o;
}

// ============ residual add + LayerNorm, writes f32 + bf16 mirror ============
__global__ __launch_bounds__(256)
void add_ln_k(float* __restrict__ x, unsigned short* __restrict__ xb,
              const float* __restrict__ add, int Nn)
{
  const int wv = (blockIdx.x * blockDim.x + threadIdx.x) >> 6;
  if (wv >= Nn) return;
  const int lane = threadIdx.x & 63;
  float4 xv = *(const float4*)(x + (size_t)wv * 256 + lane * 4);
  float4 av = *(const float4*)(add + (size_t)wv * 256 + lane * 4);
  float4 y;
  y.x = xv.x + av.x; y.y = xv.y + av.y; y.z = xv.z + av.z; y.w = xv.w + av.w;
  float s = y.x + y.y + y.z + y.w;
#pragma unroll
  for (int msk = 1; msk < 64; msk <<= 1) s += __shfl_xor(s, msk, 64);
  const float mean = s * (1.f / 256.f);
  float4 d;
  d.x = y.x - mean; d.y = y.y - mean; d.z = y.z - mean; d.w = y.w - mean;
  float sq = d.x*d.x + d.y*d.y + d.z*d.z + d.w*d.w;
#pragma unroll
  for (int msk = 1; msk < 64; msk <<= 1) sq += __shfl_xor(sq, msk, 64);
  const float r = rsqrtf(sq * (1.f / 256.f) + 1e-5f);
  float4 o;
  o.x = d.x * r; o.y = d.y * r; o.z = d.z * r; o.w = d.w * r;
  *(float4*)(x + (size_t)wv * 256 + lane * 4) = o;
  ushort4 ob;
  ob.x = f2bf(o.x); ob.y = f2bf(o.y); ob.z = f2bf(o.z); ob.w = f2bf(o.w);
  *(ushort4*)(xb + (size_t)wv * 256 + lane * 4) = ob;
}

// ============ init: copy f32 + bf16 mirror ============
__global__ void cvt_x_k(const float* __restrict__ a, float* __restrict__ x,
                        unsigned short* __restrict__ xb, int n4)
{
  int i = blockIdx.x * 256 + threadIdx.x;
  if (i >= n4) return;
  float4 v = ((const float4*)a)[i];
  ((float4*)x)[i] = v;
  ushort4 b;
  b.x = f2bf(v.x); b.y = f2bf(v.y); b.z = f2bf(v.z); b.w = f2bf(v.w);
  ((ushort4*)xb)[i] = b;
}

// ============ CSR kernels ============
__global__ void zero4_k(int* p, int n) {
  int i = blockIdx.x * 256 + threadIdx.x;
  if (i < n) p[i] = 0;
}
__global__ void hist4_k(const int* d0, const int* d1, const int* d2, const int* d3,
                        int E0, int E1, int E2, int E3, int* cnt, int Nn) {
  const int s = blockIdx.y;
  const int* d = (s == 0) ? d0 : (s == 1) ? d1 : (s == 2) ? d2 : d3;
  const int E = (s == 0) ? E0 : (s == 1) ? E1 : (s == 2) ? E2 : E3;
  int e = blockIdx.x * 256 + threadIdx.x;
  if (e < E) atomicAdd(&cnt[s * Nn + d[e]], 1);
}
__global__ __launch_bounds__(256)
void scan4_k(const int* __restrict__ cnt, int* __restrict__ offs, int* __restrict__ cursor, int Nn)
{
  __shared__ int sums[256];
  const int s = blockIdx.x;
  const int t = threadIdx.x;
  const int* c = cnt + (size_t)s * Nn;
  int* o = offs + (size_t)s * (Nn + 1);
  int* cur = cursor + (size_t)s * Nn;
  const int chunk = (Nn + 255) / 256;
  const int base = t * chunk;
  int sl = 0;
  for (int i = 0; i < chunk; ++i) {
    int idx = base + i;
    if (idx < Nn) sl += c[idx];
  }
  sums[t] = sl;
  __syncthreads();
  for (int off = 1; off < 256; off <<= 1) {
    int val = (t >= off) ? sums[t - off] : 0;
    __syncthreads();
    sums[t] += val;
    __syncthreads();
  }
  int run = (t == 0) ? 0 : sums[t - 1];
  for (int i = 0; i < chunk; ++i) {
    int idx = base + i;
    if (idx < Nn) { o[idx] = run; cur[idx] = run; run += c[idx]; }
  }
  if (t == 255) o[Nn] = run;
}
// emits (eid, src) packed pairs in CSR order
__global__ void scatter4_k(const int* e0p, const int* e1p, const int* e2p, const int* e3p,
                           int E0, int E1, int E2, int E3, int* cursor,
                           int2* p0, int2* p1, int2* p2, int2* p3, int Nn) {
  const int s = blockIdx.y;
  const int* ei = (s == 0) ? e0p : (s == 1) ? e1p : (s == 2) ? e2p : e3p;
  int2* po = (s == 0) ? p0 : (s == 1) ? p1 : (s == 2) ? p2 : p3;
  const int E = (s == 0) ? E0 : (s == 1) ? E1 : (s == 2) ? E2 : E3;
  int e = blockIdx.x * 256 + threadIdx.x;
  if (e < E) {
    int pos = atomicAdd(&cursor[s * Nn + ei[E + e]], 1);
    po[pos] = make_int2(e, ei[e]);
  }
}

// ============ host orchestration ============
extern "C" void kernel_launch(void* const* d_in, const int* in_sizes, int n_in,
                              void* d_out, int out_size, void* d_ws, size_t ws_size,
                              hipStream_t stream)
{
  (void)n_in; (void)ws_size;
  const float* afl = (const float*)d_in[0];
  const float* afr = (const float*)d_in[1];
  const float* eaA[4] = {(const float*)d_in[2], (const float*)d_in[3],
                         (const float*)d_in[4], (const float*)d_in[5]};
  const int* eiA[4] = {(const int*)d_in[6], (const int*)d_in[7],
                       (const int*)d_in[8], (const int*)d_in[9]};
  const float* Wq  = (const float*)d_in[10];
  const float* Wk  = (const float*)d_in[11];
  const float* Wv  = (const float*)d_in[12];
  const float* We  = (const float*)d_in[13];
  const float* Wo  = (const float*)d_in[14];
  const float* fw1 = (const float*)d_in[15];
  const float* fb1 = (const float*)d_in[16];
  const float* fw2 = (const float*)d_in[17];
  const float* fb2 = (const float*)d_in[18];
  const float* hw1 = (const float*)d_in[19];
  const float* hb1 = (const float*)d_in[20];
  const float* hw2 = (const float*)d_in[21];
  const float* hb2 = (const float*)d_in[22];

  const int Nn = in_sizes[0] / 256;
  const int E[4] = {in_sizes[2] / 64, in_sizes[3] / 64, in_sizes[4] / 64, in_sizes[5] / 64};
  const int Mh = out_size / 14;
  const int astart = Nn - Mh;
  float* out = (float*)d_out;

  char* wsp = (char*)d_ws;
  auto alloc = [&](size_t bytes) -> void* {
    void* pp = (void*)wsp;
    wsp += (bytes + 255) & ~(size_t)255;
    return pp;
  };
  float* xl   = (float*)alloc((size_t)Nn * 256 * 4);
  float* xr   = (float*)alloc((size_t)Nn * 256 * 4);
  unsigned short* xlb = (unsigned short*)alloc((size_t)Nn * 256 * 2);
  unsigned short* xrb = (unsigned short*)alloc((size_t)Nn * 256 * 2);
  float* agg  = (float*)alloc((size_t)Nn * 256 * 4);
  unsigned short* qTb  = (unsigned short*)alloc((size_t)Nn * 768 * 2);
  unsigned short* kvb  = (unsigned short*)alloc((size_t)Nn * 512 * 2);
  unsigned short* msgL = (unsigned short*)alloc((size_t)Nn * 512 * 2);
  unsigned short* msgR = (unsigned short*)alloc((size_t)Nn * 512 * 2);
  unsigned short* BTqkvT = (unsigned short*)alloc((size_t)8 * 1280 * 256 * 2);
  unsigned short* BTo    = (unsigned short*)alloc((size_t)4 * 256 * 512 * 2);
  unsigned short* BTf1   = (unsigned short*)alloc((size_t)4 * 512 * 256 * 2);
  unsigned short* BTf2   = (unsigned short*)alloc((size_t)4 * 256 * 512 * 2);
  unsigned short* BTh1   = (unsigned short*)alloc((size_t)256 * 256 * 2);
  int* offs4 = (int*)alloc((size_t)4 * (Nn + 1) * 4);
  int* cnt4  = (int*)alloc((size_t)4 * Nn * 4);
  int* cur4  = (int*)alloc((size_t)4 * Nn * 4);
  int2* pairs[4];
  for (int s = 0; s < 4; ++s) pairs[s] = (int2*)alloc((size_t)E[s] * 8);

  const dim3 B256(256);
  const int wgNodes = (Nn * 64 + 255) / 256;
  int maxE = E[0];
  for (int s = 1; s < 4; ++s) if (E[s] > maxE) maxE = E[s];

  // ---- init x (+bf16 mirrors), CSR pair lists ----
  cvt_x_k<<<dim3((Nn * 64 + 255) / 256), B256, 0, stream>>>(afl, xl, xlb, Nn * 64);
  cvt_x_k<<<dim3((Nn * 64 + 255) / 256), B256, 0, stream>>>(afr, xr, xrb, Nn * 64);
  zero4_k<<<dim3((4 * Nn + 255) / 256), B256, 0, stream>>>(cnt4, 4 * Nn);
  {
    dim3 gh((maxE + 255) / 256, 4);
    hist4_k<<<gh, B256, 0, stream>>>(eiA[0] + E[0], eiA[1] + E[1], eiA[2] + E[2], eiA[3] + E[3],
                                     E[0], E[1], E[2], E[3], cnt4, Nn);
    scan4_k<<<dim3(4), B256, 0, stream>>>(cnt4, offs4, cur4, Nn);
    scatter4_k<<<gh, B256, 0, stream>>>(eiA[0], eiA[1], eiA[2], eiA[3],
                                        E[0], E[1], E[2], E[3], cur4,
                                        pairs[0], pairs[1], pairs[2], pairs[3], Nn);
  }
  // ---- weight conversion ----
  {
    dim3 g8((65536 + 255) / 256, 8);
    tc_k<<<g8, B256, 0, stream>>>(Wq, BTqkvT, 256, 256, 65536, 327680, 0,    256, 0);
    tc_k<<<g8, B256, 0, stream>>>(Wk, BTqkvT, 256, 256, 65536, 327680, 768,  256, 0);
    tc_k<<<g8, B256, 0, stream>>>(Wv, BTqkvT, 256, 256, 65536, 327680, 1024, 256, 0);
    wqe_k<<<dim3(512, 8), B256, 0, stream>>>(BTqkvT, We, 327680);
    dim3 g1((65536 + 255) / 256, 1);
    for (int l = 0; l < 2; ++l) {
      tc_k<<<g1, B256, 0, stream>>>(Wo + (size_t)(l*4+0)*65536, BTo + (size_t)(l*2+0)*131072, 256, 256, 0, 0, 0, 512, 0);
      tc_k<<<g1, B256, 0, stream>>>(Wo + (size_t)(l*4+3)*65536, BTo + (size_t)(l*2+0)*131072, 256, 256, 0, 0, 0, 512, 256);
      tc_k<<<g1, B256, 0, stream>>>(Wo + (size_t)(l*4+1)*65536, BTo + (size_t)(l*2+1)*131072, 256, 256, 0, 0, 0, 512, 0);
      tc_k<<<g1, B256, 0, stream>>>(Wo + (size_t)(l*4+2)*65536, BTo + (size_t)(l*2+1)*131072, 256, 256, 0, 0, 0, 512, 256);
    }
    tc_k<<<dim3((131072 + 255) / 256, 4), B256, 0, stream>>>(fw1, BTf1, 256, 512, 131072, 131072, 0, 256, 0);
    tc_k<<<dim3((131072 + 255) / 256, 4), B256, 0, stream>>>(fw2, BTf2, 512, 256, 131072, 131072, 0, 512, 0);
    tc_k<<<g1, B256, 0, stream>>>(hw1, BTh1, 256, 256, 0, 0, 0, 256, 0);
  }

  auto mfma = [&](const unsigned short* A, int lda, const unsigned short* BT,
                  const float* bias, float* Cf, int Sf, int ldf,
                  unsigned short* Cb1, int S2, int ldb1,
                  unsigned short* Cb2, int ldb2,
                  int M, int N, int K, bool biasf, bool gelu) {
    dim3 g(M / 128, N / 128);
    if (biasf && gelu) gemm_mfma_k<true, true ><<<g, B256, 0, stream>>>(A, lda, BT, bias, Cf, Sf, ldf, Cb1, S2, ldb1, Cb2, ldb2, M, N, K);
    else if (biasf)    gemm_mfma_k<true, false><<<g, B256, 0, stream>>>(A, lda, BT, bias, Cf, Sf, ldf, Cb1, S2, ldb1, Cb2, ldb2, M, N, K);
    else               gemm_mfma_k<false,false><<<g, B256, 0, stream>>>(A, lda, BT, bias, Cf, Sf, ldf, Cb1, S2, ldb1, Cb2, ldb2, M, N, K);
  };

  // attn: weights index i, edge set s, writes msg[...moff]
  auto run_attn = [&](int l, int i, int s, const unsigned short* xqb, const unsigned short* xkb,
                      unsigned short* msg, int moff) {
    const int idx = l * 4 + i;
    const unsigned short* bt = BTqkvT + (size_t)idx * 327680;
    if (xqb == xkb) {
      // one GEMM: cols [0,768)->qTb, [768,1280)->kvb
      mfma(xqb, 256, bt, nullptr, nullptr, 0, 0, qTb, 768, 768, kvb, 512,
           Nn, 1280, 256, false, false);
    } else {
      mfma(xqb, 256, bt, nullptr, nullptr, 0, 0, qTb, 768, 768, nullptr, 0,
           Nn, 768, 256, false, false);
      mfma(xkb, 256, bt + (size_t)768 * 256, nullptr, nullptr, 0, 0, nullptr, 0, 0, kvb, 512,
           Nn, 512, 256, false, false);
    }
    edge_attn_k<<<dim3(wgNodes), B256, 0, stream>>>(offs4 + (size_t)s * (Nn + 1), pairs[s],
                                                    eaA[s], qTb, kvb,
                                                    We + (size_t)idx * 16384, msg, moff, Nn);
  };

  for (int l = 0; l < 2; ++l) {
    run_attn(l, 0, 0, xlb, xlb, msgL, 0);    // ll
    run_attn(l, 3, 3, xlb, xrb, msgL, 256);  // rl (q from xl, kv from xr)
    run_attn(l, 1, 1, xrb, xrb, msgR, 0);    // rr
    run_attn(l, 2, 2, xrb, xlb, msgR, 256);  // lr (q from xr, kv from xl)
    // fused Wo pair GEMMs + add+LN
    mfma(msgL, 512, BTo + (size_t)(l*2+0)*131072, nullptr, agg, 256, 256,
         nullptr, 0, 0, nullptr, 0, Nn, 256, 512, false, false);
    add_ln_k<<<dim3(wgNodes), B256, 0, stream>>>(xl, xlb, agg, Nn);
    mfma(msgR, 512, BTo + (size_t)(l*2+1)*131072, nullptr, agg, 256, 256,
         nullptr, 0, 0, nullptr, 0, Nn, 256, 512, false, false);
    add_ln_k<<<dim3(wgNodes), B256, 0, stream>>>(xr, xrb, agg, Nn);
    // FFN per side
    for (int s2 = 0; s2 < 2; ++s2) {
      float* x = s2 ? xr : xl;
      unsigned short* xb = s2 ? xrb : xlb;
      const int fi = l * 2 + s2;
      mfma(xb, 256, BTf1 + (size_t)fi * 131072, fb1 + (size_t)fi * 512,
           nullptr, 0, 0, kvb, 512, 512, nullptr, 0, Nn, 512, 256, true, true);
      mfma(kvb, 512, BTf2 + (size_t)fi * 131072, fb2 + (size_t)fi * 256,
           agg, 256, 256, nullptr, 0, 0, nullptr, 0, Nn, 256, 512, true, false);
      add_ln_k<<<dim3(wgNodes), B256, 0, stream>>>(x, xb, agg, Nn);
    }
  }
  // heads: gelu(x@hw1+hb1) @ hw2 + hb2
  mfma(xlb + (size_t)astart * 256, 256, BTh1, hb1, agg, 256, 256,
       nullptr, 0, 0, nullptr, 0, Mh, 256, 256, true, true);
  gemm_k<true><<<dim3(Mh / 128, 1), B256, 0, stream>>>(agg, hw2, hb2, out, Mh, 7, 256);
  mfma(xrb + (size_t)astart * 256, 256, BTh1, hb1, agg, 256, 256,
       nullptr, 0, 0, nullptr, 0, Mh, 256, 256, true, true);
  gemm_k<true><<<dim3(Mh / 128, 1), B256, 0, stream>>>(agg, hw2, hb2, out + (size_t)Mh * 7, Mh, 7, 256);
}

// Round 6
// 1299.077 us; speedup vs baseline: 1.6149x; 1.2782x over previous
//
#include <hip/hip_runtime.h>
#include <math.h>

typedef __attribute__((ext_vector_type(8))) short short8;
typedef __attribute__((ext_vector_type(4))) float f32x4;

__device__ __forceinline__ unsigned short f2bf(float f) {
  unsigned u = __builtin_bit_cast(unsigned, f);
  u += 0x7fff + ((u >> 16) & 1);
  return (unsigned short)(u >> 16);
}
__device__ __forceinline__ float bf2f(unsigned short h) {
  unsigned u = ((unsigned)h) << 16;
  return __builtin_bit_cast(float, u);
}
__device__ __forceinline__ float gelu_f(float x) {
  const float c0 = 0.7978845608028654f;
  return 0.5f * x * (1.0f + tanhf(c0 * (x + 0.044715f * x * x * x)));
}

// ===== 2-context bf16 MFMA GEMM (blockIdx.z selects L/R context) =====
// C = A(bf16,[M][lda]) @ BT(bf16,[N][K]); col split: [0,Sf)->f32 Cf (opt ACC),
// [Sf,S2)->bf16 Cb1, [S2,N)->bf16 Cb2.
template<bool ACC, bool BIAS, bool GELU>
__global__ __launch_bounds__(256)
void gemm_mfma2_k(const unsigned short* __restrict__ A0, const unsigned short* __restrict__ A1,
                  int lda,
                  const unsigned short* __restrict__ BT0, const unsigned short* __restrict__ BT1,
                  const float* __restrict__ bias0, const float* __restrict__ bias1,
                  float* __restrict__ Cf0, float* __restrict__ Cf1, int Sf, int ldf,
                  unsigned short* __restrict__ Cb10, unsigned short* __restrict__ Cb11,
                  int S2, int ldb1,
                  unsigned short* __restrict__ Cb20, unsigned short* __restrict__ Cb21, int ldb2,
                  int M, int N, int K)
{
  const int z = blockIdx.z;
  const unsigned short* A  = z ? A1  : A0;
  const unsigned short* BT = z ? BT1 : BT0;
  const float* bias        = z ? bias1 : bias0;
  float* Cf                = z ? Cf1 : Cf0;
  unsigned short* Cb1      = z ? Cb11 : Cb10;
  unsigned short* Cb2      = z ? Cb21 : Cb20;

  __shared__ __align__(16) unsigned short As[128 * 32];
  __shared__ __align__(16) unsigned short Bs[128 * 32];
  const int tid = threadIdx.x;
  const int bm = blockIdx.x * 128, bn = blockIdx.y * 128;
  const int lane = tid & 63, w = tid >> 6;
  const int wr = w >> 1, wc = w & 1;
  const int l15 = lane & 15, kg = lane >> 4;
  const int sr = tid >> 1, kh = tid & 1;
  const unsigned short* ap = A + (size_t)(bm + sr) * lda + kh * 16;
  const unsigned short* bp = BT + (size_t)(bn + sr) * K + kh * 16;
  const int ph0 = ((kh * 2 + 0) + (sr >> 1)) & 3;   // k-slot swizzle (2-way free)
  const int ph1 = ((kh * 2 + 1) + (sr >> 1)) & 3;
  unsigned short* wa0 = As + sr * 32 + ph0 * 8;
  unsigned short* wa1 = As + sr * 32 + ph1 * 8;
  unsigned short* wb0 = Bs + sr * 32 + ph0 * 8;
  unsigned short* wb1 = Bs + sr * 32 + ph1 * 8;

  f32x4 acc[4][4] = {};

  for (int k0 = 0; k0 < K; k0 += 32) {
    uint4 a0 = *(const uint4*)(ap + k0);
    uint4 a1 = *(const uint4*)(ap + k0 + 8);
    uint4 b0 = *(const uint4*)(bp + k0);
    uint4 b1 = *(const uint4*)(bp + k0 + 8);
    *(uint4*)wa0 = a0;
    *(uint4*)wa1 = a1;
    *(uint4*)wb0 = b0;
    *(uint4*)wb1 = b1;
    __syncthreads();
    short8 af[4], bfr[4];
#pragma unroll
    for (int m = 0; m < 4; ++m) {
      int row = wr * 64 + m * 16 + l15;
      int ph = (kg + (row >> 1)) & 3;
      af[m] = *(const short8*)(As + row * 32 + ph * 8);
    }
#pragma unroll
    for (int n = 0; n < 4; ++n) {
      int col = wc * 64 + n * 16 + l15;
      int ph = (kg + (col >> 1)) & 3;
      bfr[n] = *(const short8*)(Bs + col * 32 + ph * 8);
    }
#pragma unroll
    for (int m = 0; m < 4; ++m)
#pragma unroll
      for (int n = 0; n < 4; ++n)
        acc[m][n] = __builtin_amdgcn_mfma_f32_16x16x32_bf16(af[m], bfr[n], acc[m][n], 0, 0, 0);
    __syncthreads();
  }

#pragma unroll
  for (int m = 0; m < 4; ++m) {
#pragma unroll
    for (int n = 0; n < 4; ++n) {
      int col = bn + wc * 64 + n * 16 + l15;
      float bv = BIAS ? bias[col] : 0.f;
      f32x4 v = acc[m][n];
#pragma unroll
      for (int r2 = 0; r2 < 4; ++r2) {
        int row = bm + wr * 64 + m * 16 + kg * 4 + r2;
        float val = v[r2] + bv;
        if (GELU) val = gelu_f(val);
        if (col < Sf) {
          float* p = Cf + (size_t)row * ldf + col;
          if (ACC) val += *p;
          *p = val;
        } else if (col < S2) {
          Cb1[(size_t)row * ldb1 + (col - Sf)] = f2bf(val);
        } else {
          Cb2[(size_t)row * ldb2 + (col - S2)] = f2bf(val);
        }
      }
    }
  }
}

// ===== f32 GEMM, 2-context (tiny N=7 head2) =====
template<bool BIAS>
__global__ __launch_bounds__(256)
void gemm_k2(const float* __restrict__ A0, const float* __restrict__ A1,
             const float* __restrict__ B, const float* __restrict__ bias,
             float* __restrict__ C0, float* __restrict__ C1,
             int M, int N, int K)
{
  const float* A = blockIdx.z ? A1 : A0;
  float* C = blockIdx.z ? C1 : C0;
  __shared__ float As[16][132];
  __shared__ float Bs[16][132];
  const int tid = threadIdx.x;
  const int tx = tid & 15, ty = tid >> 4;
  const int bm = blockIdx.x * 128;
  float acc[8][8];
#pragma unroll
  for (int i = 0; i < 8; ++i)
#pragma unroll
    for (int j = 0; j < 8; ++j) acc[i][j] = 0.f;
  const int ar = tid >> 1;
  const int ac = (tid & 1) * 8;
  const int br = tid >> 4;
  const int bc = (tid & 15) * 8;
  for (int k0 = 0; k0 < K; k0 += 16) {
    {
      float av[8] = {0,0,0,0,0,0,0,0};
      if (bm + ar < M) {
        const float* app = A + (size_t)(bm + ar) * K + (k0 + ac);
        float4 a0 = *(const float4*)app;
        float4 a1 = *(const float4*)(app + 4);
        av[0]=a0.x; av[1]=a0.y; av[2]=a0.z; av[3]=a0.w;
        av[4]=a1.x; av[5]=a1.y; av[6]=a1.z; av[7]=a1.w;
      }
#pragma unroll
      for (int i = 0; i < 8; ++i) As[ac + i][ar] = av[i];
    }
    {
      float bv[8] = {0,0,0,0,0,0,0,0};
      const float* bpp = B + (size_t)(k0 + br) * N + bc;
#pragma unroll
      for (int i = 0; i < 8; ++i) { if (bc + i < N) bv[i] = bpp[i]; }
#pragma unroll
      for (int i = 0; i < 8; ++i) Bs[br][bc + i] = bv[i];
    }
    __syncthreads();
#pragma unroll
    for (int kk = 0; kk < 16; ++kk) {
      float a[8], b[8];
      float4 t0 = *(const float4*)&As[kk][ty * 8];
      float4 t1 = *(const float4*)&As[kk][ty * 8 + 4];
      float4 u0 = *(const float4*)&Bs[kk][tx * 8];
      float4 u1 = *(const float4*)&Bs[kk][tx * 8 + 4];
      a[0]=t0.x;a[1]=t0.y;a[2]=t0.z;a[3]=t0.w;a[4]=t1.x;a[5]=t1.y;a[6]=t1.z;a[7]=t1.w;
      b[0]=u0.x;b[1]=u0.y;b[2]=u0.z;b[3]=u0.w;b[4]=u1.x;b[5]=u1.y;b[6]=u1.z;b[7]=u1.w;
#pragma unroll
      for (int i = 0; i < 8; ++i)
#pragma unroll
        for (int j = 0; j < 8; ++j)
          acc[i][j] = fmaf(a[i], b[j], acc[i][j]);
    }
    __syncthreads();
  }
#pragma unroll
  for (int i = 0; i < 8; ++i) {
    int row = bm + ty * 8 + i;
    if (row >= M) continue;
    int colg = tx * 8;
    float* cp = C + (size_t)row * N + colg;
#pragma unroll
    for (int j = 0; j < 8; ++j) {
      int cc = colg + j;
      if (cc < N) {
        float val = acc[i][j];
        if (BIAS) val += bias[cc];
        cp[j] = val;
      }
    }
  }
}

// ===== transpose+convert: out[(rowOff+n)*totK + kOff + k] = bf16(in[k*N + n]) =====
__global__ void tc_k(const float* __restrict__ in, unsigned short* __restrict__ out,
                     int K, int N, int inStride, int outStride, int rowOff, int totK, int kOff)
{
  const int mat = blockIdx.y;
  const int idx = blockIdx.x * 256 + threadIdx.x;
  if (idx >= N * K) return;
  const int n = idx / K, k = idx - n * K;
  out[(size_t)mat * outStride + (size_t)(rowOff + n) * totK + kOff + k] =
      f2bf(in[(size_t)mat * inStride + (size_t)k * N + n]);
}

// ===== fused T-weight: BTqkvT rows 256..767 = (Wq @ WeBD)^T =====
__global__ __launch_bounds__(256)
void wqe_k(unsigned short* __restrict__ BT, const float* __restrict__ We, int matStride)
{
  const int mat = blockIdx.y;
  const int oc = blockIdx.x;           // 0..511 = head*64 + c
  const int g = oc >> 6, cc = oc & 63;
  const int kin = threadIdx.x;         // 0..255
  const float* wrow = We + (size_t)mat * 16384 + (size_t)cc * 256 + g * 32;
  const unsigned short* bq = BT + (size_t)mat * matStride + (size_t)(g * 32) * 256 + kin;
  float acc = 0.f;
#pragma unroll 8
  for (int d = 0; d < 32; ++d)
    acc += bf2f(bq[(size_t)d * 256]) * wrow[d];
  BT[(size_t)mat * matStride + (size_t)(256 + oc) * 256 + kin] = f2bf(acc);
}

// ===== Wc fold: BTwo[mat][n][256 + h*64+c] = sum_d We[c,h*32+d]*Wo[h*32+d,n] =====
__global__ __launch_bounds__(256)
void wc_k(const float* __restrict__ We, const float* __restrict__ Wo,
          unsigned short* __restrict__ BTwo)
{
  const int mat = blockIdx.y;          // 0..7 = l*4+i
  const int j = blockIdx.x;            // 0..511 = h*64+c
  const int h = j >> 6, c = j & 63;
  const int n = threadIdx.x;           // 0..255
  const float* wep = We + (size_t)mat * 16384 + (size_t)c * 256 + h * 32;
  const float* wop = Wo + (size_t)mat * 65536 + (size_t)(h * 32) * 256 + n;
  float acc = 0.f;
#pragma unroll 8
  for (int d = 0; d < 32; ++d)
    acc += wep[d] * wop[(size_t)d * 256];
  BTwo[(size_t)mat * 196608 + (size_t)n * 768 + 256 + j] = f2bf(acc);
}

// ===== per-dst online-softmax edge aggregation -> attnV(256) + Gn(512) =====
__global__ __launch_bounds__(256)
void edge_attn_k(const int* __restrict__ offs, const int2* __restrict__ pairs,
                 const float* __restrict__ ea, const unsigned short* __restrict__ qTb,
                 const unsigned short* __restrict__ kv,
                 unsigned short* __restrict__ msg, int Nn)
{
  const int wv = (blockIdx.x * blockDim.x + threadIdx.x) >> 6;
  if (wv >= Nn) return;
  const int lane = threadIdx.x & 63;
  const int g = lane >> 3, p = lane & 7;
  const float scale = 0.17677669529663687f;
  const ushort4 qu = *(const ushort4*)(qTb + (size_t)wv * 768 + lane * 4);
  const float qx = bf2f(qu.x), qy = bf2f(qu.y), qz = bf2f(qu.z), qw = bf2f(qu.w);
  const unsigned short* Tp = qTb + (size_t)wv * 768 + 256 + g * 64 + p * 8;
  const ushort4 tu0 = *(const ushort4*)Tp;
  const ushort4 tu1 = *(const ushort4*)(Tp + 4);
  const float Ta0 = bf2f(tu0.x), Ta1 = bf2f(tu0.y), Ta2 = bf2f(tu0.z), Ta3 = bf2f(tu0.w);
  const float Tc0 = bf2f(tu1.x), Tc1 = bf2f(tu1.y), Tc2 = bf2f(tu1.z), Tc3 = bf2f(tu1.w);
  float m = -INFINITY, den = 0.f;
  float ax = 0.f, ay = 0.f, az = 0.f, aw = 0.f;
  float G[8] = {0,0,0,0,0,0,0,0};
  const int e0 = __builtin_amdgcn_readfirstlane(offs[wv]);
  const int e1 = __builtin_amdgcn_readfirstlane(offs[wv + 1]);
  for (int j = e0; j < e1; j += 2) {
    const bool hasB = (j + 1) < e1;
    const int2 prA = pairs[j];
    const int2 prB = hasB ? pairs[j + 1] : prA;
    const float* epA = ea + (size_t)prA.x * 64 + p * 8;
    const float* epB = ea + (size_t)prB.x * 64 + p * 8;
    const unsigned short* kpA = kv + (size_t)prA.y * 512 + lane * 4;
    const unsigned short* kpB = kv + (size_t)prB.y * 512 + lane * 4;
    const float4 eA0 = *(const float4*)epA;
    const float4 eA1 = *(const float4*)(epA + 4);
    const float4 eB0 = *(const float4*)epB;
    const float4 eB1 = *(const float4*)(epB + 4);
    const ushort4 kAu = *(const ushort4*)kpA;
    const ushort4 vAu = *(const ushort4*)(kpA + 256);
    const ushort4 kBu = *(const ushort4*)kpB;
    const ushort4 vBu = *(const ushort4*)(kpB + 256);
    float pA = qx * bf2f(kAu.x) + qy * bf2f(kAu.y) + qz * bf2f(kAu.z) + qw * bf2f(kAu.w);
    pA += eA0.x * Ta0 + eA0.y * Ta1 + eA0.z * Ta2 + eA0.w * Ta3;
    pA += eA1.x * Tc0 + eA1.y * Tc1 + eA1.z * Tc2 + eA1.w * Tc3;
    float pB = qx * bf2f(kBu.x) + qy * bf2f(kBu.y) + qz * bf2f(kBu.z) + qw * bf2f(kBu.w);
    pB += eB0.x * Ta0 + eB0.y * Ta1 + eB0.z * Ta2 + eB0.w * Ta3;
    pB += eB1.x * Tc0 + eB1.y * Tc1 + eB1.z * Tc2 + eB1.w * Tc3;
    pA += __shfl_xor(pA, 1, 64); pA += __shfl_xor(pA, 2, 64); pA += __shfl_xor(pA, 4, 64);
    pB += __shfl_xor(pB, 1, 64); pB += __shfl_xor(pB, 2, 64); pB += __shfl_xor(pB, 4, 64);
    const float sA = pA * scale;
    const float sB = hasB ? pB * scale : -INFINITY;
    const float mn = fmaxf(m, fmaxf(sA, sB));
    const float corr = __expf(m - mn);   // exp(-inf)=0 on first iteration
    const float wA = __expf(sA - mn);
    const float wB = __expf(sB - mn);
    m = mn;
    den = den * corr + wA + wB;
    ax = ax * corr + wA * bf2f(vAu.x) + wB * bf2f(vBu.x);
    ay = ay * corr + wA * bf2f(vAu.y) + wB * bf2f(vBu.y);
    az = az * corr + wA * bf2f(vAu.z) + wB * bf2f(vBu.z);
    aw = aw * corr + wA * bf2f(vAu.w) + wB * bf2f(vBu.w);
    G[0] = G[0] * corr + wA * eA0.x + wB * eB0.x;
    G[1] = G[1] * corr + wA * eA0.y + wB * eB0.y;
    G[2] = G[2] * corr + wA * eA0.z + wB * eB0.z;
    G[3] = G[3] * corr + wA * eA0.w + wB * eB0.w;
    G[4] = G[4] * corr + wA * eA1.x + wB * eB1.x;
    G[5] = G[5] * corr + wA * eA1.y + wB * eB1.y;
    G[6] = G[6] * corr + wA * eA1.z + wB * eB1.z;
    G[7] = G[7] * corr + wA * eA1.w + wB * eB1.w;
  }
  const float inv = 1.f / (den + 1e-9f);
  ushort4 o;
  o.x = f2bf(ax * inv); o.y = f2bf(ay * inv);
  o.z = f2bf(az * inv); o.w = f2bf(aw * inv);
  *(ushort4*)(msg + (size_t)wv * 768 + lane * 4) = o;
  short8 gn;
#pragma unroll
  for (int i = 0; i < 8; ++i) gn[i] = (short)f2bf(G[i] * inv);
  *(short8*)(msg + (size_t)wv * 768 + 256 + g * 64 + p * 8) = gn;
}

// ===== residual add + LayerNorm on bf16 carry (L/R via blockIdx.y) =====
__global__ __launch_bounds__(256)
void add_ln2_k(unsigned short* __restrict__ xbL, const float* __restrict__ addL,
               unsigned short* __restrict__ xbR, const float* __restrict__ addR, int Nn)
{
  unsigned short* xb = blockIdx.y ? xbR : xbL;
  const float* add = blockIdx.y ? addR : addL;
  const int wv = (blockIdx.x * blockDim.x + threadIdx.x) >> 6;
  if (wv >= Nn) return;
  const int lane = threadIdx.x & 63;
  ushort4 xu = *(const ushort4*)(xb + (size_t)wv * 256 + lane * 4);
  float4 av = *(const float4*)(add + (size_t)wv * 256 + lane * 4);
  float4 y;
  y.x = bf2f(xu.x) + av.x; y.y = bf2f(xu.y) + av.y;
  y.z = bf2f(xu.z) + av.z; y.w = bf2f(xu.w) + av.w;
  float s = y.x + y.y + y.z + y.w;
#pragma unroll
  for (int msk = 1; msk < 64; msk <<= 1) s += __shfl_xor(s, msk, 64);
  const float mean = s * (1.f / 256.f);
  float4 d;
  d.x = y.x - mean; d.y = y.y - mean; d.z = y.z - mean; d.w = y.w - mean;
  float sq = d.x*d.x + d.y*d.y + d.z*d.z + d.w*d.w;
#pragma unroll
  for (int msk = 1; msk < 64; msk <<= 1) sq += __shfl_xor(sq, msk, 64);
  const float r = rsqrtf(sq * (1.f / 256.f) + 1e-5f);
  ushort4 ob;
  ob.x = f2bf(d.x * r); ob.y = f2bf(d.y * r);
  ob.z = f2bf(d.z * r); ob.w = f2bf(d.w * r);
  *(ushort4*)(xb + (size_t)wv * 256 + lane * 4) = ob;
}

// ===== init: f32 input -> bf16 carry (L/R via blockIdx.y) =====
__global__ void cvt_x2_k(const float* __restrict__ aL, unsigned short* __restrict__ xbL,
                         const float* __restrict__ aR, unsigned short* __restrict__ xbR, int n4)
{
  const float* a = blockIdx.y ? aR : aL;
  unsigned short* xb = blockIdx.y ? xbR : xbL;
  int i = blockIdx.x * 256 + threadIdx.x;
  if (i >= n4) return;
  float4 v = ((const float4*)a)[i];
  ushort4 b;
  b.x = f2bf(v.x); b.y = f2bf(v.y); b.z = f2bf(v.z); b.w = f2bf(v.w);
  ((ushort4*)xb)[i] = b;
}

// ===== CSR kernels =====
__global__ void zero4_k(int* p, int n) {
  int i = blockIdx.x * 256 + threadIdx.x;
  if (i < n) p[i] = 0;
}
__global__ void hist4_k(const int* d0, const int* d1, const int* d2, const int* d3,
                        int E0, int E1, int E2, int E3, int* cnt, int Nn) {
  const int s = blockIdx.y;
  const int* d = (s == 0) ? d0 : (s == 1) ? d1 : (s == 2) ? d2 : d3;
  const int E = (s == 0) ? E0 : (s == 1) ? E1 : (s == 2) ? E2 : E3;
  int e = blockIdx.x * 256 + threadIdx.x;
  if (e < E) atomicAdd(&cnt[s * Nn + d[e]], 1);
}
__global__ __launch_bounds__(256)
void scan4_k(const int* __restrict__ cnt, int* __restrict__ offs, int* __restrict__ cursor, int Nn)
{
  __shared__ int sums[256];
  const int s = blockIdx.x;
  const int t = threadIdx.x;
  const int* c = cnt + (size_t)s * Nn;
  int* o = offs + (size_t)s * (Nn + 1);
  int* cur = cursor + (size_t)s * Nn;
  const int chunk = (Nn + 255) / 256;
  const int base = t * chunk;
  int sl = 0;
  for (int i = 0; i < chunk; ++i) {
    int idx = base + i;
    if (idx < Nn) sl += c[idx];
  }
  sums[t] = sl;
  __syncthreads();
  for (int off = 1; off < 256; off <<= 1) {
    int val = (t >= off) ? sums[t - off] : 0;
    __syncthreads();
    sums[t] += val;
    __syncthreads();
  }
  int run = (t == 0) ? 0 : sums[t - 1];
  for (int i = 0; i < chunk; ++i) {
    int idx = base + i;
    if (idx < Nn) { o[idx] = run; cur[idx] = run; run += c[idx]; }
  }
  if (t == 255) o[Nn] = run;
}
__global__ void scatter4_k(const int* e0p, const int* e1p, const int* e2p, const int* e3p,
                           int E0, int E1, int E2, int E3, int* cursor,
                           int2* p0, int2* p1, int2* p2, int2* p3, int Nn) {
  const int s = blockIdx.y;
  const int* ei = (s == 0) ? e0p : (s == 1) ? e1p : (s == 2) ? e2p : e3p;
  int2* po = (s == 0) ? p0 : (s == 1) ? p1 : (s == 2) ? p2 : p3;
  const int E = (s == 0) ? E0 : (s == 1) ? E1 : (s == 2) ? E2 : E3;
  int e = blockIdx.x * 256 + threadIdx.x;
  if (e < E) {
    int pos = atomicAdd(&cursor[s * Nn + ei[E + e]], 1);
    po[pos] = make_int2(e, ei[e]);
  }
}

// ===== host orchestration =====
extern "C" void kernel_launch(void* const* d_in, const int* in_sizes, int n_in,
                              void* d_out, int out_size, void* d_ws, size_t ws_size,
                              hipStream_t stream)
{
  (void)n_in; (void)ws_size;
  const float* afl = (const float*)d_in[0];
  const float* afr = (const float*)d_in[1];
  const float* eaA[4] = {(const float*)d_in[2], (const float*)d_in[3],
                         (const float*)d_in[4], (const float*)d_in[5]};
  const int* eiA[4] = {(const int*)d_in[6], (const int*)d_in[7],
                       (const int*)d_in[8], (const int*)d_in[9]};
  const float* Wq  = (const float*)d_in[10];
  const float* Wk  = (const float*)d_in[11];
  const float* Wv  = (const float*)d_in[12];
  const float* We  = (const float*)d_in[13];
  const float* Wo  = (const float*)d_in[14];
  const float* fw1 = (const float*)d_in[15];
  const float* fb1 = (const float*)d_in[16];
  const float* fw2 = (const float*)d_in[17];
  const float* fb2 = (const float*)d_in[18];
  const float* hw1 = (const float*)d_in[19];
  const float* hb1 = (const float*)d_in[20];
  const float* hw2 = (const float*)d_in[21];
  const float* hb2 = (const float*)d_in[22];

  const int Nn = in_sizes[0] / 256;
  const int E[4] = {in_sizes[2] / 64, in_sizes[3] / 64, in_sizes[4] / 64, in_sizes[5] / 64};
  const int Mh = out_size / 14;
  const int astart = Nn - Mh;
  float* out = (float*)d_out;

  // workspace budget: ~225 MB (xb 19 + agg 38 + qTb 57 + kv 38 + msg 57 + weights 11 + csr 7)
  char* wsp = (char*)d_ws;
  auto alloc = [&](size_t bytes) -> void* {
    void* pp = (void*)wsp;
    wsp += (bytes + 255) & ~(size_t)255;
    return pp;
  };
  unsigned short* xlb = (unsigned short*)alloc((size_t)Nn * 256 * 2);
  unsigned short* xrb = (unsigned short*)alloc((size_t)Nn * 256 * 2);
  float* aggL = (float*)alloc((size_t)Nn * 256 * 4);
  float* aggR = (float*)alloc((size_t)Nn * 256 * 4);
  unsigned short* qTbA = (unsigned short*)alloc((size_t)Nn * 768 * 2);
  unsigned short* qTbB = (unsigned short*)alloc((size_t)Nn * 768 * 2);
  unsigned short* kvbA = (unsigned short*)alloc((size_t)Nn * 512 * 2);
  unsigned short* kvbB = (unsigned short*)alloc((size_t)Nn * 512 * 2);
  unsigned short* msgA = (unsigned short*)alloc((size_t)Nn * 768 * 2);
  unsigned short* msgB = (unsigned short*)alloc((size_t)Nn * 768 * 2);
  unsigned short* BTqkvT = (unsigned short*)alloc((size_t)8 * 1280 * 256 * 2);
  unsigned short* BTwo   = (unsigned short*)alloc((size_t)8 * 256 * 768 * 2);
  unsigned short* BTf1   = (unsigned short*)alloc((size_t)4 * 512 * 256 * 2);
  unsigned short* BTf2   = (unsigned short*)alloc((size_t)4 * 256 * 512 * 2);
  unsigned short* BTh1   = (unsigned short*)alloc((size_t)256 * 256 * 2);
  int* offs4 = (int*)alloc((size_t)4 * (Nn + 1) * 4);
  int* cnt4  = (int*)alloc((size_t)4 * Nn * 4);
  int* cur4  = (int*)alloc((size_t)4 * Nn * 4);
  int2* pairs[4];
  for (int s = 0; s < 4; ++s) pairs[s] = (int2*)alloc((size_t)E[s] * 8);

  const dim3 B256(256);
  const int wgNodes = (Nn * 64 + 255) / 256;
  int maxE = E[0];
  for (int s = 1; s < 4; ++s) if (E[s] > maxE) maxE = E[s];

  // ---- init xb, CSR pair lists ----
  cvt_x2_k<<<dim3((Nn * 64 + 255) / 256, 2), B256, 0, stream>>>(afl, xlb, afr, xrb, Nn * 64);
  zero4_k<<<dim3((4 * Nn + 255) / 256), B256, 0, stream>>>(cnt4, 4 * Nn);
  {
    dim3 gh((maxE + 255) / 256, 4);
    hist4_k<<<gh, B256, 0, stream>>>(eiA[0] + E[0], eiA[1] + E[1], eiA[2] + E[2], eiA[3] + E[3],
                                     E[0], E[1], E[2], E[3], cnt4, Nn);
    scan4_k<<<dim3(4), B256, 0, stream>>>(cnt4, offs4, cur4, Nn);
    scatter4_k<<<gh, B256, 0, stream>>>(eiA[0], eiA[1], eiA[2], eiA[3],
                                        E[0], E[1], E[2], E[3], cur4,
                                        pairs[0], pairs[1], pairs[2], pairs[3], Nn);
  }
  // ---- weight conversion ----
  {
    dim3 g8((65536 + 255) / 256, 8);
    tc_k<<<g8, B256, 0, stream>>>(Wq, BTqkvT, 256, 256, 65536, 327680, 0,    256, 0);
    tc_k<<<g8, B256, 0, stream>>>(Wk, BTqkvT, 256, 256, 65536, 327680, 768,  256, 0);
    tc_k<<<g8, B256, 0, stream>>>(Wv, BTqkvT, 256, 256, 65536, 327680, 1024, 256, 0);
    wqe_k<<<dim3(512, 8), B256, 0, stream>>>(BTqkvT, We, 327680);
    tc_k<<<g8, B256, 0, stream>>>(Wo, BTwo, 256, 256, 65536, 196608, 0, 768, 0);
    wc_k<<<dim3(512, 8), B256, 0, stream>>>(We, Wo, BTwo);
    tc_k<<<dim3((131072 + 255) / 256, 4), B256, 0, stream>>>(fw1, BTf1, 256, 512, 131072, 131072, 0, 256, 0);
    tc_k<<<dim3((131072 + 255) / 256, 4), B256, 0, stream>>>(fw2, BTf2, 512, 256, 131072, 131072, 0, 512, 0);
    tc_k<<<dim3((65536 + 255) / 256, 1), B256, 0, stream>>>(hw1, BTh1, 256, 256, 0, 0, 0, 256, 0);
  }

  auto mfma2 = [&](const unsigned short* A0, const unsigned short* A1, int lda,
                   const unsigned short* BT0, const unsigned short* BT1,
                   const float* bias0, const float* bias1,
                   float* Cf0, float* Cf1, int Sf, int ldf,
                   unsigned short* Cb10, unsigned short* Cb11, int S2, int ldb1,
                   unsigned short* Cb20, unsigned short* Cb21, int ldb2,
                   int M, int N, int K, bool accf, bool biasf, bool gelu) {
    dim3 g(M / 128, N / 128, 2);
    if (accf)
      gemm_mfma2_k<true, false, false><<<g, B256, 0, stream>>>(A0, A1, lda, BT0, BT1, bias0, bias1,
          Cf0, Cf1, Sf, ldf, Cb10, Cb11, S2, ldb1, Cb20, Cb21, ldb2, M, N, K);
    else if (biasf && gelu)
      gemm_mfma2_k<false, true, true ><<<g, B256, 0, stream>>>(A0, A1, lda, BT0, BT1, bias0, bias1,
          Cf0, Cf1, Sf, ldf, Cb10, Cb11, S2, ldb1, Cb20, Cb21, ldb2, M, N, K);
    else if (biasf)
      gemm_mfma2_k<false, true, false><<<g, B256, 0, stream>>>(A0, A1, lda, BT0, BT1, bias0, bias1,
          Cf0, Cf1, Sf, ldf, Cb10, Cb11, S2, ldb1, Cb20, Cb21, ldb2, M, N, K);
    else
      gemm_mfma2_k<false, false, false><<<g, B256, 0, stream>>>(A0, A1, lda, BT0, BT1, bias0, bias1,
          Cf0, Cf1, Sf, ldf, Cb10, Cb11, S2, ldb1, Cb20, Cb21, ldb2, M, N, K);
  };
  auto edge = [&](int s, const unsigned short* qTb, const unsigned short* kvb,
                  unsigned short* msg) {
    edge_attn_k<<<dim3(wgNodes), B256, 0, stream>>>(offs4 + (size_t)s * (Nn + 1), pairs[s],
                                                    eaA[s], qTb, kvb, msg, Nn);
  };

  for (int l = 0; l < 2; ++l) {
    const unsigned short* btLL = BTqkvT + (size_t)(l*4+0) * 327680;
    const unsigned short* btRR = BTqkvT + (size_t)(l*4+1) * 327680;
    const unsigned short* btLR = BTqkvT + (size_t)(l*4+2) * 327680;
    const unsigned short* btRL = BTqkvT + (size_t)(l*4+3) * 327680;
    // self QKV+T (z0: ll from xl; z1: rr from xr) -> qTb (768) + kvb (512)
    mfma2(xlb, xrb, 256, btLL, btRR, nullptr, nullptr, nullptr, nullptr, 0, 0,
          qTbA, qTbB, 768, 768, kvbA, kvbB, 512, Nn, 1280, 256, false, false, false);
    edge(0, qTbA, kvbA, msgA);   // ll
    edge(1, qTbB, kvbB, msgB);   // rr
    // Wo #1: agg = msg @ [Wo | Wc]
    mfma2(msgA, msgB, 768, BTwo + (size_t)(l*4+0)*196608, BTwo + (size_t)(l*4+1)*196608,
          nullptr, nullptr, aggL, aggR, 256, 256, nullptr, nullptr, 0, 0, nullptr, nullptr, 0,
          Nn, 256, 768, false, false, false);
    // cross q+T (z0: rl q from xl; z1: lr q from xr)
    mfma2(xlb, xrb, 256, btRL, btLR, nullptr, nullptr, nullptr, nullptr, 0, 0,
          qTbA, qTbB, 768, 768, nullptr, nullptr, 0, Nn, 768, 256, false, false, false);
    // cross kv (z0: rl kv from xr; z1: lr kv from xl)
    mfma2(xrb, xlb, 256, btRL + (size_t)768 * 256, btLR + (size_t)768 * 256,
          nullptr, nullptr, nullptr, nullptr, 0, 0,
          nullptr, nullptr, 0, 0, kvbA, kvbB, 512, Nn, 512, 256, false, false, false);
    edge(3, qTbA, kvbA, msgA);   // rl
    edge(2, qTbB, kvbB, msgB);   // lr
    // Wo #2 (ACC into agg)
    mfma2(msgA, msgB, 768, BTwo + (size_t)(l*4+3)*196608, BTwo + (size_t)(l*4+2)*196608,
          nullptr, nullptr, aggL, aggR, 256, 256, nullptr, nullptr, 0, 0, nullptr, nullptr, 0,
          Nn, 256, 768, true, false, false);
    add_ln2_k<<<dim3(wgNodes, 2), B256, 0, stream>>>(xlb, aggL, xrb, aggR, Nn);
    // FFN (L/R combined)
    const int fL = l * 2 + 0, fR = l * 2 + 1;
    mfma2(xlb, xrb, 256, BTf1 + (size_t)fL*131072, BTf1 + (size_t)fR*131072,
          fb1 + (size_t)fL*512, fb1 + (size_t)fR*512, nullptr, nullptr, 0, 0,
          nullptr, nullptr, 0, 0, kvbA, kvbB, 512, Nn, 512, 256, false, true, true);
    mfma2(kvbA, kvbB, 512, BTf2 + (size_t)fL*131072, BTf2 + (size_t)fR*131072,
          fb2 + (size_t)fL*256, fb2 + (size_t)fR*256, aggL, aggR, 256, 256,
          nullptr, nullptr, 0, 0, nullptr, nullptr, 0, Nn, 256, 512, false, true, false);
    add_ln2_k<<<dim3(wgNodes, 2), B256, 0, stream>>>(xlb, aggL, xrb, aggR, Nn);
  }
  // heads: gelu(x@hw1+hb1) @ hw2 + hb2
  mfma2(xlb + (size_t)astart * 256, xrb + (size_t)astart * 256, 256, BTh1, BTh1,
        hb1, hb1, aggL, aggR, 256, 256, nullptr, nullptr, 0, 0, nullptr, nullptr, 0,
        Mh, 256, 256, false, true, true);
  gemm_k2<true><<<dim3(Mh / 128, 1, 2), B256, 0, stream>>>(aggL, aggR, hw2, hb2,
                                                           out, out + (size_t)Mh * 7, Mh, 7, 256);
}

// Round 7
// 1256.281 us; speedup vs baseline: 1.6699x; 1.0341x over previous
//
#include <hip/hip_runtime.h>
#include <math.h>

typedef __attribute__((ext_vector_type(8))) short short8;
typedef __attribute__((ext_vector_type(4))) float f32x4;

__device__ __forceinline__ unsigned short f2bf(float f) {
  unsigned u = __builtin_bit_cast(unsigned, f);
  u += 0x7fff + ((u >> 16) & 1);
  return (unsigned short)(u >> 16);
}
__device__ __forceinline__ float bf2f(unsigned short h) {
  unsigned u = ((unsigned)h) << 16;
  return __builtin_bit_cast(float, u);
}
__device__ __forceinline__ float gelu_f(float x) {
  const float c0 = 0.7978845608028654f;
  return 0.5f * x * (1.0f + tanhf(c0 * (x + 0.044715f * x * x * x)));
}
// async global->LDS, 16B per lane; LDS dest = wave-uniform base + lane*16
__device__ __forceinline__ void gload16(const unsigned short* g, unsigned short* l) {
  __builtin_amdgcn_global_load_lds(
      (const __attribute__((address_space(1))) unsigned int*)g,
      (__attribute__((address_space(3))) unsigned int*)l, 16, 0, 0);
}

// ===== 2-context bf16 MFMA GEMM (blockIdx.z selects L/R context) =====
// C = A(bf16,[M][lda]) @ BT(bf16,[N][K]); col split: [0,Sf)->f32 Cf (opt ACC),
// [Sf,S2)->bf16 Cb1, [S2,N)->bf16 Cb2.  Staging via global_load_lds with
// pre-swizzled global source (LDS image identical to the old reg-staged one).
template<bool ACC, bool BIAS, bool GELU>
__global__ __launch_bounds__(256)
void gemm_mfma2_k(const unsigned short* __restrict__ A0, const unsigned short* __restrict__ A1,
                  int lda,
                  const unsigned short* __restrict__ BT0, const unsigned short* __restrict__ BT1,
                  const float* __restrict__ bias0, const float* __restrict__ bias1,
                  float* __restrict__ Cf0, float* __restrict__ Cf1, int Sf, int ldf,
                  unsigned short* __restrict__ Cb10, unsigned short* __restrict__ Cb11,
                  int S2, int ldb1,
                  unsigned short* __restrict__ Cb20, unsigned short* __restrict__ Cb21, int ldb2,
                  int M, int N, int K)
{
  const int z = blockIdx.z;
  const unsigned short* A  = z ? A1  : A0;
  const unsigned short* BT = z ? BT1 : BT0;
  const float* bias        = z ? bias1 : bias0;
  float* Cf                = z ? Cf1 : Cf0;
  unsigned short* Cb1      = z ? Cb11 : Cb10;
  unsigned short* Cb2      = z ? Cb21 : Cb20;

  __shared__ __align__(16) unsigned short As[128 * 32];
  __shared__ __align__(16) unsigned short Bs[128 * 32];
  const int tid = threadIdx.x;
  const int bm = blockIdx.x * 128, bn = blockIdx.y * 128;
  const int lane = tid & 63, w = tid >> 6;
  const int wr = w >> 1, wc = w & 1;
  const int l15 = lane & 15, kg = lane >> 4;

  // staging: wave w covers LDS rows [w*16, w*16+16) (half 0) and +64 (half 1);
  // lane covers row w*16 + lane/4, phys k-slot = lane&3.
  // phys slot s of row r must hold logical slot L = (s - (r>>1)) & 3.
  const int srow0 = w * 16 + (lane >> 2);
  const int srow1 = 64 + srow0;
  const int sslot = lane & 3;
  const int koff0 = (((sslot - (srow0 >> 1)) & 3)) * 8;
  const int koff1 = (((sslot - (srow1 >> 1)) & 3)) * 8;
  const unsigned short* gA0 = A + (size_t)(bm + srow0) * lda + koff0;
  const unsigned short* gA1 = A + (size_t)(bm + srow1) * lda + koff1;
  const unsigned short* gB0 = BT + (size_t)(bn + srow0) * K + koff0;
  const unsigned short* gB1 = BT + (size_t)(bn + srow1) * K + koff1;
  unsigned short* lA0 = As + w * 512;          // byte off w*1024
  unsigned short* lA1 = As + 2048 + w * 512;
  unsigned short* lB0 = Bs + w * 512;
  unsigned short* lB1 = Bs + 2048 + w * 512;

  f32x4 acc[4][4] = {};

  for (int k0 = 0; k0 < K; k0 += 32) {
    gload16(gA0 + k0, lA0);
    gload16(gA1 + k0, lA1);
    gload16(gB0 + k0, lB0);
    gload16(gB1 + k0, lB1);
    __syncthreads();
    short8 af[4], bfr[4];
#pragma unroll
    for (int m = 0; m < 4; ++m) {
      int row = wr * 64 + m * 16 + l15;
      int ph = (kg + (row >> 1)) & 3;
      af[m] = *(const short8*)(As + row * 32 + ph * 8);
    }
#pragma unroll
    for (int n = 0; n < 4; ++n) {
      int col = wc * 64 + n * 16 + l15;
      int ph = (kg + (col >> 1)) & 3;
      bfr[n] = *(const short8*)(Bs + col * 32 + ph * 8);
    }
#pragma unroll
    for (int m = 0; m < 4; ++m)
#pragma unroll
      for (int n = 0; n < 4; ++n)
        acc[m][n] = __builtin_amdgcn_mfma_f32_16x16x32_bf16(af[m], bfr[n], acc[m][n], 0, 0, 0);
    __syncthreads();
  }

#pragma unroll
  for (int m = 0; m < 4; ++m) {
#pragma unroll
    for (int n = 0; n < 4; ++n) {
      int col = bn + wc * 64 + n * 16 + l15;
      float bv = BIAS ? bias[col] : 0.f;
      f32x4 v = acc[m][n];
#pragma unroll
      for (int r2 = 0; r2 < 4; ++r2) {
        int row = bm + wr * 64 + m * 16 + kg * 4 + r2;
        float val = v[r2] + bv;
        if (GELU) val = gelu_f(val);
        if (col < Sf) {
          float* p = Cf + (size_t)row * ldf + col;
          if (ACC) val += *p;
          *p = val;
        } else if (col < S2) {
          Cb1[(size_t)row * ldb1 + (col - Sf)] = f2bf(val);
        } else {
          Cb2[(size_t)row * ldb2 + (col - S2)] = f2bf(val);
        }
      }
    }
  }
}

// ===== f32 GEMM, 2-context (tiny N=7 head2) =====
template<bool BIAS>
__global__ __launch_bounds__(256)
void gemm_k2(const float* __restrict__ A0, const float* __restrict__ A1,
             const float* __restrict__ B, const float* __restrict__ bias,
             float* __restrict__ C0, float* __restrict__ C1,
             int M, int N, int K)
{
  const float* A = blockIdx.z ? A1 : A0;
  float* C = blockIdx.z ? C1 : C0;
  __shared__ float As[16][132];
  __shared__ float Bs[16][132];
  const int tid = threadIdx.x;
  const int tx = tid & 15, ty = tid >> 4;
  const int bm = blockIdx.x * 128;
  float acc[8][8];
#pragma unroll
  for (int i = 0; i < 8; ++i)
#pragma unroll
    for (int j = 0; j < 8; ++j) acc[i][j] = 0.f;
  const int ar = tid >> 1;
  const int ac = (tid & 1) * 8;
  const int br = tid >> 4;
  const int bc = (tid & 15) * 8;
  for (int k0 = 0; k0 < K; k0 += 16) {
    {
      float av[8] = {0,0,0,0,0,0,0,0};
      if (bm + ar < M) {
        const float* app = A + (size_t)(bm + ar) * K + (k0 + ac);
        float4 a0 = *(const float4*)app;
        float4 a1 = *(const float4*)(app + 4);
        av[0]=a0.x; av[1]=a0.y; av[2]=a0.z; av[3]=a0.w;
        av[4]=a1.x; av[5]=a1.y; av[6]=a1.z; av[7]=a1.w;
      }
#pragma unroll
      for (int i = 0; i < 8; ++i) As[ac + i][ar] = av[i];
    }
    {
      float bv[8] = {0,0,0,0,0,0,0,0};
      const float* bpp = B + (size_t)(k0 + br) * N + bc;
#pragma unroll
      for (int i = 0; i < 8; ++i) { if (bc + i < N) bv[i] = bpp[i]; }
#pragma unroll
      for (int i = 0; i < 8; ++i) Bs[br][bc + i] = bv[i];
    }
    __syncthreads();
#pragma unroll
    for (int kk = 0; kk < 16; ++kk) {
      float a[8], b[8];
      float4 t0 = *(const float4*)&As[kk][ty * 8];
      float4 t1 = *(const float4*)&As[kk][ty * 8 + 4];
      float4 u0 = *(const float4*)&Bs[kk][tx * 8];
      float4 u1 = *(const float4*)&Bs[kk][tx * 8 + 4];
      a[0]=t0.x;a[1]=t0.y;a[2]=t0.z;a[3]=t0.w;a[4]=t1.x;a[5]=t1.y;a[6]=t1.z;a[7]=t1.w;
      b[0]=u0.x;b[1]=u0.y;b[2]=u0.z;b[3]=u0.w;b[4]=u1.x;b[5]=u1.y;b[6]=u1.z;b[7]=u1.w;
#pragma unroll
      for (int i = 0; i < 8; ++i)
#pragma unroll
        for (int j = 0; j < 8; ++j)
          acc[i][j] = fmaf(a[i], b[j], acc[i][j]);
    }
    __syncthreads();
  }
#pragma unroll
  for (int i = 0; i < 8; ++i) {
    int row = bm + ty * 8 + i;
    if (row >= M) continue;
    int colg = tx * 8;
    float* cp = C + (size_t)row * N + colg;
#pragma unroll
    for (int j = 0; j < 8; ++j) {
      int cc = colg + j;
      if (cc < N) {
        float val = acc[i][j];
        if (BIAS) val += bias[cc];
        cp[j] = val;
      }
    }
  }
}

// ===== transpose+convert: out[(rowOff+n)*totK + kOff + k] = bf16(in[k*N + n]) =====
__global__ void tc_k(const float* __restrict__ in, unsigned short* __restrict__ out,
                     int K, int N, int inStride, int outStride, int rowOff, int totK, int kOff)
{
  const int mat = blockIdx.y;
  const int idx = blockIdx.x * 256 + threadIdx.x;
  if (idx >= N * K) return;
  const int n = idx / K, k = idx - n * K;
  out[(size_t)mat * outStride + (size_t)(rowOff + n) * totK + kOff + k] =
      f2bf(in[(size_t)mat * inStride + (size_t)k * N + n]);
}

// ===== fused T-weight: BTqkvT rows 256..767 = (Wq @ WeBD)^T =====
__global__ __launch_bounds__(256)
void wqe_k(unsigned short* __restrict__ BT, const float* __restrict__ We, int matStride)
{
  const int mat = blockIdx.y;
  const int oc = blockIdx.x;           // 0..511 = head*64 + c
  const int g = oc >> 6, cc = oc & 63;
  const int kin = threadIdx.x;         // 0..255
  const float* wrow = We + (size_t)mat * 16384 + (size_t)cc * 256 + g * 32;
  const unsigned short* bq = BT + (size_t)mat * matStride + (size_t)(g * 32) * 256 + kin;
  float acc = 0.f;
#pragma unroll 8
  for (int d = 0; d < 32; ++d)
    acc += bf2f(bq[(size_t)d * 256]) * wrow[d];
  BT[(size_t)mat * matStride + (size_t)(256 + oc) * 256 + kin] = f2bf(acc);
}

// ===== Wc fold: BTwo[mat][n][256 + h*64+c] = sum_d We[c,h*32+d]*Wo[h*32+d,n] =====
__global__ __launch_bounds__(256)
void wc_k(const float* __restrict__ We, const float* __restrict__ Wo,
          unsigned short* __restrict__ BTwo)
{
  const int mat = blockIdx.y;          // 0..7 = l*4+i
  const int j = blockIdx.x;            // 0..511 = h*64+c
  const int h = j >> 6, c = j & 63;
  const int n = threadIdx.x;           // 0..255
  const float* wep = We + (size_t)mat * 16384 + (size_t)c * 256 + h * 32;
  const float* wop = Wo + (size_t)mat * 65536 + (size_t)(h * 32) * 256 + n;
  float acc = 0.f;
#pragma unroll 8
  for (int d = 0; d < 32; ++d)
    acc += wep[d] * wop[(size_t)d * 256];
  BTwo[(size_t)mat * 196608 + (size_t)n * 768 + 256 + j] = f2bf(acc);
}

// ===== per-dst online-softmax edge aggregation =====
// Reads q/T from qTmsg[wv] then overwrites the same row with attnV(256)+Gn(512).
template<bool EABF>
__global__ __launch_bounds__(256)
void edge_attn_k(const int* __restrict__ offs, const int2* __restrict__ pairs,
                 const void* __restrict__ eaP, unsigned short* qTmsg,
                 const unsigned short* __restrict__ kv, int Nn)
{
  const int wv = (blockIdx.x * blockDim.x + threadIdx.x) >> 6;
  if (wv >= Nn) return;
  const int lane = threadIdx.x & 63;
  const int g = lane >> 3, p = lane & 7;
  const float scale = 0.17677669529663687f;
  const ushort4 qu = *(const ushort4*)(qTmsg + (size_t)wv * 768 + lane * 4);
  const float qx = bf2f(qu.x), qy = bf2f(qu.y), qz = bf2f(qu.z), qw = bf2f(qu.w);
  const unsigned short* Tp = qTmsg + (size_t)wv * 768 + 256 + g * 64 + p * 8;
  const ushort4 tu0 = *(const ushort4*)Tp;
  const ushort4 tu1 = *(const ushort4*)(Tp + 4);
  const float Ta0 = bf2f(tu0.x), Ta1 = bf2f(tu0.y), Ta2 = bf2f(tu0.z), Ta3 = bf2f(tu0.w);
  const float Tc0 = bf2f(tu1.x), Tc1 = bf2f(tu1.y), Tc2 = bf2f(tu1.z), Tc3 = bf2f(tu1.w);
  float m = -INFINITY, den = 0.f;
  float ax = 0.f, ay = 0.f, az = 0.f, aw = 0.f;
  float G[8] = {0,0,0,0,0,0,0,0};
  const int e0 = __builtin_amdgcn_readfirstlane(offs[wv]);
  const int e1 = __builtin_amdgcn_readfirstlane(offs[wv + 1]);
  for (int j = e0; j < e1; j += 2) {
    const bool hasB = (j + 1) < e1;
    const int2 prA = pairs[j];
    const int2 prB = hasB ? pairs[j + 1] : prA;
    float eA[8], eB[8];
    if (EABF) {
      const unsigned short* ebp = (const unsigned short*)eaP;
      const short8 eAu = *(const short8*)(ebp + (size_t)prA.x * 64 + p * 8);
      const short8 eBu = *(const short8*)(ebp + (size_t)prB.x * 64 + p * 8);
#pragma unroll
      for (int i = 0; i < 8; ++i) {
        eA[i] = bf2f((unsigned short)eAu[i]);
        eB[i] = bf2f((unsigned short)eBu[i]);
      }
    } else {
      const float* efp = (const float*)eaP;
      const float4 a0 = *(const float4*)(efp + (size_t)prA.x * 64 + p * 8);
      const float4 a1 = *(const float4*)(efp + (size_t)prA.x * 64 + p * 8 + 4);
      const float4 b0 = *(const float4*)(efp + (size_t)prB.x * 64 + p * 8);
      const float4 b1 = *(const float4*)(efp + (size_t)prB.x * 64 + p * 8 + 4);
      eA[0]=a0.x; eA[1]=a0.y; eA[2]=a0.z; eA[3]=a0.w;
      eA[4]=a1.x; eA[5]=a1.y; eA[6]=a1.z; eA[7]=a1.w;
      eB[0]=b0.x; eB[1]=b0.y; eB[2]=b0.z; eB[3]=b0.w;
      eB[4]=b1.x; eB[5]=b1.y; eB[6]=b1.z; eB[7]=b1.w;
    }
    const unsigned short* kpA = kv + (size_t)prA.y * 512 + lane * 4;
    const unsigned short* kpB = kv + (size_t)prB.y * 512 + lane * 4;
    const ushort4 kAu = *(const ushort4*)kpA;
    const ushort4 vAu = *(const ushort4*)(kpA + 256);
    const ushort4 kBu = *(const ushort4*)kpB;
    const ushort4 vBu = *(const ushort4*)(kpB + 256);
    float pA = qx * bf2f(kAu.x) + qy * bf2f(kAu.y) + qz * bf2f(kAu.z) + qw * bf2f(kAu.w);
    pA += eA[0]*Ta0 + eA[1]*Ta1 + eA[2]*Ta2 + eA[3]*Ta3;
    pA += eA[4]*Tc0 + eA[5]*Tc1 + eA[6]*Tc2 + eA[7]*Tc3;
    float pB = qx * bf2f(kBu.x) + qy * bf2f(kBu.y) + qz * bf2f(kBu.z) + qw * bf2f(kBu.w);
    pB += eB[0]*Ta0 + eB[1]*Ta1 + eB[2]*Ta2 + eB[3]*Ta3;
    pB += eB[4]*Tc0 + eB[5]*Tc1 + eB[6]*Tc2 + eB[7]*Tc3;
    pA += __shfl_xor(pA, 1, 64); pA += __shfl_xor(pA, 2, 64); pA += __shfl_xor(pA, 4, 64);
    pB += __shfl_xor(pB, 1, 64); pB += __shfl_xor(pB, 2, 64); pB += __shfl_xor(pB, 4, 64);
    const float sA = pA * scale;
    const float sB = hasB ? pB * scale : -INFINITY;
    const float mn = fmaxf(m, fmaxf(sA, sB));
    const float corr = __expf(m - mn);   // exp(-inf)=0 on first iteration
    const float wA = __expf(sA - mn);
    const float wB = __expf(sB - mn);
    m = mn;
    den = den * corr + wA + wB;
    ax = ax * corr + wA * bf2f(vAu.x) + wB * bf2f(vBu.x);
    ay = ay * corr + wA * bf2f(vAu.y) + wB * bf2f(vBu.y);
    az = az * corr + wA * bf2f(vAu.z) + wB * bf2f(vBu.z);
    aw = aw * corr + wA * bf2f(vAu.w) + wB * bf2f(vBu.w);
#pragma unroll
    for (int i = 0; i < 8; ++i)
      G[i] = G[i] * corr + wA * eA[i] + wB * eB[i];
  }
  const float inv = 1.f / (den + 1e-9f);
  ushort4 o;
  o.x = f2bf(ax * inv); o.y = f2bf(ay * inv);
  o.z = f2bf(az * inv); o.w = f2bf(aw * inv);
  *(ushort4*)(qTmsg + (size_t)wv * 768 + lane * 4) = o;
  short8 gn;
#pragma unroll
  for (int i = 0; i < 8; ++i) gn[i] = (short)f2bf(G[i] * inv);
  *(short8*)(qTmsg + (size_t)wv * 768 + 256 + g * 64 + p * 8) = gn;
}

// ===== residual add + LayerNorm on bf16 carry (L/R via blockIdx.y) =====
__global__ __launch_bounds__(256)
void add_ln2_k(unsigned short* __restrict__ xbL, const float* __restrict__ addL,
               unsigned short* __restrict__ xbR, const float* __restrict__ addR, int Nn)
{
  unsigned short* xb = blockIdx.y ? xbR : xbL;
  const float* add = blockIdx.y ? addR : addL;
  const int wv = (blockIdx.x * blockDim.x + threadIdx.x) >> 6;
  if (wv >= Nn) return;
  const int lane = threadIdx.x & 63;
  ushort4 xu = *(const ushort4*)(xb + (size_t)wv * 256 + lane * 4);
  float4 av = *(const float4*)(add + (size_t)wv * 256 + lane * 4);
  float4 y;
  y.x = bf2f(xu.x) + av.x; y.y = bf2f(xu.y) + av.y;
  y.z = bf2f(xu.z) + av.z; y.w = bf2f(xu.w) + av.w;
  float s = y.x + y.y + y.z + y.w;
#pragma unroll
  for (int msk = 1; msk < 64; msk <<= 1) s += __shfl_xor(s, msk, 64);
  const float mean = s * (1.f / 256.f);
  float4 d;
  d.x = y.x - mean; d.y = y.y - mean; d.z = y.z - mean; d.w = y.w - mean;
  float sq = d.x*d.x + d.y*d.y + d.z*d.z + d.w*d.w;
#pragma unroll
  for (int msk = 1; msk < 64; msk <<= 1) sq += __shfl_xor(sq, msk, 64);
  const float r = rsqrtf(sq * (1.f / 256.f) + 1e-5f);
  ushort4 ob;
  ob.x = f2bf(d.x * r); ob.y = f2bf(d.y * r);
  ob.z = f2bf(d.z * r); ob.w = f2bf(d.w * r);
  *(ushort4*)(xb + (size_t)wv * 256 + lane * 4) = ob;
}

// ===== init: f32 input -> bf16 carry (L/R via blockIdx.y) =====
__global__ void cvt_x2_k(const float* __restrict__ aL, unsigned short* __restrict__ xbL,
                         const float* __restrict__ aR, unsigned short* __restrict__ xbR, int n4)
{
  const float* a = blockIdx.y ? aR : aL;
  unsigned short* xb = blockIdx.y ? xbR : xbL;
  int i = blockIdx.x * 256 + threadIdx.x;
  if (i >= n4) return;
  float4 v = ((const float4*)a)[i];
  ushort4 b;
  b.x = f2bf(v.x); b.y = f2bf(v.y); b.z = f2bf(v.z); b.w = f2bf(v.w);
  ((ushort4*)xb)[i] = b;
}

// ===== ea f32 -> bf16 for the two big sets =====
__global__ void cvt_ea2_k(const float* __restrict__ s0, const float* __restrict__ s1,
                          unsigned short* __restrict__ d0, unsigned short* __restrict__ d1,
                          int n8a, int n8b)
{
  const float* src = blockIdx.y ? s1 : s0;
  unsigned short* dst = blockIdx.y ? d1 : d0;
  const int n8 = blockIdx.y ? n8b : n8a;
  int i = blockIdx.x * 256 + threadIdx.x;
  if (i >= n8) return;
  float4 a = ((const float4*)src)[i * 2];
  float4 b = ((const float4*)src)[i * 2 + 1];
  short8 o;
  o[0] = (short)f2bf(a.x); o[1] = (short)f2bf(a.y);
  o[2] = (short)f2bf(a.z); o[3] = (short)f2bf(a.w);
  o[4] = (short)f2bf(b.x); o[5] = (short)f2bf(b.y);
  o[6] = (short)f2bf(b.z); o[7] = (short)f2bf(b.w);
  *(short8*)(dst + (size_t)i * 8) = o;
}

// ===== CSR kernels =====
__global__ void zero4_k(int* p, int n) {
  int i = blockIdx.x * 256 + threadIdx.x;
  if (i < n) p[i] = 0;
}
__global__ void hist4_k(const int* d0, const int* d1, const int* d2, const int* d3,
                        int E0, int E1, int E2, int E3, int* cnt, int Nn) {
  const int s = blockIdx.y;
  const int* d = (s == 0) ? d0 : (s == 1) ? d1 : (s == 2) ? d2 : d3;
  const int E = (s == 0) ? E0 : (s == 1) ? E1 : (s == 2) ? E2 : E3;
  int e = blockIdx.x * 256 + threadIdx.x;
  if (e < E) atomicAdd(&cnt[s * Nn + d[e]], 1);
}
__global__ __launch_bounds__(256)
void scan4_k(const int* __restrict__ cnt, int* __restrict__ offs, int* __restrict__ cursor, int Nn)
{
  __shared__ int sums[256];
  const int s = blockIdx.x;
  const int t = threadIdx.x;
  const int* c = cnt + (size_t)s * Nn;
  int* o = offs + (size_t)s * (Nn + 1);
  int* cur = cursor + (size_t)s * Nn;
  const int chunk = (Nn + 255) / 256;
  const int base = t * chunk;
  int sl = 0;
  for (int i = 0; i < chunk; ++i) {
    int idx = base + i;
    if (idx < Nn) sl += c[idx];
  }
  sums[t] = sl;
  __syncthreads();
  for (int off = 1; off < 256; off <<= 1) {
    int val = (t >= off) ? sums[t - off] : 0;
    __syncthreads();
    sums[t] += val;
    __syncthreads();
  }
  int run = (t == 0) ? 0 : sums[t - 1];
  for (int i = 0; i < chunk; ++i) {
    int idx = base + i;
    if (idx < Nn) { o[idx] = run; cur[idx] = run; run += c[idx]; }
  }
  if (t == 255) o[Nn] = run;
}
__global__ void scatter4_k(const int* e0p, const int* e1p, const int* e2p, const int* e3p,
                           int E0, int E1, int E2, int E3, int* cursor,
                           int2* p0, int2* p1, int2* p2, int2* p3, int Nn) {
  const int s = blockIdx.y;
  const int* ei = (s == 0) ? e0p : (s == 1) ? e1p : (s == 2) ? e2p : e3p;
  int2* po = (s == 0) ? p0 : (s == 1) ? p1 : (s == 2) ? p2 : p3;
  const int E = (s == 0) ? E0 : (s == 1) ? E1 : (s == 2) ? E2 : E3;
  int e = blockIdx.x * 256 + threadIdx.x;
  if (e < E) {
    int pos = atomicAdd(&cursor[s * Nn + ei[E + e]], 1);
    po[pos] = make_int2(e, ei[e]);
  }
}

// ===== host orchestration =====
extern "C" void kernel_launch(void* const* d_in, const int* in_sizes, int n_in,
                              void* d_out, int out_size, void* d_ws, size_t ws_size,
                              hipStream_t stream)
{
  (void)n_in; (void)ws_size;
  const float* afl = (const float*)d_in[0];
  const float* afr = (const float*)d_in[1];
  const float* eaA[4] = {(const float*)d_in[2], (const float*)d_in[3],
                         (const float*)d_in[4], (const float*)d_in[5]};
  const int* eiA[4] = {(const int*)d_in[6], (const int*)d_in[7],
                       (const int*)d_in[8], (const int*)d_in[9]};
  const float* Wq  = (const float*)d_in[10];
  const float* Wk  = (const float*)d_in[11];
  const float* Wv  = (const float*)d_in[12];
  const float* We  = (const float*)d_in[13];
  const float* Wo  = (const float*)d_in[14];
  const float* fw1 = (const float*)d_in[15];
  const float* fb1 = (const float*)d_in[16];
  const float* fw2 = (const float*)d_in[17];
  const float* fb2 = (const float*)d_in[18];
  const float* hw1 = (const float*)d_in[19];
  const float* hb1 = (const float*)d_in[20];
  const float* hw2 = (const float*)d_in[21];
  const float* hb2 = (const float*)d_in[22];

  const int Nn = in_sizes[0] / 256;
  const int E[4] = {in_sizes[2] / 64, in_sizes[3] / 64, in_sizes[4] / 64, in_sizes[5] / 64};
  const int Mh = out_size / 14;
  const int astart = Nn - Mh;
  float* out = (float*)d_out;

  // workspace ~244 MB: xb 19 + agg 38 + qTb(=msg) 57 + kv 38 + weights 11
  //                    + eabf(big sets 0,1) 75 + csr 7
  char* wsp = (char*)d_ws;
  auto alloc = [&](size_t bytes) -> void* {
    void* pp = (void*)wsp;
    wsp += (bytes + 255) & ~(size_t)255;
    return pp;
  };
  unsigned short* xlb = (unsigned short*)alloc((size_t)Nn * 256 * 2);
  unsigned short* xrb = (unsigned short*)alloc((size_t)Nn * 256 * 2);
  float* aggL = (float*)alloc((size_t)Nn * 256 * 4);
  float* aggR = (float*)alloc((size_t)Nn * 256 * 4);
  unsigned short* qTbA = (unsigned short*)alloc((size_t)Nn * 768 * 2);  // q+T, then attnV+Gn
  unsigned short* qTbB = (unsigned short*)alloc((size_t)Nn * 768 * 2);
  unsigned short* kvbA = (unsigned short*)alloc((size_t)Nn * 512 * 2);
  unsigned short* kvbB = (unsigned short*)alloc((size_t)Nn * 512 * 2);
  unsigned short* BTqkvT = (unsigned short*)alloc((size_t)8 * 1280 * 256 * 2);
  unsigned short* BTwo   = (unsigned short*)alloc((size_t)8 * 256 * 768 * 2);
  unsigned short* BTf1   = (unsigned short*)alloc((size_t)4 * 512 * 256 * 2);
  unsigned short* BTf2   = (unsigned short*)alloc((size_t)4 * 256 * 512 * 2);
  unsigned short* BTh1   = (unsigned short*)alloc((size_t)256 * 256 * 2);
  unsigned short* eabf0  = (unsigned short*)alloc((size_t)E[0] * 64 * 2);
  unsigned short* eabf1  = (unsigned short*)alloc((size_t)E[1] * 64 * 2);
  int* offs4 = (int*)alloc((size_t)4 * (Nn + 1) * 4);
  int* cnt4  = (int*)alloc((size_t)4 * Nn * 4);
  int* cur4  = (int*)alloc((size_t)4 * Nn * 4);
  int2* pairs[4];
  for (int s = 0; s < 4; ++s) pairs[s] = (int2*)alloc((size_t)E[s] * 8);

  const dim3 B256(256);
  const int wgNodes = (Nn * 64 + 255) / 256;
  int maxE = E[0];
  for (int s = 1; s < 4; ++s) if (E[s] > maxE) maxE = E[s];

  // ---- init xb, big-set ea->bf16, CSR pair lists ----
  cvt_x2_k<<<dim3((Nn * 64 + 255) / 256, 2), B256, 0, stream>>>(afl, xlb, afr, xrb, Nn * 64);
  {
    int n8a = E[0] * 8, n8b = E[1] * 8;
    int gx = ((n8a > n8b ? n8a : n8b) + 255) / 256;
    cvt_ea2_k<<<dim3(gx, 2), B256, 0, stream>>>(eaA[0], eaA[1], eabf0, eabf1, n8a, n8b);
  }
  zero4_k<<<dim3((4 * Nn + 255) / 256), B256, 0, stream>>>(cnt4, 4 * Nn);
  {
    dim3 gh((maxE + 255) / 256, 4);
    hist4_k<<<gh, B256, 0, stream>>>(eiA[0] + E[0], eiA[1] + E[1], eiA[2] + E[2], eiA[3] + E[3],
                                     E[0], E[1], E[2], E[3], cnt4, Nn);
    scan4_k<<<dim3(4), B256, 0, stream>>>(cnt4, offs4, cur4, Nn);
    scatter4_k<<<gh, B256, 0, stream>>>(eiA[0], eiA[1], eiA[2], eiA[3],
                                        E[0], E[1], E[2], E[3], cur4,
                                        pairs[0], pairs[1], pairs[2], pairs[3], Nn);
  }
  // ---- weight conversion ----
  {
    dim3 g8((65536 + 255) / 256, 8);
    tc_k<<<g8, B256, 0, stream>>>(Wq, BTqkvT, 256, 256, 65536, 327680, 0,    256, 0);
    tc_k<<<g8, B256, 0, stream>>>(Wk, BTqkvT, 256, 256, 65536, 327680, 768,  256, 0);
    tc_k<<<g8, B256, 0, stream>>>(Wv, BTqkvT, 256, 256, 65536, 327680, 1024, 256, 0);
    wqe_k<<<dim3(512, 8), B256, 0, stream>>>(BTqkvT, We, 327680);
    tc_k<<<g8, B256, 0, stream>>>(Wo, BTwo, 256, 256, 65536, 196608, 0, 768, 0);
    wc_k<<<dim3(512, 8), B256, 0, stream>>>(We, Wo, BTwo);
    tc_k<<<dim3((131072 + 255) / 256, 4), B256, 0, stream>>>(fw1, BTf1, 256, 512, 131072, 131072, 0, 256, 0);
    tc_k<<<dim3((131072 + 255) / 256, 4), B256, 0, stream>>>(fw2, BTf2, 512, 256, 131072, 131072, 0, 512, 0);
    tc_k<<<dim3((65536 + 255) / 256, 1), B256, 0, stream>>>(hw1, BTh1, 256, 256, 0, 0, 0, 256, 0);
  }

  auto mfma2 = [&](const unsigned short* A0, const unsigned short* A1, int lda,
                   const unsigned short* BT0, const unsigned short* BT1,
                   const float* bias0, const float* bias1,
                   float* Cf0, float* Cf1, int Sf, int ldf,
                   unsigned short* Cb10, unsigned short* Cb11, int S2, int ldb1,
                   unsigned short* Cb20, unsigned short* Cb21, int ldb2,
                   int M, int N, int K, bool accf, bool biasf, bool gelu) {
    dim3 g(M / 128, N / 128, 2);
    if (accf)
      gemm_mfma2_k<true, false, false><<<g, B256, 0, stream>>>(A0, A1, lda, BT0, BT1, bias0, bias1,
          Cf0, Cf1, Sf, ldf, Cb10, Cb11, S2, ldb1, Cb20, Cb21, ldb2, M, N, K);
    else if (biasf && gelu)
      gemm_mfma2_k<false, true, true ><<<g, B256, 0, stream>>>(A0, A1, lda, BT0, BT1, bias0, bias1,
          Cf0, Cf1, Sf, ldf, Cb10, Cb11, S2, ldb1, Cb20, Cb21, ldb2, M, N, K);
    else if (biasf)
      gemm_mfma2_k<false, true, false><<<g, B256, 0, stream>>>(A0, A1, lda, BT0, BT1, bias0, bias1,
          Cf0, Cf1, Sf, ldf, Cb10, Cb11, S2, ldb1, Cb20, Cb21, ldb2, M, N, K);
    else
      gemm_mfma2_k<false, false, false><<<g, B256, 0, stream>>>(A0, A1, lda, BT0, BT1, bias0, bias1,
          Cf0, Cf1, Sf, ldf, Cb10, Cb11, S2, ldb1, Cb20, Cb21, ldb2, M, N, K);
  };
  auto edge = [&](int s, unsigned short* qTmsg, const unsigned short* kvb) {
    if (s <= 1) {
      const unsigned short* eb = s == 0 ? eabf0 : eabf1;
      edge_attn_k<true><<<dim3(wgNodes), B256, 0, stream>>>(
          offs4 + (size_t)s * (Nn + 1), pairs[s], (const void*)eb, qTmsg, kvb, Nn);
    } else {
      edge_attn_k<false><<<dim3(wgNodes), B256, 0, stream>>>(
          offs4 + (size_t)s * (Nn + 1), pairs[s], (const void*)eaA[s], qTmsg, kvb, Nn);
    }
  };

  for (int l = 0; l < 2; ++l) {
    const unsigned short* btLL = BTqkvT + (size_t)(l*4+0) * 327680;
    const unsigned short* btRR = BTqkvT + (size_t)(l*4+1) * 327680;
    const unsigned short* btLR = BTqkvT + (size_t)(l*4+2) * 327680;
    const unsigned short* btRL = BTqkvT + (size_t)(l*4+3) * 327680;
    // self QKV+T (z0: ll from xl; z1: rr from xr) -> qTb (768) + kvb (512)
    mfma2(xlb, xrb, 256, btLL, btRR, nullptr, nullptr, nullptr, nullptr, 0, 0,
          qTbA, qTbB, 768, 768, kvbA, kvbB, 512, Nn, 1280, 256, false, false, false);
    edge(0, qTbA, kvbA);   // ll  (qTbA now holds attnV+Gn)
    edge(1, qTbB, kvbB);   // rr
    // Wo #1: agg = msg @ [Wo | Wc]
    mfma2(qTbA, qTbB, 768, BTwo + (size_t)(l*4+0)*196608, BTwo + (size_t)(l*4+1)*196608,
          nullptr, nullptr, aggL, aggR, 256, 256, nullptr, nullptr, 0, 0, nullptr, nullptr, 0,
          Nn, 256, 768, false, false, false);
    // cross q+T (z0: rl q from xl; z1: lr q from xr)
    mfma2(xlb, xrb, 256, btRL, btLR, nullptr, nullptr, nullptr, nullptr, 0, 0,
          qTbA, qTbB, 768, 768, nullptr, nullptr, 0, Nn, 768, 256, false, false, false);
    // cross kv (z0: rl kv from xr; z1: lr kv from xl)
    mfma2(xrb, xlb, 256, btRL + (size_t)768 * 256, btLR + (size_t)768 * 256,
          nullptr, nullptr, nullptr, nullptr, 0, 0,
          nullptr, nullptr, 0, 0, kvbA, kvbB, 512, Nn, 512, 256, false, false, false);
    edge(3, qTbA, kvbA);   // rl
    edge(2, qTbB, kvbB);   // lr
    // Wo #2 (ACC into agg)
    mfma2(qTbA, qTbB, 768, BTwo + (size_t)(l*4+3)*196608, BTwo + (size_t)(l*4+2)*196608,
          nullptr, nullptr, aggL, aggR, 256, 256, nullptr, nullptr, 0, 0, nullptr, nullptr, 0,
          Nn, 256, 768, true, false, false);
    add_ln2_k<<<dim3(wgNodes, 2), B256, 0, stream>>>(xlb, aggL, xrb, aggR, Nn);
    // FFN (L/R combined)
    const int fL = l * 2 + 0, fR = l * 2 + 1;
    mfma2(xlb, xrb, 256, BTf1 + (size_t)fL*131072, BTf1 + (size_t)fR*131072,
          fb1 + (size_t)fL*512, fb1 + (size_t)fR*512, nullptr, nullptr, 0, 0,
          nullptr, nullptr, 0, 0, kvbA, kvbB, 512, Nn, 512, 256, false, true, true);
    mfma2(kvbA, kvbB, 512, BTf2 + (size_t)fL*131072, BTf2 + (size_t)fR*131072,
          fb2 + (size_t)fL*256, fb2 + (size_t)fR*256, aggL, aggR, 256, 256,
          nullptr, nullptr, 0, 0, nullptr, nullptr, 0, Nn, 256, 512, false, true, false);
    add_ln2_k<<<dim3(wgNodes, 2), B256, 0, stream>>>(xlb, aggL, xrb, aggR, Nn);
  }
  // heads: gelu(x@hw1+hb1) @ hw2 + hb2
  mfma2(xlb + (size_t)astart * 256, xrb + (size_t)astart * 256, 256, BTh1, BTh1,
        hb1, hb1, aggL, aggR, 256, 256, nullptr, nullptr, 0, 0, nullptr, nullptr, 0,
        Mh, 256, 256, false, true, true);
  gemm_k2<true><<<dim3(Mh / 128, 1, 2), B256, 0, stream>>>(aggL, aggR, hw2, hb2,
                                                           out, out + (size_t)Mh * 7, Mh, 7, 256);
}

// Round 8
// 1233.260 us; speedup vs baseline: 1.7011x; 1.0187x over previous
//
#include <hip/hip_runtime.h>
#include <math.h>

typedef __attribute__((ext_vector_type(8))) short short8;
typedef __attribute__((ext_vector_type(4))) float f32x4;

__device__ __forceinline__ unsigned short f2bf(float f) {
  unsigned u = __builtin_bit_cast(unsigned, f);
  u += 0x7fff + ((u >> 16) & 1);
  return (unsigned short)(u >> 16);
}
__device__ __forceinline__ float bf2f(unsigned short h) {
  unsigned u = ((unsigned)h) << 16;
  return __builtin_bit_cast(float, u);
}
__device__ __forceinline__ float gelu_f(float x) {
  const float c0 = 0.7978845608028654f;
  return 0.5f * x * (1.0f + tanhf(c0 * (x + 0.044715f * x * x * x)));
}
// async global->LDS, 16B per lane; LDS dest = wave-uniform base + lane*16
__device__ __forceinline__ void gload16(const unsigned short* g, unsigned short* l) {
  __builtin_amdgcn_global_load_lds(
      (const __attribute__((address_space(1))) unsigned int*)g,
      (__attribute__((address_space(3))) unsigned int*)l, 16, 0, 0);
}

// ===== 2-context bf16 MFMA GEMM, 2-phase double-buffered staging =====
// C = A(bf16,[M][lda]) @ BT(bf16,[N][K]); col split: [0,Sf)->f32 Cf (opt ACC),
// [Sf,S2)->bf16 Cb1, [S2,N)->bf16 Cb2.  global_load_lds staging with
// pre-swizzled global source; next tile staged while current computes.
template<bool ACC, bool BIAS, bool GELU>
__global__ __launch_bounds__(256)
void gemm_mfma2_k(const unsigned short* __restrict__ A0, const unsigned short* __restrict__ A1,
                  int lda,
                  const unsigned short* __restrict__ BT0, const unsigned short* __restrict__ BT1,
                  const float* __restrict__ bias0, const float* __restrict__ bias1,
                  float* __restrict__ Cf0, float* __restrict__ Cf1, int Sf, int ldf,
                  unsigned short* __restrict__ Cb10, unsigned short* __restrict__ Cb11,
                  int S2, int ldb1,
                  unsigned short* __restrict__ Cb20, unsigned short* __restrict__ Cb21, int ldb2,
                  int M, int N, int K)
{
  const int z = blockIdx.z;
  const unsigned short* A  = z ? A1  : A0;
  const unsigned short* BT = z ? BT1 : BT0;
  const float* bias        = z ? bias1 : bias0;
  float* Cf                = z ? Cf1 : Cf0;
  unsigned short* Cb1      = z ? Cb11 : Cb10;
  unsigned short* Cb2      = z ? Cb21 : Cb20;

  __shared__ __align__(16) unsigned short As[2][4096];
  __shared__ __align__(16) unsigned short Bs[2][4096];
  const int tid = threadIdx.x;
  const int bm = blockIdx.x * 128, bn = blockIdx.y * 128;
  const int lane = tid & 63, w = tid >> 6;
  const int wr = w >> 1, wc = w & 1;
  const int l15 = lane & 15, kg = lane >> 4;

  // staging: wave w covers LDS rows [w*16, w*16+16) (half 0) and +64 (half 1);
  // lane covers row w*16 + lane/4, phys k-slot = lane&3.
  // phys slot s of row r holds logical slot (s - (r>>1)) & 3  (inverse of read swizzle).
  const int srow0 = w * 16 + (lane >> 2);
  const int srow1 = 64 + srow0;
  const int sslot = lane & 3;
  const int koff0 = (((sslot - (srow0 >> 1)) & 3)) * 8;
  const int koff1 = (((sslot - (srow1 >> 1)) & 3)) * 8;
  const unsigned short* gA0 = A + (size_t)(bm + srow0) * lda + koff0;
  const unsigned short* gA1 = A + (size_t)(bm + srow1) * lda + koff1;
  const unsigned short* gB0 = BT + (size_t)(bn + srow0) * K + koff0;
  const unsigned short* gB1 = BT + (size_t)(bn + srow1) * K + koff1;
  const int lo0 = w * 512;          // LDS ushort offset within a buffer
  const int lo1 = 2048 + w * 512;

  // read offsets (swizzled), precomputed
  int roffA[4], roffB[4];
#pragma unroll
  for (int m = 0; m < 4; ++m) {
    int row = wr * 64 + m * 16 + l15;
    roffA[m] = row * 32 + ((kg + (row >> 1)) & 3) * 8;
  }
#pragma unroll
  for (int n = 0; n < 4; ++n) {
    int col = wc * 64 + n * 16 + l15;
    roffB[n] = col * 32 + ((kg + (col >> 1)) & 3) * 8;
  }

  // prologue: stage tile 0 into buffer 0
  gload16(gA0, &As[0][lo0]);
  gload16(gA1, &As[0][lo1]);
  gload16(gB0, &Bs[0][lo0]);
  gload16(gB1, &Bs[0][lo1]);
  __syncthreads();

  f32x4 acc[4][4] = {};
  int cur = 0;
  for (int k0 = 0; k0 < K; k0 += 32) {
    if (k0 + 32 < K) {          // stage next tile into the other buffer
      const int nxt = cur ^ 1;
      gload16(gA0 + k0 + 32, &As[nxt][lo0]);
      gload16(gA1 + k0 + 32, &As[nxt][lo1]);
      gload16(gB0 + k0 + 32, &Bs[nxt][lo0]);
      gload16(gB1 + k0 + 32, &Bs[nxt][lo1]);
    }
    short8 af[4], bfr[4];
#pragma unroll
    for (int m = 0; m < 4; ++m) af[m] = *(const short8*)(&As[cur][roffA[m]]);
#pragma unroll
    for (int n = 0; n < 4; ++n) bfr[n] = *(const short8*)(&Bs[cur][roffB[n]]);
#pragma unroll
    for (int m = 0; m < 4; ++m)
#pragma unroll
      for (int n = 0; n < 4; ++n)
        acc[m][n] = __builtin_amdgcn_mfma_f32_16x16x32_bf16(af[m], bfr[n], acc[m][n], 0, 0, 0);
    __syncthreads();            // drains next-tile stages (vmcnt) + lds
    cur ^= 1;
  }

#pragma unroll
  for (int m = 0; m < 4; ++m) {
#pragma unroll
    for (int n = 0; n < 4; ++n) {
      int col = bn + wc * 64 + n * 16 + l15;
      float bv = BIAS ? bias[col] : 0.f;
      f32x4 v = acc[m][n];
#pragma unroll
      for (int r2 = 0; r2 < 4; ++r2) {
        int row = bm + wr * 64 + m * 16 + kg * 4 + r2;
        float val = v[r2] + bv;
        if (GELU) val = gelu_f(val);
        if (col < Sf) {
          float* p = Cf + (size_t)row * ldf + col;
          if (ACC) val += *p;
          *p = val;
        } else if (col < S2) {
          Cb1[(size_t)row * ldb1 + (col - Sf)] = f2bf(val);
        } else {
          Cb2[(size_t)row * ldb2 + (col - S2)] = f2bf(val);
        }
      }
    }
  }
}

// ===== f32 GEMM, 2-context (tiny N=7 head2) =====
template<bool BIAS>
__global__ __launch_bounds__(256)
void gemm_k2(const float* __restrict__ A0, const float* __restrict__ A1,
             const float* __restrict__ B, const float* __restrict__ bias,
             float* __restrict__ C0, float* __restrict__ C1,
             int M, int N, int K)
{
  const float* A = blockIdx.z ? A1 : A0;
  float* C = blockIdx.z ? C1 : C0;
  __shared__ float As[16][132];
  __shared__ float Bs[16][132];
  const int tid = threadIdx.x;
  const int tx = tid & 15, ty = tid >> 4;
  const int bm = blockIdx.x * 128;
  float acc[8][8];
#pragma unroll
  for (int i = 0; i < 8; ++i)
#pragma unroll
    for (int j = 0; j < 8; ++j) acc[i][j] = 0.f;
  const int ar = tid >> 1;
  const int ac = (tid & 1) * 8;
  const int br = tid >> 4;
  const int bc = (tid & 15) * 8;
  for (int k0 = 0; k0 < K; k0 += 16) {
    {
      float av[8] = {0,0,0,0,0,0,0,0};
      if (bm + ar < M) {
        const float* app = A + (size_t)(bm + ar) * K + (k0 + ac);
        float4 a0 = *(const float4*)app;
        float4 a1 = *(const float4*)(app + 4);
        av[0]=a0.x; av[1]=a0.y; av[2]=a0.z; av[3]=a0.w;
        av[4]=a1.x; av[5]=a1.y; av[6]=a1.z; av[7]=a1.w;
      }
#pragma unroll
      for (int i = 0; i < 8; ++i) As[ac + i][ar] = av[i];
    }
    {
      float bv[8] = {0,0,0,0,0,0,0,0};
      const float* bpp = B + (size_t)(k0 + br) * N + bc;
#pragma unroll
      for (int i = 0; i < 8; ++i) { if (bc + i < N) bv[i] = bpp[i]; }
#pragma unroll
      for (int i = 0; i < 8; ++i) Bs[br][bc + i] = bv[i];
    }
    __syncthreads();
#pragma unroll
    for (int kk = 0; kk < 16; ++kk) {
      float a[8], b[8];
      float4 t0 = *(const float4*)&As[kk][ty * 8];
      float4 t1 = *(const float4*)&As[kk][ty * 8 + 4];
      float4 u0 = *(const float4*)&Bs[kk][tx * 8];
      float4 u1 = *(const float4*)&Bs[kk][tx * 8 + 4];
      a[0]=t0.x;a[1]=t0.y;a[2]=t0.z;a[3]=t0.w;a[4]=t1.x;a[5]=t1.y;a[6]=t1.z;a[7]=t1.w;
      b[0]=u0.x;b[1]=u0.y;b[2]=u0.z;b[3]=u0.w;b[4]=u1.x;b[5]=u1.y;b[6]=u1.z;b[7]=u1.w;
#pragma unroll
      for (int i = 0; i < 8; ++i)
#pragma unroll
        for (int j = 0; j < 8; ++j)
          acc[i][j] = fmaf(a[i], b[j], acc[i][j]);
    }
    __syncthreads();
  }
#pragma unroll
  for (int i = 0; i < 8; ++i) {
    int row = bm + ty * 8 + i;
    if (row >= M) continue;
    int colg = tx * 8;
    float* cp = C + (size_t)row * N + colg;
#pragma unroll
    for (int j = 0; j < 8; ++j) {
      int cc = colg + j;
      if (cc < N) {
        float val = acc[i][j];
        if (BIAS) val += bias[cc];
        cp[j] = val;
      }
    }
  }
}

// ===== transpose+convert: out[(rowOff+n)*totK + kOff + k] = bf16(in[k*N + n]) =====
__global__ void tc_k(const float* __restrict__ in, unsigned short* __restrict__ out,
                     int K, int N, int inStride, int outStride, int rowOff, int totK, int kOff)
{
  const int mat = blockIdx.y;
  const int idx = blockIdx.x * 256 + threadIdx.x;
  if (idx >= N * K) return;
  const int n = idx / K, k = idx - n * K;
  out[(size_t)mat * outStride + (size_t)(rowOff + n) * totK + kOff + k] =
      f2bf(in[(size_t)mat * inStride + (size_t)k * N + n]);
}

// ===== QKV transpose+convert, 3 sources via blockIdx.z =====
__global__ void tc_qkv_k(const float* __restrict__ Wq, const float* __restrict__ Wk,
                         const float* __restrict__ Wv, unsigned short* __restrict__ out)
{
  const int zz = blockIdx.z;
  const float* in = (zz == 0) ? Wq : (zz == 1) ? Wk : Wv;
  const int rowOff = (zz == 0) ? 0 : (zz == 1) ? 768 : 1024;
  const int mat = blockIdx.y;
  const int idx = blockIdx.x * 256 + threadIdx.x;
  const int n = idx >> 8, k = idx & 255;
  out[(size_t)mat * 327680 + (size_t)(rowOff + n) * 256 + k] =
      f2bf(in[(size_t)mat * 65536 + (size_t)k * 256 + n]);
}

// ===== fused T-weight: BTqkvT rows 256..767 = (Wq @ WeBD)^T =====
__global__ __launch_bounds__(256)
void wqe_k(unsigned short* __restrict__ BT, const float* __restrict__ We, int matStride)
{
  const int mat = blockIdx.y;
  const int oc = blockIdx.x;           // 0..511 = head*64 + c
  const int g = oc >> 6, cc = oc & 63;
  const int kin = threadIdx.x;         // 0..255
  const float* wrow = We + (size_t)mat * 16384 + (size_t)cc * 256 + g * 32;
  const unsigned short* bq = BT + (size_t)mat * matStride + (size_t)(g * 32) * 256 + kin;
  float acc = 0.f;
#pragma unroll 8
  for (int d = 0; d < 32; ++d)
    acc += bf2f(bq[(size_t)d * 256]) * wrow[d];
  BT[(size_t)mat * matStride + (size_t)(256 + oc) * 256 + kin] = f2bf(acc);
}

// ===== Wc fold: BTwo[mat][n][256 + h*64+c] = sum_d We[c,h*32+d]*Wo[h*32+d,n] =====
__global__ __launch_bounds__(256)
void wc_k(const float* __restrict__ We, const float* __restrict__ Wo,
          unsigned short* __restrict__ BTwo)
{
  const int mat = blockIdx.y;          // 0..7 = l*4+i
  const int j = blockIdx.x;            // 0..511 = h*64+c
  const int h = j >> 6, c = j & 63;
  const int n = threadIdx.x;           // 0..255
  const float* wep = We + (size_t)mat * 16384 + (size_t)c * 256 + h * 32;
  const float* wop = Wo + (size_t)mat * 65536 + (size_t)(h * 32) * 256 + n;
  float acc = 0.f;
#pragma unroll 8
  for (int d = 0; d < 32; ++d)
    acc += wep[d] * wop[(size_t)d * 256];
  BTwo[(size_t)mat * 196608 + (size_t)n * 768 + 256 + j] = f2bf(acc);
}

// ===== per-dst online-softmax edge aggregation =====
// Reads q/T from qTmsg[wv] then overwrites the same row with attnV(256)+Gn(512).
template<bool EABF>
__global__ __launch_bounds__(256)
void edge_attn_k(const int* __restrict__ offs, const int2* __restrict__ pairs,
                 const void* __restrict__ eaP, unsigned short* qTmsg,
                 const unsigned short* __restrict__ kv, int Nn)
{
  const int wv = (blockIdx.x * blockDim.x + threadIdx.x) >> 6;
  if (wv >= Nn) return;
  const int lane = threadIdx.x & 63;
  const int g = lane >> 3, p = lane & 7;
  const float scale = 0.17677669529663687f;
  const ushort4 qu = *(const ushort4*)(qTmsg + (size_t)wv * 768 + lane * 4);
  const float qx = bf2f(qu.x), qy = bf2f(qu.y), qz = bf2f(qu.z), qw = bf2f(qu.w);
  const unsigned short* Tp = qTmsg + (size_t)wv * 768 + 256 + g * 64 + p * 8;
  const ushort4 tu0 = *(const ushort4*)Tp;
  const ushort4 tu1 = *(const ushort4*)(Tp + 4);
  const float Ta0 = bf2f(tu0.x), Ta1 = bf2f(tu0.y), Ta2 = bf2f(tu0.z), Ta3 = bf2f(tu0.w);
  const float Tc0 = bf2f(tu1.x), Tc1 = bf2f(tu1.y), Tc2 = bf2f(tu1.z), Tc3 = bf2f(tu1.w);
  float m = -INFINITY, den = 0.f;
  float ax = 0.f, ay = 0.f, az = 0.f, aw = 0.f;
  float G[8] = {0,0,0,0,0,0,0,0};
  const int e0 = __builtin_amdgcn_readfirstlane(offs[wv]);
  const int e1 = __builtin_amdgcn_readfirstlane(offs[wv + 1]);
  for (int j = e0; j < e1; j += 2) {
    const bool hasB = (j + 1) < e1;
    const int2 prA = pairs[j];
    const int2 prB = hasB ? pairs[j + 1] : prA;
    float eA[8], eB[8];
    if (EABF) {
      const unsigned short* ebp = (const unsigned short*)eaP;
      const short8 eAu = *(const short8*)(ebp + (size_t)prA.x * 64 + p * 8);
      const short8 eBu = *(const short8*)(ebp + (size_t)prB.x * 64 + p * 8);
#pragma unroll
      for (int i = 0; i < 8; ++i) {
        eA[i] = bf2f((unsigned short)eAu[i]);
        eB[i] = bf2f((unsigned short)eBu[i]);
      }
    } else {
      const float* efp = (const float*)eaP;
      const float4 a0 = *(const float4*)(efp + (size_t)prA.x * 64 + p * 8);
      const float4 a1 = *(const float4*)(efp + (size_t)prA.x * 64 + p * 8 + 4);
      const float4 b0 = *(const float4*)(efp + (size_t)prB.x * 64 + p * 8);
      const float4 b1 = *(const float4*)(efp + (size_t)prB.x * 64 + p * 8 + 4);
      eA[0]=a0.x; eA[1]=a0.y; eA[2]=a0.z; eA[3]=a0.w;
      eA[4]=a1.x; eA[5]=a1.y; eA[6]=a1.z; eA[7]=a1.w;
      eB[0]=b0.x; eB[1]=b0.y; eB[2]=b0.z; eB[3]=b0.w;
      eB[4]=b1.x; eB[5]=b1.y; eB[6]=b1.z; eB[7]=b1.w;
    }
    const unsigned short* kpA = kv + (size_t)prA.y * 512 + lane * 4;
    const unsigned short* kpB = kv + (size_t)prB.y * 512 + lane * 4;
    const ushort4 kAu = *(const ushort4*)kpA;
    const ushort4 vAu = *(const ushort4*)(kpA + 256);
    const ushort4 kBu = *(const ushort4*)kpB;
    const ushort4 vBu = *(const ushort4*)(kpB + 256);
    float pA = qx * bf2f(kAu.x) + qy * bf2f(kAu.y) + qz * bf2f(kAu.z) + qw * bf2f(kAu.w);
    pA += eA[0]*Ta0 + eA[1]*Ta1 + eA[2]*Ta2 + eA[3]*Ta3;
    pA += eA[4]*Tc0 + eA[5]*Tc1 + eA[6]*Tc2 + eA[7]*Tc3;
    float pB = qx * bf2f(kBu.x) + qy * bf2f(kBu.y) + qz * bf2f(kBu.z) + qw * bf2f(kBu.w);
    pB += eB[0]*Ta0 + eB[1]*Ta1 + eB[2]*Ta2 + eB[3]*Ta3;
    pB += eB[4]*Tc0 + eB[5]*Tc1 + eB[6]*Tc2 + eB[7]*Tc3;
    pA += __shfl_xor(pA, 1, 64); pA += __shfl_xor(pA, 2, 64); pA += __shfl_xor(pA, 4, 64);
    pB += __shfl_xor(pB, 1, 64); pB += __shfl_xor(pB, 2, 64); pB += __shfl_xor(pB, 4, 64);
    const float sA = pA * scale;
    const float sB = hasB ? pB * scale : -INFINITY;
    const float mn = fmaxf(m, fmaxf(sA, sB));
    const float corr = __expf(m - mn);   // exp(-inf)=0 on first iteration
    const float wA = __expf(sA - mn);
    const float wB = __expf(sB - mn);
    m = mn;
    den = den * corr + wA + wB;
    ax = ax * corr + wA * bf2f(vAu.x) + wB * bf2f(vBu.x);
    ay = ay * corr + wA * bf2f(vAu.y) + wB * bf2f(vBu.y);
    az = az * corr + wA * bf2f(vAu.z) + wB * bf2f(vBu.z);
    aw = aw * corr + wA * bf2f(vAu.w) + wB * bf2f(vBu.w);
#pragma unroll
    for (int i = 0; i < 8; ++i)
      G[i] = G[i] * corr + wA * eA[i] + wB * eB[i];
  }
  const float inv = 1.f / (den + 1e-9f);
  ushort4 o;
  o.x = f2bf(ax * inv); o.y = f2bf(ay * inv);
  o.z = f2bf(az * inv); o.w = f2bf(aw * inv);
  *(ushort4*)(qTmsg + (size_t)wv * 768 + lane * 4) = o;
  short8 gn;
#pragma unroll
  for (int i = 0; i < 8; ++i) gn[i] = (short)f2bf(G[i] * inv);
  *(short8*)(qTmsg + (size_t)wv * 768 + 256 + g * 64 + p * 8) = gn;
}

// ===== residual add + LayerNorm on bf16 carry (L/R via blockIdx.y) =====
__global__ __launch_bounds__(256)
void add_ln2_k(unsigned short* __restrict__ xbL, const float* __restrict__ addL,
               unsigned short* __restrict__ xbR, const float* __restrict__ addR, int Nn)
{
  unsigned short* xb = blockIdx.y ? xbR : xbL;
  const float* add = blockIdx.y ? addR : addL;
  const int wv = (blockIdx.x * blockDim.x + threadIdx.x) >> 6;
  if (wv >= Nn) return;
  const int lane = threadIdx.x & 63;
  ushort4 xu = *(const ushort4*)(xb + (size_t)wv * 256 + lane * 4);
  float4 av = *(const float4*)(add + (size_t)wv * 256 + lane * 4);
  float4 y;
  y.x = bf2f(xu.x) + av.x; y.y = bf2f(xu.y) + av.y;
  y.z = bf2f(xu.z) + av.z; y.w = bf2f(xu.w) + av.w;
  float s = y.x + y.y + y.z + y.w;
#pragma unroll
  for (int msk = 1; msk < 64; msk <<= 1) s += __shfl_xor(s, msk, 64);
  const float mean = s * (1.f / 256.f);
  float4 d;
  d.x = y.x - mean; d.y = y.y - mean; d.z = y.z - mean; d.w = y.w - mean;
  float sq = d.x*d.x + d.y*d.y + d.z*d.z + d.w*d.w;
#pragma unroll
  for (int msk = 1; msk < 64; msk <<= 1) sq += __shfl_xor(sq, msk, 64);
  const float r = rsqrtf(sq * (1.f / 256.f) + 1e-5f);
  ushort4 ob;
  ob.x = f2bf(d.x * r); ob.y = f2bf(d.y * r);
  ob.z = f2bf(d.z * r); ob.w = f2bf(d.w * r);
  *(ushort4*)(xb + (size_t)wv * 256 + lane * 4) = ob;
}

// ===== init: f32 input -> bf16 carry (L/R via blockIdx.y) =====
__global__ void cvt_x2_k(const float* __restrict__ aL, unsigned short* __restrict__ xbL,
                         const float* __restrict__ aR, unsigned short* __restrict__ xbR, int n4)
{
  const float* a = blockIdx.y ? aR : aL;
  unsigned short* xb = blockIdx.y ? xbR : xbL;
  int i = blockIdx.x * 256 + threadIdx.x;
  if (i >= n4) return;
  float4 v = ((const float4*)a)[i];
  ushort4 b;
  b.x = f2bf(v.x); b.y = f2bf(v.y); b.z = f2bf(v.z); b.w = f2bf(v.w);
  ((ushort4*)xb)[i] = b;
}

// ===== ea f32 -> bf16 for the two big sets =====
__global__ void cvt_ea2_k(const float* __restrict__ s0, const float* __restrict__ s1,
                          unsigned short* __restrict__ d0, unsigned short* __restrict__ d1,
                          int n8a, int n8b)
{
  const float* src = blockIdx.y ? s1 : s0;
  unsigned short* dst = blockIdx.y ? d1 : d0;
  const int n8 = blockIdx.y ? n8b : n8a;
  int i = blockIdx.x * 256 + threadIdx.x;
  if (i >= n8) return;
  float4 a = ((const float4*)src)[i * 2];
  float4 b = ((const float4*)src)[i * 2 + 1];
  short8 o;
  o[0] = (short)f2bf(a.x); o[1] = (short)f2bf(a.y);
  o[2] = (short)f2bf(a.z); o[3] = (short)f2bf(a.w);
  o[4] = (short)f2bf(b.x); o[5] = (short)f2bf(b.y);
  o[6] = (short)f2bf(b.z); o[7] = (short)f2bf(b.w);
  *(short8*)(dst + (size_t)i * 8) = o;
}

// ===== CSR kernels =====
__global__ void zero4_k(int* p, int n) {
  int i = blockIdx.x * 256 + threadIdx.x;
  if (i < n) p[i] = 0;
}
__global__ void hist4_k(const int* d0, const int* d1, const int* d2, const int* d3,
                        int E0, int E1, int E2, int E3, int* cnt, int Nn) {
  const int s = blockIdx.y;
  const int* d = (s == 0) ? d0 : (s == 1) ? d1 : (s == 2) ? d2 : d3;
  const int E = (s == 0) ? E0 : (s == 1) ? E1 : (s == 2) ? E2 : E3;
  int e = blockIdx.x * 256 + threadIdx.x;
  if (e < E) atomicAdd(&cnt[s * Nn + d[e]], 1);
}
__global__ __launch_bounds__(256)
void scan4_k(const int* __restrict__ cnt, int* __restrict__ offs, int* __restrict__ cursor, int Nn)
{
  __shared__ int sums[256];
  const int s = blockIdx.x;
  const int t = threadIdx.x;
  const int* c = cnt + (size_t)s * Nn;
  int* o = offs + (size_t)s * (Nn + 1);
  int* cur = cursor + (size_t)s * Nn;
  const int chunk = (Nn + 255) / 256;
  const int base = t * chunk;
  int sl = 0;
  for (int i = 0; i < chunk; ++i) {
    int idx = base + i;
    if (idx < Nn) sl += c[idx];
  }
  sums[t] = sl;
  __syncthreads();
  for (int off = 1; off < 256; off <<= 1) {
    int val = (t >= off) ? sums[t - off] : 0;
    __syncthreads();
    sums[t] += val;
    __syncthreads();
  }
  int run = (t == 0) ? 0 : sums[t - 1];
  for (int i = 0; i < chunk; ++i) {
    int idx = base + i;
    if (idx < Nn) { o[idx] = run; cur[idx] = run; run += c[idx]; }
  }
  if (t == 255) o[Nn] = run;
}
__global__ void scatter4_k(const int* e0p, const int* e1p, const int* e2p, const int* e3p,
                           int E0, int E1, int E2, int E3, int* cursor,
                           int2* p0, int2* p1, int2* p2, int2* p3, int Nn) {
  const int s = blockIdx.y;
  const int* ei = (s == 0) ? e0p : (s == 1) ? e1p : (s == 2) ? e2p : e3p;
  int2* po = (s == 0) ? p0 : (s == 1) ? p1 : (s == 2) ? p2 : p3;
  const int E = (s == 0) ? E0 : (s == 1) ? E1 : (s == 2) ? E2 : E3;
  int e = blockIdx.x * 256 + threadIdx.x;
  if (e < E) {
    int pos = atomicAdd(&cursor[s * Nn + ei[E + e]], 1);
    po[pos] = make_int2(e, ei[e]);
  }
}

// ===== host orchestration =====
extern "C" void kernel_launch(void* const* d_in, const int* in_sizes, int n_in,
                              void* d_out, int out_size, void* d_ws, size_t ws_size,
                              hipStream_t stream)
{
  (void)n_in; (void)ws_size;
  const float* afl = (const float*)d_in[0];
  const float* afr = (const float*)d_in[1];
  const float* eaA[4] = {(const float*)d_in[2], (const float*)d_in[3],
                         (const float*)d_in[4], (const float*)d_in[5]};
  const int* eiA[4] = {(const int*)d_in[6], (const int*)d_in[7],
                       (const int*)d_in[8], (const int*)d_in[9]};
  const float* Wq  = (const float*)d_in[10];
  const float* Wk  = (const float*)d_in[11];
  const float* Wv  = (const float*)d_in[12];
  const float* We  = (const float*)d_in[13];
  const float* Wo  = (const float*)d_in[14];
  const float* fw1 = (const float*)d_in[15];
  const float* fb1 = (const float*)d_in[16];
  const float* fw2 = (const float*)d_in[17];
  const float* fb2 = (const float*)d_in[18];
  const float* hw1 = (const float*)d_in[19];
  const float* hb1 = (const float*)d_in[20];
  const float* hw2 = (const float*)d_in[21];
  const float* hb2 = (const float*)d_in[22];

  const int Nn = in_sizes[0] / 256;
  const int E[4] = {in_sizes[2] / 64, in_sizes[3] / 64, in_sizes[4] / 64, in_sizes[5] / 64};
  const int Mh = out_size / 14;
  const int astart = Nn - Mh;
  float* out = (float*)d_out;

  // workspace ~244 MB: xb 19 + agg 38 + qTb(=msg) 57 + kv 38 + weights 11
  //                    + eabf(big sets 0,1) 75 + csr 7
  char* wsp = (char*)d_ws;
  auto alloc = [&](size_t bytes) -> void* {
    void* pp = (void*)wsp;
    wsp += (bytes + 255) & ~(size_t)255;
    return pp;
  };
  unsigned short* xlb = (unsigned short*)alloc((size_t)Nn * 256 * 2);
  unsigned short* xrb = (unsigned short*)alloc((size_t)Nn * 256 * 2);
  float* aggL = (float*)alloc((size_t)Nn * 256 * 4);
  float* aggR = (float*)alloc((size_t)Nn * 256 * 4);
  unsigned short* qTbA = (unsigned short*)alloc((size_t)Nn * 768 * 2);  // q+T, then attnV+Gn
  unsigned short* qTbB = (unsigned short*)alloc((size_t)Nn * 768 * 2);
  unsigned short* kvbA = (unsigned short*)alloc((size_t)Nn * 512 * 2);
  unsigned short* kvbB = (unsigned short*)alloc((size_t)Nn * 512 * 2);
  unsigned short* BTqkvT = (unsigned short*)alloc((size_t)8 * 1280 * 256 * 2);
  unsigned short* BTwo   = (unsigned short*)alloc((size_t)8 * 256 * 768 * 2);
  unsigned short* BTf1   = (unsigned short*)alloc((size_t)4 * 512 * 256 * 2);
  unsigned short* BTf2   = (unsigned short*)alloc((size_t)4 * 256 * 512 * 2);
  unsigned short* BTh1   = (unsigned short*)alloc((size_t)256 * 256 * 2);
  unsigned short* eabf0  = (unsigned short*)alloc((size_t)E[0] * 64 * 2);
  unsigned short* eabf1  = (unsigned short*)alloc((size_t)E[1] * 64 * 2);
  int* offs4 = (int*)alloc((size_t)4 * (Nn + 1) * 4);
  int* cnt4  = (int*)alloc((size_t)4 * Nn * 4);
  int* cur4  = (int*)alloc((size_t)4 * Nn * 4);
  int2* pairs[4];
  for (int s = 0; s < 4; ++s) pairs[s] = (int2*)alloc((size_t)E[s] * 8);

  const dim3 B256(256);
  const int wgNodes = (Nn * 64 + 255) / 256;
  int maxE = E[0];
  for (int s = 1; s < 4; ++s) if (E[s] > maxE) maxE = E[s];

  // ---- init xb, big-set ea->bf16, CSR pair lists ----
  cvt_x2_k<<<dim3((Nn * 64 + 255) / 256, 2), B256, 0, stream>>>(afl, xlb, afr, xrb, Nn * 64);
  {
    int n8a = E[0] * 8, n8b = E[1] * 8;
    int gx = ((n8a > n8b ? n8a : n8b) + 255) / 256;
    cvt_ea2_k<<<dim3(gx, 2), B256, 0, stream>>>(eaA[0], eaA[1], eabf0, eabf1, n8a, n8b);
  }
  zero4_k<<<dim3((4 * Nn + 255) / 256), B256, 0, stream>>>(cnt4, 4 * Nn);
  {
    dim3 gh((maxE + 255) / 256, 4);
    hist4_k<<<gh, B256, 0, stream>>>(eiA[0] + E[0], eiA[1] + E[1], eiA[2] + E[2], eiA[3] + E[3],
                                     E[0], E[1], E[2], E[3], cnt4, Nn);
    scan4_k<<<dim3(4), B256, 0, stream>>>(cnt4, offs4, cur4, Nn);
    scatter4_k<<<gh, B256, 0, stream>>>(eiA[0], eiA[1], eiA[2], eiA[3],
                                        E[0], E[1], E[2], E[3], cur4,
                                        pairs[0], pairs[1], pairs[2], pairs[3], Nn);
  }
  // ---- weight conversion ----
  {
    tc_qkv_k<<<dim3(256, 8, 3), B256, 0, stream>>>(Wq, Wk, Wv, BTqkvT);
    wqe_k<<<dim3(512, 8), B256, 0, stream>>>(BTqkvT, We, 327680);
    dim3 g8((65536 + 255) / 256, 8);
    tc_k<<<g8, B256, 0, stream>>>(Wo, BTwo, 256, 256, 65536, 196608, 0, 768, 0);
    wc_k<<<dim3(512, 8), B256, 0, stream>>>(We, Wo, BTwo);
    tc_k<<<dim3((131072 + 255) / 256, 4), B256, 0, stream>>>(fw1, BTf1, 256, 512, 131072, 131072, 0, 256, 0);
    tc_k<<<dim3((131072 + 255) / 256, 4), B256, 0, stream>>>(fw2, BTf2, 512, 256, 131072, 131072, 0, 512, 0);
    tc_k<<<dim3((65536 + 255) / 256, 1), B256, 0, stream>>>(hw1, BTh1, 256, 256, 0, 0, 0, 256, 0);
  }

  auto mfma2 = [&](const unsigned short* A0, const unsigned short* A1, int lda,
                   const unsigned short* BT0, const unsigned short* BT1,
                   const float* bias0, const float* bias1,
                   float* Cf0, float* Cf1, int Sf, int ldf,
                   unsigned short* Cb10, unsigned short* Cb11, int S2, int ldb1,
                   unsigned short* Cb20, unsigned short* Cb21, int ldb2,
                   int M, int N, int K, bool accf, bool biasf, bool gelu) {
    dim3 g(M / 128, N / 128, 2);
    if (accf)
      gemm_mfma2_k<true, false, false><<<g, B256, 0, stream>>>(A0, A1, lda, BT0, BT1, bias0, bias1,
          Cf0, Cf1, Sf, ldf, Cb10, Cb11, S2, ldb1, Cb20, Cb21, ldb2, M, N, K);
    else if (biasf && gelu)
      gemm_mfma2_k<false, true, true ><<<g, B256, 0, stream>>>(A0, A1, lda, BT0, BT1, bias0, bias1,
          Cf0, Cf1, Sf, ldf, Cb10, Cb11, S2, ldb1, Cb20, Cb21, ldb2, M, N, K);
    else if (biasf)
      gemm_mfma2_k<false, true, false><<<g, B256, 0, stream>>>(A0, A1, lda, BT0, BT1, bias0, bias1,
          Cf0, Cf1, Sf, ldf, Cb10, Cb11, S2, ldb1, Cb20, Cb21, ldb2, M, N, K);
    else
      gemm_mfma2_k<false, false, false><<<g, B256, 0, stream>>>(A0, A1, lda, BT0, BT1, bias0, bias1,
          Cf0, Cf1, Sf, ldf, Cb10, Cb11, S2, ldb1, Cb20, Cb21, ldb2, M, N, K);
  };
  auto edge = [&](int s, unsigned short* qTmsg, const unsigned short* kvb) {
    if (s <= 1) {
      const unsigned short* eb = s == 0 ? eabf0 : eabf1;
      edge_attn_k<true><<<dim3(wgNodes), B256, 0, stream>>>(
          offs4 + (size_t)s * (Nn + 1), pairs[s], (const void*)eb, qTmsg, kvb, Nn);
    } else {
      edge_attn_k<false><<<dim3(wgNodes), B256, 0, stream>>>(
          offs4 + (size_t)s * (Nn + 1), pairs[s], (const void*)eaA[s], qTmsg, kvb, Nn);
    }
  };

  for (int l = 0; l < 2; ++l) {
    const unsigned short* btLL = BTqkvT + (size_t)(l*4+0) * 327680;
    const unsigned short* btRR = BTqkvT + (size_t)(l*4+1) * 327680;
    const unsigned short* btLR = BTqkvT + (size_t)(l*4+2) * 327680;
    const unsigned short* btRL = BTqkvT + (size_t)(l*4+3) * 327680;
    // self QKV+T (z0: ll from xl; z1: rr from xr) -> qTb (768) + kvb (512)
    mfma2(xlb, xrb, 256, btLL, btRR, nullptr, nullptr, nullptr, nullptr, 0, 0,
          qTbA, qTbB, 768, 768, kvbA, kvbB, 512, Nn, 1280, 256, false, false, false);
    edge(0, qTbA, kvbA);   // ll  (qTbA now holds attnV+Gn)
    edge(1, qTbB, kvbB);   // rr
    // Wo #1: agg = msg @ [Wo | Wc]
    mfma2(qTbA, qTbB, 768, BTwo + (size_t)(l*4+0)*196608, BTwo + (size_t)(l*4+1)*196608,
          nullptr, nullptr, aggL, aggR, 256, 256, nullptr, nullptr, 0, 0, nullptr, nullptr, 0,
          Nn, 256, 768, false, false, false);
    // cross q+T (z0: rl q from xl; z1: lr q from xr)
    mfma2(xlb, xrb, 256, btRL, btLR, nullptr, nullptr, nullptr, nullptr, 0, 0,
          qTbA, qTbB, 768, 768, nullptr, nullptr, 0, Nn, 768, 256, false, false, false);
    // cross kv (z0: rl kv from xr; z1: lr kv from xl)
    mfma2(xrb, xlb, 256, btRL + (size_t)768 * 256, btLR + (size_t)768 * 256,
          nullptr, nullptr, nullptr, nullptr, 0, 0,
          nullptr, nullptr, 0, 0, kvbA, kvbB, 512, Nn, 512, 256, false, false, false);
    edge(3, qTbA, kvbA);   // rl
    edge(2, qTbB, kvbB);   // lr
    // Wo #2 (ACC into agg)
    mfma2(qTbA, qTbB, 768, BTwo + (size_t)(l*4+3)*196608, BTwo + (size_t)(l*4+2)*196608,
          nullptr, nullptr, aggL, aggR, 256, 256, nullptr, nullptr, 0, 0, nullptr, nullptr, 0,
          Nn, 256, 768, true, false, false);
    add_ln2_k<<<dim3(wgNodes, 2), B256, 0, stream>>>(xlb, aggL, xrb, aggR, Nn);
    // FFN (L/R combined)
    const int fL = l * 2 + 0, fR = l * 2 + 1;
    mfma2(xlb, xrb, 256, BTf1 + (size_t)fL*131072, BTf1 + (size_t)fR*131072,
          fb1 + (size_t)fL*512, fb1 + (size_t)fR*512, nullptr, nullptr, 0, 0,
          nullptr, nullptr, 0, 0, kvbA, kvbB, 512, Nn, 512, 256, false, true, true);
    mfma2(kvbA, kvbB, 512, BTf2 + (size_t)fL*131072, BTf2 + (size_t)fR*131072,
          fb2 + (size_t)fL*256, fb2 + (size_t)fR*256, aggL, aggR, 256, 256,
          nullptr, nullptr, 0, 0, nullptr, nullptr, 0, Nn, 256, 512, false, true, false);
    add_ln2_k<<<dim3(wgNodes, 2), B256, 0, stream>>>(xlb, aggL, xrb, aggR, Nn);
  }
  // heads: gelu(x@hw1+hb1) @ hw2 + hb2
  mfma2(xlb + (size_t)astart * 256, xrb + (size_t)astart * 256, 256, BTh1, BTh1,
        hb1, hb1, aggL, aggR, 256, 256, nullptr, nullptr, 0, 0, nullptr, nullptr, 0,
        Mh, 256, 256, false, true, true);
  gemm_k2<true><<<dim3(Mh / 128, 1, 2), B256, 0, stream>>>(aggL, aggR, hw2, hb2,
                                                           out, out + (size_t)Mh * 7, Mh, 7, 256);
}

// Round 9
// 1162.220 us; speedup vs baseline: 1.8051x; 1.0611x over previous
//
#include <hip/hip_runtime.h>
#include <math.h>

typedef __attribute__((ext_vector_type(8))) short short8;
typedef __attribute__((ext_vector_type(4))) float f32x4;

__device__ __forceinline__ unsigned short f2bf(float f) {
  unsigned u = __builtin_bit_cast(unsigned, f);
  u += 0x7fff + ((u >> 16) & 1);
  return (unsigned short)(u >> 16);
}
__device__ __forceinline__ float bf2f(unsigned short h) {
  unsigned u = ((unsigned)h) << 16;
  return __builtin_bit_cast(float, u);
}
__device__ __forceinline__ float gelu_f(float x) {
  const float c0 = 0.7978845608028654f;
  return 0.5f * x * (1.0f + tanhf(c0 * (x + 0.044715f * x * x * x)));
}
// async global->LDS, 16B per lane; LDS dest = wave-uniform base + lane*16
__device__ __forceinline__ void gload16(const unsigned short* g, unsigned short* l) {
  __builtin_amdgcn_global_load_lds(
      (const __attribute__((address_space(1))) unsigned int*)g,
      (__attribute__((address_space(3))) unsigned int*)l, 16, 0, 0);
}

// ===== 2-context bf16 MFMA GEMM (blockIdx.z = L/R), single-buffer staging =====
// C = A(bf16,[M][lda]) @ BT(bf16,[N][K]); col split: [0,Sf)->f32 Cf,
// [Sf,S2)->bf16 Cb1, [S2,N)->bf16 Cb2.
template<bool BIAS, bool GELU>
__global__ __launch_bounds__(256)
void gemm_mfma2_k(const unsigned short* __restrict__ A0, const unsigned short* __restrict__ A1,
                  int lda,
                  const unsigned short* __restrict__ BT0, const unsigned short* __restrict__ BT1,
                  const float* __restrict__ bias0, const float* __restrict__ bias1,
                  float* __restrict__ Cf0, float* __restrict__ Cf1, int Sf, int ldf,
                  unsigned short* __restrict__ Cb10, unsigned short* __restrict__ Cb11,
                  int S2, int ldb1,
                  unsigned short* __restrict__ Cb20, unsigned short* __restrict__ Cb21, int ldb2,
                  int M, int N, int K)
{
  const int z = blockIdx.z;
  const unsigned short* A  = z ? A1  : A0;
  const unsigned short* BT = z ? BT1 : BT0;
  const float* bias        = z ? bias1 : bias0;
  float* Cf                = z ? Cf1 : Cf0;
  unsigned short* Cb1      = z ? Cb11 : Cb10;
  unsigned short* Cb2      = z ? Cb21 : Cb20;

  __shared__ __align__(16) unsigned short As[128 * 32];
  __shared__ __align__(16) unsigned short Bs[128 * 32];
  const int tid = threadIdx.x;
  const int bm = blockIdx.x * 128, bn = blockIdx.y * 128;
  const int lane = tid & 63, w = tid >> 6;
  const int wr = w >> 1, wc = w & 1;
  const int l15 = lane & 15, kg = lane >> 4;

  // staging: wave w covers LDS rows [w*16,w*16+16) (half 0) and +64 (half 1);
  // phys slot s of row r holds logical slot (s - (r>>1)) & 3 (inverse of read swizzle).
  const int srow0 = w * 16 + (lane >> 2);
  const int srow1 = 64 + srow0;
  const int sslot = lane & 3;
  const int koff0 = (((sslot - (srow0 >> 1)) & 3)) * 8;
  const int koff1 = (((sslot - (srow1 >> 1)) & 3)) * 8;
  const unsigned short* gA0 = A + (size_t)(bm + srow0) * lda + koff0;
  const unsigned short* gA1 = A + (size_t)(bm + srow1) * lda + koff1;
  const unsigned short* gB0 = BT + (size_t)(bn + srow0) * K + koff0;
  const unsigned short* gB1 = BT + (size_t)(bn + srow1) * K + koff1;
  unsigned short* lA0 = As + w * 512;
  unsigned short* lA1 = As + 2048 + w * 512;
  unsigned short* lB0 = Bs + w * 512;
  unsigned short* lB1 = Bs + 2048 + w * 512;

  int roffA[4], roffB[4];
#pragma unroll
  for (int m = 0; m < 4; ++m) {
    int row = wr * 64 + m * 16 + l15;
    roffA[m] = row * 32 + ((kg + (row >> 1)) & 3) * 8;
  }
#pragma unroll
  for (int n = 0; n < 4; ++n) {
    int col = wc * 64 + n * 16 + l15;
    roffB[n] = col * 32 + ((kg + (col >> 1)) & 3) * 8;
  }

  f32x4 acc[4][4] = {};

  for (int k0 = 0; k0 < K; k0 += 32) {
    gload16(gA0 + k0, lA0);
    gload16(gA1 + k0, lA1);
    gload16(gB0 + k0, lB0);
    gload16(gB1 + k0, lB1);
    __syncthreads();
    short8 af[4], bfr[4];
#pragma unroll
    for (int m = 0; m < 4; ++m) af[m] = *(const short8*)(As + roffA[m]);
#pragma unroll
    for (int n = 0; n < 4; ++n) bfr[n] = *(const short8*)(Bs + roffB[n]);
#pragma unroll
    for (int m = 0; m < 4; ++m)
#pragma unroll
      for (int n = 0; n < 4; ++n)
        acc[m][n] = __builtin_amdgcn_mfma_f32_16x16x32_bf16(af[m], bfr[n], acc[m][n], 0, 0, 0);
    __syncthreads();
  }

#pragma unroll
  for (int m = 0; m < 4; ++m) {
#pragma unroll
    for (int n = 0; n < 4; ++n) {
      int col = bn + wc * 64 + n * 16 + l15;
      float bv = BIAS ? bias[col] : 0.f;
      f32x4 v = acc[m][n];
#pragma unroll
      for (int r2 = 0; r2 < 4; ++r2) {
        int row = bm + wr * 64 + m * 16 + kg * 4 + r2;
        float val = v[r2] + bv;
        if (GELU) val = gelu_f(val);
        if (col < Sf) {
          Cf[(size_t)row * ldf + col] = val;
        } else if (col < S2) {
          Cb1[(size_t)row * ldb1 + (col - Sf)] = f2bf(val);
        } else {
          Cb2[(size_t)row * ldb2 + (col - S2)] = f2bf(val);
        }
      }
    }
  }
}

// ===== 4-context bf16 MFMA GEMM (z picks ctx; per-ctx N with early exit) =====
__global__ __launch_bounds__(256)
void gemm_mfma4_k(const unsigned short* __restrict__ Ax0, const unsigned short* __restrict__ Ax1,
                  const unsigned short* __restrict__ Ax2, const unsigned short* __restrict__ Ax3,
                  const unsigned short* __restrict__ Bx0, const unsigned short* __restrict__ Bx1,
                  const unsigned short* __restrict__ Bx2, const unsigned short* __restrict__ Bx3,
                  unsigned short* __restrict__ Cx0, unsigned short* __restrict__ Cx1,
                  unsigned short* __restrict__ Cx2, unsigned short* __restrict__ Cx3,
                  int ldb01, int ldb23, int N01, int N23, int lda, int K, int M)
{
  const int z = blockIdx.z;
  const unsigned short* A; const unsigned short* BT; unsigned short* C;
  int ldb, Nz;
  if (z == 0)      { A = Ax0; BT = Bx0; C = Cx0; ldb = ldb01; Nz = N01; }
  else if (z == 1) { A = Ax1; BT = Bx1; C = Cx1; ldb = ldb01; Nz = N01; }
  else if (z == 2) { A = Ax2; BT = Bx2; C = Cx2; ldb = ldb23; Nz = N23; }
  else             { A = Ax3; BT = Bx3; C = Cx3; ldb = ldb23; Nz = N23; }
  const int bm = blockIdx.x * 128, bn = blockIdx.y * 128;
  if (bn >= Nz) return;

  __shared__ __align__(16) unsigned short As[128 * 32];
  __shared__ __align__(16) unsigned short Bs[128 * 32];
  const int tid = threadIdx.x;
  const int lane = tid & 63, w = tid >> 6;
  const int wr = w >> 1, wc = w & 1;
  const int l15 = lane & 15, kg = lane >> 4;
  const int srow0 = w * 16 + (lane >> 2);
  const int srow1 = 64 + srow0;
  const int sslot = lane & 3;
  const int koff0 = (((sslot - (srow0 >> 1)) & 3)) * 8;
  const int koff1 = (((sslot - (srow1 >> 1)) & 3)) * 8;
  const unsigned short* gA0 = A + (size_t)(bm + srow0) * lda + koff0;
  const unsigned short* gA1 = A + (size_t)(bm + srow1) * lda + koff1;
  const unsigned short* gB0 = BT + (size_t)(bn + srow0) * K + koff0;
  const unsigned short* gB1 = BT + (size_t)(bn + srow1) * K + koff1;
  unsigned short* lA0 = As + w * 512;
  unsigned short* lA1 = As + 2048 + w * 512;
  unsigned short* lB0 = Bs + w * 512;
  unsigned short* lB1 = Bs + 2048 + w * 512;

  int roffA[4], roffB[4];
#pragma unroll
  for (int m = 0; m < 4; ++m) {
    int row = wr * 64 + m * 16 + l15;
    roffA[m] = row * 32 + ((kg + (row >> 1)) & 3) * 8;
  }
#pragma unroll
  for (int n = 0; n < 4; ++n) {
    int col = wc * 64 + n * 16 + l15;
    roffB[n] = col * 32 + ((kg + (col >> 1)) & 3) * 8;
  }

  f32x4 acc[4][4] = {};
  for (int k0 = 0; k0 < K; k0 += 32) {
    gload16(gA0 + k0, lA0);
    gload16(gA1 + k0, lA1);
    gload16(gB0 + k0, lB0);
    gload16(gB1 + k0, lB1);
    __syncthreads();
    short8 af[4], bfr[4];
#pragma unroll
    for (int m = 0; m < 4; ++m) af[m] = *(const short8*)(As + roffA[m]);
#pragma unroll
    for (int n = 0; n < 4; ++n) bfr[n] = *(const short8*)(Bs + roffB[n]);
#pragma unroll
    for (int m = 0; m < 4; ++m)
#pragma unroll
      for (int n = 0; n < 4; ++n)
        acc[m][n] = __builtin_amdgcn_mfma_f32_16x16x32_bf16(af[m], bfr[n], acc[m][n], 0, 0, 0);
    __syncthreads();
  }
#pragma unroll
  for (int m = 0; m < 4; ++m) {
#pragma unroll
    for (int n = 0; n < 4; ++n) {
      int col = bn + wc * 64 + n * 16 + l15;
      f32x4 v = acc[m][n];
#pragma unroll
      for (int r2 = 0; r2 < 4; ++r2) {
        int row = bm + wr * 64 + m * 16 + kg * 4 + r2;
        C[(size_t)row * ldb + col] = f2bf(v[r2]);
      }
    }
  }
}

// ===== f32 GEMM, 2-context (tiny N=7 head2) =====
template<bool BIAS>
__global__ __launch_bounds__(256)
void gemm_k2(const float* __restrict__ A0, const float* __restrict__ A1,
             const float* __restrict__ B, const float* __restrict__ bias,
             float* __restrict__ C0, float* __restrict__ C1,
             int M, int N, int K)
{
  const float* A = blockIdx.z ? A1 : A0;
  float* C = blockIdx.z ? C1 : C0;
  __shared__ float As[16][132];
  __shared__ float Bs[16][132];
  const int tid = threadIdx.x;
  const int tx = tid & 15, ty = tid >> 4;
  const int bm = blockIdx.x * 128;
  float acc[8][8];
#pragma unroll
  for (int i = 0; i < 8; ++i)
#pragma unroll
    for (int j = 0; j < 8; ++j) acc[i][j] = 0.f;
  const int ar = tid >> 1;
  const int ac = (tid & 1) * 8;
  const int br = tid >> 4;
  const int bc = (tid & 15) * 8;
  for (int k0 = 0; k0 < K; k0 += 16) {
    {
      float av[8] = {0,0,0,0,0,0,0,0};
      if (bm + ar < M) {
        const float* app = A + (size_t)(bm + ar) * K + (k0 + ac);
        float4 a0 = *(const float4*)app;
        float4 a1 = *(const float4*)(app + 4);
        av[0]=a0.x; av[1]=a0.y; av[2]=a0.z; av[3]=a0.w;
        av[4]=a1.x; av[5]=a1.y; av[6]=a1.z; av[7]=a1.w;
      }
#pragma unroll
      for (int i = 0; i < 8; ++i) As[ac + i][ar] = av[i];
    }
    {
      float bv[8] = {0,0,0,0,0,0,0,0};
      const float* bpp = B + (size_t)(k0 + br) * N + bc;
#pragma unroll
      for (int i = 0; i < 8; ++i) { if (bc + i < N) bv[i] = bpp[i]; }
#pragma unroll
      for (int i = 0; i < 8; ++i) Bs[br][bc + i] = bv[i];
    }
    __syncthreads();
#pragma unroll
    for (int kk = 0; kk < 16; ++kk) {
      float a[8], b[8];
      float4 t0 = *(const float4*)&As[kk][ty * 8];
      float4 t1 = *(const float4*)&As[kk][ty * 8 + 4];
      float4 u0 = *(const float4*)&Bs[kk][tx * 8];
      float4 u1 = *(const float4*)&Bs[kk][tx * 8 + 4];
      a[0]=t0.x;a[1]=t0.y;a[2]=t0.z;a[3]=t0.w;a[4]=t1.x;a[5]=t1.y;a[6]=t1.z;a[7]=t1.w;
      b[0]=u0.x;b[1]=u0.y;b[2]=u0.z;b[3]=u0.w;b[4]=u1.x;b[5]=u1.y;b[6]=u1.z;b[7]=u1.w;
#pragma unroll
      for (int i = 0; i < 8; ++i)
#pragma unroll
        for (int j = 0; j < 8; ++j)
          acc[i][j] = fmaf(a[i], b[j], acc[i][j]);
    }
    __syncthreads();
  }
#pragma unroll
  for (int i = 0; i < 8; ++i) {
    int row = bm + ty * 8 + i;
    if (row >= M) continue;
    int colg = tx * 8;
    float* cp = C + (size_t)row * N + colg;
#pragma unroll
    for (int j = 0; j < 8; ++j) {
      int cc = colg + j;
      if (cc < N) {
        float val = acc[i][j];
        if (BIAS) val += bias[cc];
        cp[j] = val;
      }
    }
  }
}

// ===== transpose+convert: out[(rowOff+n)*totK + kOff + k] = bf16(in[k*N + n]) =====
__global__ void tc_k(const float* __restrict__ in, unsigned short* __restrict__ out,
                     int K, int N, int inStride, int outStride, int rowOff, int totK, int kOff)
{
  const int mat = blockIdx.y;
  const int idx = blockIdx.x * 256 + threadIdx.x;
  if (idx >= N * K) return;
  const int n = idx / K, k = idx - n * K;
  out[(size_t)mat * outStride + (size_t)(rowOff + n) * totK + kOff + k] =
      f2bf(in[(size_t)mat * inStride + (size_t)k * N + n]);
}

// ===== QKV transpose+convert, 3 sources via blockIdx.z =====
__global__ void tc_qkv_k(const float* __restrict__ Wq, const float* __restrict__ Wk,
                         const float* __restrict__ Wv, unsigned short* __restrict__ out)
{
  const int zz = blockIdx.z;
  const float* in = (zz == 0) ? Wq : (zz == 1) ? Wk : Wv;
  const int rowOff = (zz == 0) ? 0 : (zz == 1) ? 768 : 1024;
  const int mat = blockIdx.y;
  const int idx = blockIdx.x * 256 + threadIdx.x;
  const int n = idx >> 8, k = idx & 255;
  out[(size_t)mat * 327680 + (size_t)(rowOff + n) * 256 + k] =
      f2bf(in[(size_t)mat * 65536 + (size_t)k * 256 + n]);
}

// ===== fused T-weight: BTqkvT rows 256..767 = (Wq @ WeBD)^T =====
__global__ __launch_bounds__(256)
void wqe_k(unsigned short* __restrict__ BT, const float* __restrict__ We, int matStride)
{
  const int mat = blockIdx.y;
  const int oc = blockIdx.x;           // 0..511 = head*64 + c
  const int g = oc >> 6, cc = oc & 63;
  const int kin = threadIdx.x;         // 0..255
  const float* wrow = We + (size_t)mat * 16384 + (size_t)cc * 256 + g * 32;
  const unsigned short* bq = BT + (size_t)mat * matStride + (size_t)(g * 32) * 256 + kin;
  float acc = 0.f;
#pragma unroll 8
  for (int d = 0; d < 32; ++d)
    acc += bf2f(bq[(size_t)d * 256]) * wrow[d];
  BT[(size_t)mat * matStride + (size_t)(256 + oc) * 256 + kin] = f2bf(acc);
}

// ===== fused Wo pack: BTwoF[sl][n][base + k] = Wo[mat][k][n] =====
__global__ void wo_tc_k(const float* __restrict__ Wo, unsigned short* __restrict__ BTwoF)
{
  const int mat = blockIdx.y;          // 0..7 = l*4+i
  const int idx = blockIdx.x * 256 + threadIdx.x;
  const int n = idx >> 8, k = idx & 255;
  const int l = mat >> 2, i = mat & 3;
  const int side = (i == 1 || i == 2) ? 1 : 0;
  const int base = (i >= 2) ? 768 : 0;
  BTwoF[(size_t)(l * 2 + side) * 393216 + (size_t)n * 1536 + base + k] =
      f2bf(Wo[(size_t)mat * 65536 + (size_t)k * 256 + n]);
}

// ===== Wc fold: BTwoF[sl][n][base + 256 + h*64+c] = sum_d We[c,h*32+d]*Wo[h*32+d,n] =====
__global__ __launch_bounds__(256)
void wc_k(const float* __restrict__ We, const float* __restrict__ Wo,
          unsigned short* __restrict__ BTwoF)
{
  const int mat = blockIdx.y;          // 0..7 = l*4+i
  const int j = blockIdx.x;            // 0..511 = h*64+c
  const int h = j >> 6, c = j & 63;
  const int n = threadIdx.x;           // 0..255
  const float* wep = We + (size_t)mat * 16384 + (size_t)c * 256 + h * 32;
  const float* wop = Wo + (size_t)mat * 65536 + (size_t)(h * 32) * 256 + n;
  float acc = 0.f;
#pragma unroll 8
  for (int d = 0; d < 32; ++d)
    acc += wep[d] * wop[(size_t)d * 256];
  const int l = mat >> 2, i = mat & 3;
  const int side = (i == 1 || i == 2) ? 1 : 0;
  const int base = (i >= 2) ? 768 : 0;
  BTwoF[(size_t)(l * 2 + side) * 393216 + (size_t)n * 1536 + base + 256 + j] = f2bf(acc);
}

// ===== per-dst online-softmax edge aggregation, 2 contexts via blockIdx.y =====
// Reads q/T at qTmsg[wv*1536 .. +768), overwrites same region with attnV(256)+Gn(512).
template<bool EABF>
__global__ __launch_bounds__(256)
void edge2_k(const int* __restrict__ o0, const int* __restrict__ o1,
             const int2* __restrict__ p0, const int2* __restrict__ p1,
             const void* __restrict__ e0, const void* __restrict__ e1,
             unsigned short* q0, unsigned short* q1,
             const unsigned short* __restrict__ k0, const unsigned short* __restrict__ k1,
             int Nn)
{
  const int y = blockIdx.y;
  const int* offs = y ? o1 : o0;
  const int2* pairs = y ? p1 : p0;
  const void* eaP = y ? e1 : e0;
  unsigned short* qTmsg = y ? q1 : q0;
  const unsigned short* kv = y ? k1 : k0;
  const int wv = (blockIdx.x * blockDim.x + threadIdx.x) >> 6;
  if (wv >= Nn) return;
  const int lane = threadIdx.x & 63;
  const int g = lane >> 3, p = lane & 7;
  const float scale = 0.17677669529663687f;
  const ushort4 qu = *(const ushort4*)(qTmsg + (size_t)wv * 1536 + lane * 4);
  const float qx = bf2f(qu.x), qy = bf2f(qu.y), qz = bf2f(qu.z), qw = bf2f(qu.w);
  const unsigned short* Tp = qTmsg + (size_t)wv * 1536 + 256 + g * 64 + p * 8;
  const ushort4 tu0 = *(const ushort4*)Tp;
  const ushort4 tu1 = *(const ushort4*)(Tp + 4);
  const float Ta0 = bf2f(tu0.x), Ta1 = bf2f(tu0.y), Ta2 = bf2f(tu0.z), Ta3 = bf2f(tu0.w);
  const float Tc0 = bf2f(tu1.x), Tc1 = bf2f(tu1.y), Tc2 = bf2f(tu1.z), Tc3 = bf2f(tu1.w);
  float m = -INFINITY, den = 0.f;
  float ax = 0.f, ay = 0.f, az = 0.f, aw = 0.f;
  float G[8] = {0,0,0,0,0,0,0,0};
  const int e0i = __builtin_amdgcn_readfirstlane(offs[wv]);
  const int e1i = __builtin_amdgcn_readfirstlane(offs[wv + 1]);
  for (int j = e0i; j < e1i; j += 2) {
    const bool hasB = (j + 1) < e1i;
    const int2 prA = pairs[j];
    const int2 prB = hasB ? pairs[j + 1] : prA;
    float eA[8], eB[8];
    if (EABF) {
      const unsigned short* ebp = (const unsigned short*)eaP;
      const short8 eAu = *(const short8*)(ebp + (size_t)prA.x * 64 + p * 8);
      const short8 eBu = *(const short8*)(ebp + (size_t)prB.x * 64 + p * 8);
#pragma unroll
      for (int i = 0; i < 8; ++i) {
        eA[i] = bf2f((unsigned short)eAu[i]);
        eB[i] = bf2f((unsigned short)eBu[i]);
      }
    } else {
      const float* efp = (const float*)eaP;
      const float4 a0 = *(const float4*)(efp + (size_t)prA.x * 64 + p * 8);
      const float4 a1 = *(const float4*)(efp + (size_t)prA.x * 64 + p * 8 + 4);
      const float4 b0 = *(const float4*)(efp + (size_t)prB.x * 64 + p * 8);
      const float4 b1 = *(const float4*)(efp + (size_t)prB.x * 64 + p * 8 + 4);
      eA[0]=a0.x; eA[1]=a0.y; eA[2]=a0.z; eA[3]=a0.w;
      eA[4]=a1.x; eA[5]=a1.y; eA[6]=a1.z; eA[7]=a1.w;
      eB[0]=b0.x; eB[1]=b0.y; eB[2]=b0.z; eB[3]=b0.w;
      eB[4]=b1.x; eB[5]=b1.y; eB[6]=b1.z; eB[7]=b1.w;
    }
    const unsigned short* kpA = kv + (size_t)prA.y * 512 + lane * 4;
    const unsigned short* kpB = kv + (size_t)prB.y * 512 + lane * 4;
    const ushort4 kAu = *(const ushort4*)kpA;
    const ushort4 vAu = *(const ushort4*)(kpA + 256);
    const ushort4 kBu = *(const ushort4*)kpB;
    const ushort4 vBu = *(const ushort4*)(kpB + 256);
    float pA = qx * bf2f(kAu.x) + qy * bf2f(kAu.y) + qz * bf2f(kAu.z) + qw * bf2f(kAu.w);
    pA += eA[0]*Ta0 + eA[1]*Ta1 + eA[2]*Ta2 + eA[3]*Ta3;
    pA += eA[4]*Tc0 + eA[5]*Tc1 + eA[6]*Tc2 + eA[7]*Tc3;
    float pB = qx * bf2f(kBu.x) + qy * bf2f(kBu.y) + qz * bf2f(kBu.z) + qw * bf2f(kBu.w);
    pB += eB[0]*Ta0 + eB[1]*Ta1 + eB[2]*Ta2 + eB[3]*Ta3;
    pB += eB[4]*Tc0 + eB[5]*Tc1 + eB[6]*Tc2 + eB[7]*Tc3;
    pA += __shfl_xor(pA, 1, 64); pA += __shfl_xor(pA, 2, 64); pA += __shfl_xor(pA, 4, 64);
    pB += __shfl_xor(pB, 1, 64); pB += __shfl_xor(pB, 2, 64); pB += __shfl_xor(pB, 4, 64);
    const float sA = pA * scale;
    const float sB = hasB ? pB * scale : -INFINITY;
    const float mn = fmaxf(m, fmaxf(sA, sB));
    const float corr = __expf(m - mn);   // exp(-inf)=0 on first iteration
    const float wA = __expf(sA - mn);
    const float wB = __expf(sB - mn);
    m = mn;
    den = den * corr + wA + wB;
    ax = ax * corr + wA * bf2f(vAu.x) + wB * bf2f(vBu.x);
    ay = ay * corr + wA * bf2f(vAu.y) + wB * bf2f(vBu.y);
    az = az * corr + wA * bf2f(vAu.z) + wB * bf2f(vBu.z);
    aw = aw * corr + wA * bf2f(vAu.w) + wB * bf2f(vBu.w);
#pragma unroll
    for (int i = 0; i < 8; ++i)
      G[i] = G[i] * corr + wA * eA[i] + wB * eB[i];
  }
  const float inv = 1.f / (den + 1e-9f);
  ushort4 o;
  o.x = f2bf(ax * inv); o.y = f2bf(ay * inv);
  o.z = f2bf(az * inv); o.w = f2bf(aw * inv);
  *(ushort4*)(qTmsg + (size_t)wv * 1536 + lane * 4) = o;
  short8 gn;
#pragma unroll
  for (int i = 0; i < 8; ++i) gn[i] = (short)f2bf(G[i] * inv);
  *(short8*)(qTmsg + (size_t)wv * 1536 + 256 + g * 64 + p * 8) = gn;
}

// ===== residual add + LayerNorm on bf16 carry (L/R via blockIdx.y); add is bf16 =====
__global__ __launch_bounds__(256)
void add_ln2_k(unsigned short* __restrict__ xbL, const unsigned short* __restrict__ addL,
               unsigned short* __restrict__ xbR, const unsigned short* __restrict__ addR, int Nn)
{
  unsigned short* xb = blockIdx.y ? xbR : xbL;
  const unsigned short* add = blockIdx.y ? addR : addL;
  const int wv = (blockIdx.x * blockDim.x + threadIdx.x) >> 6;
  if (wv >= Nn) return;
  const int lane = threadIdx.x & 63;
  ushort4 xu = *(const ushort4*)(xb + (size_t)wv * 256 + lane * 4);
  ushort4 au = *(const ushort4*)(add + (size_t)wv * 256 + lane * 4);
  float4 y;
  y.x = bf2f(xu.x) + bf2f(au.x); y.y = bf2f(xu.y) + bf2f(au.y);
  y.z = bf2f(xu.z) + bf2f(au.z); y.w = bf2f(xu.w) + bf2f(au.w);
  float s = y.x + y.y + y.z + y.w;
#pragma unroll
  for (int msk = 1; msk < 64; msk <<= 1) s += __shfl_xor(s, msk, 64);
  const float mean = s * (1.f / 256.f);
  float4 d;
  d.x = y.x - mean; d.y = y.y - mean; d.z = y.z - mean; d.w = y.w - mean;
  float sq = d.x*d.x + d.y*d.y + d.z*d.z + d.w*d.w;
#pragma unroll
  for (int msk = 1; msk < 64; msk <<= 1) sq += __shfl_xor(sq, msk, 64);
  const float r = rsqrtf(sq * (1.f / 256.f) + 1e-5f);
  ushort4 ob;
  ob.x = f2bf(d.x * r); ob.y = f2bf(d.y * r);
  ob.z = f2bf(d.z * r); ob.w = f2bf(d.w * r);
  *(ushort4*)(xb + (size_t)wv * 256 + lane * 4) = ob;
}

// ===== init: f32 input -> bf16 carry (L/R via blockIdx.y) =====
__global__ void cvt_x2_k(const float* __restrict__ aL, unsigned short* __restrict__ xbL,
                         const float* __restrict__ aR, unsigned short* __restrict__ xbR, int n4)
{
  const float* a = blockIdx.y ? aR : aL;
  unsigned short* xb = blockIdx.y ? xbR : xbL;
  int i = blockIdx.x * 256 + threadIdx.x;
  if (i >= n4) return;
  float4 v = ((const float4*)a)[i];
  ushort4 b;
  b.x = f2bf(v.x); b.y = f2bf(v.y); b.z = f2bf(v.z); b.w = f2bf(v.w);
  ((ushort4*)xb)[i] = b;
}

// ===== ea f32 -> bf16 (set 0 only) =====
__global__ void cvt_ea1_k(const float* __restrict__ src, unsigned short* __restrict__ dst, int n8)
{
  int i = blockIdx.x * 256 + threadIdx.x;
  if (i >= n8) return;
  float4 a = ((const float4*)src)[i * 2];
  float4 b = ((const float4*)src)[i * 2 + 1];
  short8 o;
  o[0] = (short)f2bf(a.x); o[1] = (short)f2bf(a.y);
  o[2] = (short)f2bf(a.z); o[3] = (short)f2bf(a.w);
  o[4] = (short)f2bf(b.x); o[5] = (short)f2bf(b.y);
  o[6] = (short)f2bf(b.z); o[7] = (short)f2bf(b.w);
  *(short8*)(dst + (size_t)i * 8) = o;
}

// ===== CSR kernels =====
__global__ void zero4_k(int* p, int n) {
  int i = blockIdx.x * 256 + threadIdx.x;
  if (i < n) p[i] = 0;
}
__global__ void hist4_k(const int* d0, const int* d1, const int* d2, const int* d3,
                        int E0, int E1, int E2, int E3, int* cnt, int Nn) {
  const int s = blockIdx.y;
  const int* d = (s == 0) ? d0 : (s == 1) ? d1 : (s == 2) ? d2 : d3;
  const int E = (s == 0) ? E0 : (s == 1) ? E1 : (s == 2) ? E2 : E3;
  int e = blockIdx.x * 256 + threadIdx.x;
  if (e < E) atomicAdd(&cnt[s * Nn + d[e]], 1);
}
__global__ __launch_bounds__(256)
void scan4_k(const int* __restrict__ cnt, int* __restrict__ offs, int* __restrict__ cursor, int Nn)
{
  __shared__ int sums[256];
  const int s = blockIdx.x;
  const int t = threadIdx.x;
  const int* c = cnt + (size_t)s * Nn;
  int* o = offs + (size_t)s * (Nn + 1);
  int* cur = cursor + (size_t)s * Nn;
  const int chunk = (Nn + 255) / 256;
  const int base = t * chunk;
  int sl = 0;
  for (int i = 0; i < chunk; ++i) {
    int idx = base + i;
    if (idx < Nn) sl += c[idx];
  }
  sums[t] = sl;
  __syncthreads();
  for (int off = 1; off < 256; off <<= 1) {
    int val = (t >= off) ? sums[t - off] : 0;
    __syncthreads();
    sums[t] += val;
    __syncthreads();
  }
  int run = (t == 0) ? 0 : sums[t - 1];
  for (int i = 0; i < chunk; ++i) {
    int idx = base + i;
    if (idx < Nn) { o[idx] = run; cur[idx] = run; run += c[idx]; }
  }
  if (t == 255) o[Nn] = run;
}
__global__ void scatter4_k(const int* e0p, const int* e1p, const int* e2p, const int* e3p,
                           int E0, int E1, int E2, int E3, int* cursor,
                           int2* p0, int2* p1, int2* p2, int2* p3, int Nn) {
  const int s = blockIdx.y;
  const int* ei = (s == 0) ? e0p : (s == 1) ? e1p : (s == 2) ? e2p : e3p;
  int2* po = (s == 0) ? p0 : (s == 1) ? p1 : (s == 2) ? p2 : p3;
  const int E = (s == 0) ? E0 : (s == 1) ? E1 : (s == 2) ? E2 : E3;
  int e = blockIdx.x * 256 + threadIdx.x;
  if (e < E) {
    int pos = atomicAdd(&cursor[s * Nn + ei[E + e]], 1);
    po[pos] = make_int2(e, ei[e]);
  }
}

// ===== host orchestration =====
extern "C" void kernel_launch(void* const* d_in, const int* in_sizes, int n_in,
                              void* d_out, int out_size, void* d_ws, size_t ws_size,
                              hipStream_t stream)
{
  (void)n_in; (void)ws_size;
  const float* afl = (const float*)d_in[0];
  const float* afr = (const float*)d_in[1];
  const float* eaA[4] = {(const float*)d_in[2], (const float*)d_in[3],
                         (const float*)d_in[4], (const float*)d_in[5]};
  const int* eiA[4] = {(const int*)d_in[6], (const int*)d_in[7],
                       (const int*)d_in[8], (const int*)d_in[9]};
  const float* Wq  = (const float*)d_in[10];
  const float* Wk  = (const float*)d_in[11];
  const float* Wv  = (const float*)d_in[12];
  const float* We  = (const float*)d_in[13];
  const float* Wo  = (const float*)d_in[14];
  const float* fw1 = (const float*)d_in[15];
  const float* fb1 = (const float*)d_in[16];
  const float* fw2 = (const float*)d_in[17];
  const float* fb2 = (const float*)d_in[18];
  const float* hw1 = (const float*)d_in[19];
  const float* hb1 = (const float*)d_in[20];
  const float* hw2 = (const float*)d_in[21];
  const float* hb2 = (const float*)d_in[22];

  const int Nn = in_sizes[0] / 256;
  const int E[4] = {in_sizes[2] / 64, in_sizes[3] / 64, in_sizes[4] / 64, in_sizes[5] / 64};
  const int Mh = out_size / 14;
  const int astart = Nn - Mh;
  float* out = (float*)d_out;

  // workspace ~244 MB: xb 19 + agg(bf16) 19 + qTmsg 113 + kv 38 + weights 12
  //                    + eabf0 38 + csr/pairs 7
  char* wsp = (char*)d_ws;
  auto alloc = [&](size_t bytes) -> void* {
    void* pp = (void*)wsp;
    wsp += (bytes + 255) & ~(size_t)255;
    return pp;
  };
  unsigned short* xlb = (unsigned short*)alloc((size_t)Nn * 256 * 2);
  unsigned short* xrb = (unsigned short*)alloc((size_t)Nn * 256 * 2);
  unsigned short* aggLb = (unsigned short*)alloc((size_t)Nn * 256 * 2);
  unsigned short* aggRb = (unsigned short*)alloc((size_t)Nn * 256 * 2);
  unsigned short* qTmsgA = (unsigned short*)alloc((size_t)Nn * 1536 * 2); // self q/T->msg | cross q/T->msg
  unsigned short* qTmsgB = (unsigned short*)alloc((size_t)Nn * 1536 * 2);
  unsigned short* kvbA = (unsigned short*)alloc((size_t)Nn * 512 * 2);    // also f32 head scratch
  unsigned short* kvbB = (unsigned short*)alloc((size_t)Nn * 512 * 2);
  unsigned short* BTqkvT = (unsigned short*)alloc((size_t)8 * 1280 * 256 * 2);
  unsigned short* BTwoF  = (unsigned short*)alloc((size_t)4 * 256 * 1536 * 2);
  unsigned short* BTf1   = (unsigned short*)alloc((size_t)4 * 512 * 256 * 2);
  unsigned short* BTf2   = (unsigned short*)alloc((size_t)4 * 256 * 512 * 2);
  unsigned short* BTh1   = (unsigned short*)alloc((size_t)256 * 256 * 2);
  unsigned short* eabf0  = (unsigned short*)alloc((size_t)E[0] * 64 * 2);
  int* offs4 = (int*)alloc((size_t)4 * (Nn + 1) * 4);
  int* cnt4  = (int*)alloc((size_t)4 * Nn * 4);
  int* cur4  = (int*)alloc((size_t)4 * Nn * 4);
  int2* pairs[4];
  for (int s = 0; s < 4; ++s) pairs[s] = (int2*)alloc((size_t)E[s] * 8);

  const dim3 B256(256);
  const int wgNodes = (Nn * 64 + 255) / 256;
  int maxE = E[0];
  for (int s = 1; s < 4; ++s) if (E[s] > maxE) maxE = E[s];

  // ---- init xb, ea set0 -> bf16, CSR pair lists ----
  cvt_x2_k<<<dim3((Nn * 64 + 255) / 256, 2), B256, 0, stream>>>(afl, xlb, afr, xrb, Nn * 64);
  cvt_ea1_k<<<dim3((E[0] * 8 + 255) / 256), B256, 0, stream>>>(eaA[0], eabf0, E[0] * 8);
  zero4_k<<<dim3((4 * Nn + 255) / 256), B256, 0, stream>>>(cnt4, 4 * Nn);
  {
    dim3 gh((maxE + 255) / 256, 4);
    hist4_k<<<gh, B256, 0, stream>>>(eiA[0] + E[0], eiA[1] + E[1], eiA[2] + E[2], eiA[3] + E[3],
                                     E[0], E[1], E[2], E[3], cnt4, Nn);
    scan4_k<<<dim3(4), B256, 0, stream>>>(cnt4, offs4, cur4, Nn);
    scatter4_k<<<gh, B256, 0, stream>>>(eiA[0], eiA[1], eiA[2], eiA[3],
                                        E[0], E[1], E[2], E[3], cur4,
                                        pairs[0], pairs[1], pairs[2], pairs[3], Nn);
  }
  // ---- weight conversion ----
  {
    tc_qkv_k<<<dim3(256, 8, 3), B256, 0, stream>>>(Wq, Wk, Wv, BTqkvT);
    wqe_k<<<dim3(512, 8), B256, 0, stream>>>(BTqkvT, We, 327680);
    wo_tc_k<<<dim3(256, 8), B256, 0, stream>>>(Wo, BTwoF);
    wc_k<<<dim3(512, 8), B256, 0, stream>>>(We, Wo, BTwoF);
    tc_k<<<dim3((131072 + 255) / 256, 4), B256, 0, stream>>>(fw1, BTf1, 256, 512, 131072, 131072, 0, 256, 0);
    tc_k<<<dim3((131072 + 255) / 256, 4), B256, 0, stream>>>(fw2, BTf2, 512, 256, 131072, 131072, 0, 512, 0);
    tc_k<<<dim3((65536 + 255) / 256, 1), B256, 0, stream>>>(hw1, BTh1, 256, 256, 0, 0, 0, 256, 0);
  }

  auto mfma2 = [&](const unsigned short* A0, const unsigned short* A1, int lda,
                   const unsigned short* BT0, const unsigned short* BT1,
                   const float* bias0, const float* bias1,
                   float* Cf0, float* Cf1, int Sf, int ldf,
                   unsigned short* Cb10, unsigned short* Cb11, int S2, int ldb1,
                   unsigned short* Cb20, unsigned short* Cb21, int ldb2,
                   int M, int N, int K, bool biasf, bool gelu) {
    dim3 g(M / 128, N / 128, 2);
    if (biasf && gelu)
      gemm_mfma2_k<true, true ><<<g, B256, 0, stream>>>(A0, A1, lda, BT0, BT1, bias0, bias1,
          Cf0, Cf1, Sf, ldf, Cb10, Cb11, S2, ldb1, Cb20, Cb21, ldb2, M, N, K);
    else if (biasf)
      gemm_mfma2_k<true, false><<<g, B256, 0, stream>>>(A0, A1, lda, BT0, BT1, bias0, bias1,
          Cf0, Cf1, Sf, ldf, Cb10, Cb11, S2, ldb1, Cb20, Cb21, ldb2, M, N, K);
    else
      gemm_mfma2_k<false, false><<<g, B256, 0, stream>>>(A0, A1, lda, BT0, BT1, bias0, bias1,
          Cf0, Cf1, Sf, ldf, Cb10, Cb11, S2, ldb1, Cb20, Cb21, ldb2, M, N, K);
  };

  for (int l = 0; l < 2; ++l) {
    const unsigned short* btLL = BTqkvT + (size_t)(l*4+0) * 327680;
    const unsigned short* btRR = BTqkvT + (size_t)(l*4+1) * 327680;
    const unsigned short* btLR = BTqkvT + (size_t)(l*4+2) * 327680;
    const unsigned short* btRL = BTqkvT + (size_t)(l*4+3) * 327680;
    // self QKV+T: cols [0,768)->qTmsg (ld 1536), [768,1280)->kvb
    mfma2(xlb, xrb, 256, btLL, btRR, nullptr, nullptr, nullptr, nullptr, 0, 0,
          qTmsgA, qTmsgB, 768, 1536, kvbA, kvbB, 512, Nn, 1280, 256, false, false);
    // self edges (ll bf16 ea, rr f32 ea)
    edge2_k<true><<<dim3(wgNodes, 1), B256, 0, stream>>>(
        offs4, offs4, pairs[0], pairs[0], eabf0, eabf0, qTmsgA, qTmsgA, kvbA, kvbA, Nn);
    edge2_k<false><<<dim3(wgNodes, 1), B256, 0, stream>>>(
        offs4 + (size_t)(Nn + 1), offs4 + (size_t)(Nn + 1), pairs[1], pairs[1],
        eaA[1], eaA[1], qTmsgB, qTmsgB, kvbB, kvbB, Nn);
    // cross GEMMs fused: z0 rl-q, z1 lr-q (N=768); z2 rl-kv, z3 lr-kv (N=512)
    gemm_mfma4_k<<<dim3(Nn / 128, 6, 4), B256, 0, stream>>>(
        xlb, xrb, xrb, xlb,
        btRL, btLR, btRL + (size_t)768 * 256, btLR + (size_t)768 * 256,
        qTmsgA + 768, qTmsgB + 768, kvbA, kvbB,
        1536, 512, 768, 512, 256, 256, Nn);
    // cross edges (rl -> A, lr -> B), both f32 ea, merged
    edge2_k<false><<<dim3(wgNodes, 2), B256, 0, stream>>>(
        offs4 + (size_t)3 * (Nn + 1), offs4 + (size_t)2 * (Nn + 1), pairs[3], pairs[2],
        eaA[3], eaA[2], qTmsgA + 768, qTmsgB + 768, kvbA, kvbB, Nn);
    // fused Wo: agg = [selfV|selfGn|crossV|crossGn] @ [Wo_s|Wc_s|Wo_c|Wc_c], K=1536
    mfma2(qTmsgA, qTmsgB, 1536, BTwoF + (size_t)(l*2+0)*393216, BTwoF + (size_t)(l*2+1)*393216,
          nullptr, nullptr, nullptr, nullptr, 0, 0, aggLb, aggRb, 256, 256,
          nullptr, nullptr, 0, Nn, 256, 1536, false, false);
    add_ln2_k<<<dim3(wgNodes, 2), B256, 0, stream>>>(xlb, aggLb, xrb, aggRb, Nn);
    // FFN (L/R combined)
    const int fL = l * 2 + 0, fR = l * 2 + 1;
    mfma2(xlb, xrb, 256, BTf1 + (size_t)fL*131072, BTf1 + (size_t)fR*131072,
          fb1 + (size_t)fL*512, fb1 + (size_t)fR*512, nullptr, nullptr, 0, 0,
          nullptr, nullptr, 0, 0, kvbA, kvbB, 512, Nn, 512, 256, true, true);
    mfma2(kvbA, kvbB, 512, BTf2 + (size_t)fL*131072, BTf2 + (size_t)fR*131072,
          fb2 + (size_t)fL*256, fb2 + (size_t)fR*256, nullptr, nullptr, 0, 0,
          aggLb, aggRb, 256, 256, nullptr, nullptr, 0, Nn, 256, 512, true, false);
    add_ln2_k<<<dim3(wgNodes, 2), B256, 0, stream>>>(xlb, aggLb, xrb, aggRb, Nn);
  }
  // heads: gelu(x@hw1+hb1) -> f32 scratch (kvb), then @ hw2 + hb2
  float* h1L = (float*)kvbA;
  float* h1R = (float*)kvbB;
  mfma2(xlb + (size_t)astart * 256, xrb + (size_t)astart * 256, 256, BTh1, BTh1,
        hb1, hb1, h1L, h1R, 256, 256, nullptr, nullptr, 0, 0, nullptr, nullptr, 0,
        Mh, 256, 256, true, true);
  gemm_k2<true><<<dim3(Mh / 128, 1, 2), B256, 0, stream>>>(h1L, h1R, hw2, hb2,
                                                           out, out + (size_t)Mh * 7, Mh, 7, 256);
}

// Round 10
// 1105.596 us; speedup vs baseline: 1.8975x; 1.0512x over previous
//
#include <hip/hip_runtime.h>
#include <math.h>

typedef __attribute__((ext_vector_type(8))) short short8;
typedef __attribute__((ext_vector_type(4))) float f32x4;

__device__ __forceinline__ unsigned short f2bf(float f) {
  unsigned u = __builtin_bit_cast(unsigned, f);
  u += 0x7fff + ((u >> 16) & 1);
  return (unsigned short)(u >> 16);
}
__device__ __forceinline__ float bf2f(unsigned short h) {
  unsigned u = ((unsigned)h) << 16;
  return __builtin_bit_cast(float, u);
}
__device__ __forceinline__ float gelu_f(float x) {
  const float c0 = 0.7978845608028654f;
  return 0.5f * x * (1.0f + tanhf(c0 * (x + 0.044715f * x * x * x)));
}
// async global->LDS, 16B per lane; LDS dest = wave-uniform base + lane*16
__device__ __forceinline__ void gload16(const unsigned short* g, unsigned short* l) {
  __builtin_amdgcn_global_load_lds(
      (const __attribute__((address_space(1))) unsigned int*)g,
      (__attribute__((address_space(3))) unsigned int*)l, 16, 0, 0);
}
// interleave map for kv rows: k elem e -> (e>>2)*8 + (e&3); v elem e -> (e>>2)*8+4+(e&3)
__device__ __forceinline__ int ileave512(int cc) {
  const int base = (cc & 256) ? 4 : 0;
  const int c2 = cc & 255;
  return (c2 >> 2) * 8 + base + (c2 & 3);
}

// ===== mega QKV GEMM: per z-context computes everything derived from one x =====
// N=2560 col split: [0,768) qT self; [768,1280) kvS (interleaved);
// [1280,2048) qT cross; [2048,2560) kvX (interleaved).
__global__ __launch_bounds__(256)
void gemm_qkv_k(const unsigned short* __restrict__ A0, const unsigned short* __restrict__ A1,
                const unsigned short* __restrict__ BT0, const unsigned short* __restrict__ BT1,
                unsigned short* __restrict__ qT0, unsigned short* __restrict__ qT1,
                unsigned short* __restrict__ kvS0, unsigned short* __restrict__ kvS1,
                unsigned short* __restrict__ kvX0, unsigned short* __restrict__ kvX1,
                int M)
{
  const int z = blockIdx.z;
  const unsigned short* A  = z ? A1  : A0;
  const unsigned short* BT = z ? BT1 : BT0;
  unsigned short* qT  = z ? qT1  : qT0;
  unsigned short* kvS = z ? kvS1 : kvS0;
  unsigned short* kvX = z ? kvX1 : kvX0;
  const int K = 256, lda = 256;

  __shared__ __align__(16) unsigned short As[128 * 32];
  __shared__ __align__(16) unsigned short Bs[128 * 32];
  const int tid = threadIdx.x;
  const int bm = blockIdx.x * 128, bn = blockIdx.y * 128;
  const int lane = tid & 63, w = tid >> 6;
  const int wr = w >> 1, wc = w & 1;
  const int l15 = lane & 15, kg = lane >> 4;
  const int srow0 = w * 16 + (lane >> 2);
  const int srow1 = 64 + srow0;
  const int sslot = lane & 3;
  const int koff0 = (((sslot - (srow0 >> 1)) & 3)) * 8;
  const int koff1 = (((sslot - (srow1 >> 1)) & 3)) * 8;
  const unsigned short* gA0 = A + (size_t)(bm + srow0) * lda + koff0;
  const unsigned short* gA1 = A + (size_t)(bm + srow1) * lda + koff1;
  const unsigned short* gB0 = BT + (size_t)(bn + srow0) * K + koff0;
  const unsigned short* gB1 = BT + (size_t)(bn + srow1) * K + koff1;
  unsigned short* lA0 = As + w * 512;
  unsigned short* lA1 = As + 2048 + w * 512;
  unsigned short* lB0 = Bs + w * 512;
  unsigned short* lB1 = Bs + 2048 + w * 512;

  int roffA[4], roffB[4];
#pragma unroll
  for (int m = 0; m < 4; ++m) {
    int row = wr * 64 + m * 16 + l15;
    roffA[m] = row * 32 + ((kg + (row >> 1)) & 3) * 8;
  }
#pragma unroll
  for (int n = 0; n < 4; ++n) {
    int col = wc * 64 + n * 16 + l15;
    roffB[n] = col * 32 + ((kg + (col >> 1)) & 3) * 8;
  }

  f32x4 acc[4][4] = {};
  for (int k0 = 0; k0 < K; k0 += 32) {
    gload16(gA0 + k0, lA0);
    gload16(gA1 + k0, lA1);
    gload16(gB0 + k0, lB0);
    gload16(gB1 + k0, lB1);
    __syncthreads();
    short8 af[4], bfr[4];
#pragma unroll
    for (int m = 0; m < 4; ++m) af[m] = *(const short8*)(As + roffA[m]);
#pragma unroll
    for (int n = 0; n < 4; ++n) bfr[n] = *(const short8*)(Bs + roffB[n]);
#pragma unroll
    for (int m = 0; m < 4; ++m)
#pragma unroll
      for (int n = 0; n < 4; ++n)
        acc[m][n] = __builtin_amdgcn_mfma_f32_16x16x32_bf16(af[m], bfr[n], acc[m][n], 0, 0, 0);
    __syncthreads();
  }
#pragma unroll
  for (int m = 0; m < 4; ++m) {
#pragma unroll
    for (int n = 0; n < 4; ++n) {
      int col = bn + wc * 64 + n * 16 + l15;
      f32x4 v = acc[m][n];
#pragma unroll
      for (int r2 = 0; r2 < 4; ++r2) {
        int row = bm + wr * 64 + m * 16 + kg * 4 + r2;
        unsigned short bv = f2bf(v[r2]);
        if (col < 768) {
          qT[(size_t)row * 1536 + col] = bv;
        } else if (col < 1280) {
          kvS[(size_t)row * 512 + ileave512(col - 768)] = bv;
        } else if (col < 2048) {
          qT[(size_t)row * 1536 + 768 + (col - 1280)] = bv;
        } else {
          kvX[(size_t)row * 512 + ileave512(col - 2048)] = bv;
        }
      }
    }
  }
}

// ===== generic 2-context bf16 MFMA GEMM (blockIdx.z = L/R) =====
// col split: [0,Sf)->f32 Cf, [Sf,S2)->bf16 Cb1, [S2,N)->bf16 Cb2 (plain layouts).
template<bool BIAS, bool GELU>
__global__ __launch_bounds__(256)
void gemm_mfma2_k(const unsigned short* __restrict__ A0, const unsigned short* __restrict__ A1,
                  int lda,
                  const unsigned short* __restrict__ BT0, const unsigned short* __restrict__ BT1,
                  const float* __restrict__ bias0, const float* __restrict__ bias1,
                  float* __restrict__ Cf0, float* __restrict__ Cf1, int Sf, int ldf,
                  unsigned short* __restrict__ Cb10, unsigned short* __restrict__ Cb11,
                  int S2, int ldb1,
                  unsigned short* __restrict__ Cb20, unsigned short* __restrict__ Cb21, int ldb2,
                  int M, int N, int K)
{
  const int z = blockIdx.z;
  const unsigned short* A  = z ? A1  : A0;
  const unsigned short* BT = z ? BT1 : BT0;
  const float* bias        = z ? bias1 : bias0;
  float* Cf                = z ? Cf1 : Cf0;
  unsigned short* Cb1      = z ? Cb11 : Cb10;
  unsigned short* Cb2      = z ? Cb21 : Cb20;

  __shared__ __align__(16) unsigned short As[128 * 32];
  __shared__ __align__(16) unsigned short Bs[128 * 32];
  const int tid = threadIdx.x;
  const int bm = blockIdx.x * 128, bn = blockIdx.y * 128;
  const int lane = tid & 63, w = tid >> 6;
  const int wr = w >> 1, wc = w & 1;
  const int l15 = lane & 15, kg = lane >> 4;
  const int srow0 = w * 16 + (lane >> 2);
  const int srow1 = 64 + srow0;
  const int sslot = lane & 3;
  const int koff0 = (((sslot - (srow0 >> 1)) & 3)) * 8;
  const int koff1 = (((sslot - (srow1 >> 1)) & 3)) * 8;
  const unsigned short* gA0 = A + (size_t)(bm + srow0) * lda + koff0;
  const unsigned short* gA1 = A + (size_t)(bm + srow1) * lda + koff1;
  const unsigned short* gB0 = BT + (size_t)(bn + srow0) * K + koff0;
  const unsigned short* gB1 = BT + (size_t)(bn + srow1) * K + koff1;
  unsigned short* lA0 = As + w * 512;
  unsigned short* lA1 = As + 2048 + w * 512;
  unsigned short* lB0 = Bs + w * 512;
  unsigned short* lB1 = Bs + 2048 + w * 512;

  int roffA[4], roffB[4];
#pragma unroll
  for (int m = 0; m < 4; ++m) {
    int row = wr * 64 + m * 16 + l15;
    roffA[m] = row * 32 + ((kg + (row >> 1)) & 3) * 8;
  }
#pragma unroll
  for (int n = 0; n < 4; ++n) {
    int col = wc * 64 + n * 16 + l15;
    roffB[n] = col * 32 + ((kg + (col >> 1)) & 3) * 8;
  }

  f32x4 acc[4][4] = {};
  for (int k0 = 0; k0 < K; k0 += 32) {
    gload16(gA0 + k0, lA0);
    gload16(gA1 + k0, lA1);
    gload16(gB0 + k0, lB0);
    gload16(gB1 + k0, lB1);
    __syncthreads();
    short8 af[4], bfr[4];
#pragma unroll
    for (int m = 0; m < 4; ++m) af[m] = *(const short8*)(As + roffA[m]);
#pragma unroll
    for (int n = 0; n < 4; ++n) bfr[n] = *(const short8*)(Bs + roffB[n]);
#pragma unroll
    for (int m = 0; m < 4; ++m)
#pragma unroll
      for (int n = 0; n < 4; ++n)
        acc[m][n] = __builtin_amdgcn_mfma_f32_16x16x32_bf16(af[m], bfr[n], acc[m][n], 0, 0, 0);
    __syncthreads();
  }
#pragma unroll
  for (int m = 0; m < 4; ++m) {
#pragma unroll
    for (int n = 0; n < 4; ++n) {
      int col = bn + wc * 64 + n * 16 + l15;
      float bv = BIAS ? bias[col] : 0.f;
      f32x4 v = acc[m][n];
#pragma unroll
      for (int r2 = 0; r2 < 4; ++r2) {
        int row = bm + wr * 64 + m * 16 + kg * 4 + r2;
        float val = v[r2] + bv;
        if (GELU) val = gelu_f(val);
        if (col < Sf) {
          Cf[(size_t)row * ldf + col] = val;
        } else if (col < S2) {
          Cb1[(size_t)row * ldb1 + (col - Sf)] = f2bf(val);
        } else {
          Cb2[(size_t)row * ldb2 + (col - S2)] = f2bf(val);
        }
      }
    }
  }
}

// ===== f32 GEMM, 2-context (tiny N=7 head2) =====
template<bool BIAS>
__global__ __launch_bounds__(256)
void gemm_k2(const float* __restrict__ A0, const float* __restrict__ A1,
             const float* __restrict__ B, const float* __restrict__ bias,
             float* __restrict__ C0, float* __restrict__ C1,
             int M, int N, int K)
{
  const float* A = blockIdx.z ? A1 : A0;
  float* C = blockIdx.z ? C1 : C0;
  __shared__ float As[16][132];
  __shared__ float Bs[16][132];
  const int tid = threadIdx.x;
  const int tx = tid & 15, ty = tid >> 4;
  const int bm = blockIdx.x * 128;
  float acc[8][8];
#pragma unroll
  for (int i = 0; i < 8; ++i)
#pragma unroll
    for (int j = 0; j < 8; ++j) acc[i][j] = 0.f;
  const int ar = tid >> 1;
  const int ac = (tid & 1) * 8;
  const int br = tid >> 4;
  const int bc = (tid & 15) * 8;
  for (int k0 = 0; k0 < K; k0 += 16) {
    {
      float av[8] = {0,0,0,0,0,0,0,0};
      if (bm + ar < M) {
        const float* app = A + (size_t)(bm + ar) * K + (k0 + ac);
        float4 a0 = *(const float4*)app;
        float4 a1 = *(const float4*)(app + 4);
        av[0]=a0.x; av[1]=a0.y; av[2]=a0.z; av[3]=a0.w;
        av[4]=a1.x; av[5]=a1.y; av[6]=a1.z; av[7]=a1.w;
      }
#pragma unroll
      for (int i = 0; i < 8; ++i) As[ac + i][ar] = av[i];
    }
    {
      float bv[8] = {0,0,0,0,0,0,0,0};
      const float* bpp = B + (size_t)(k0 + br) * N + bc;
#pragma unroll
      for (int i = 0; i < 8; ++i) { if (bc + i < N) bv[i] = bpp[i]; }
#pragma unroll
      for (int i = 0; i < 8; ++i) Bs[br][bc + i] = bv[i];
    }
    __syncthreads();
#pragma unroll
    for (int kk = 0; kk < 16; ++kk) {
      float a[8], b[8];
      float4 t0 = *(const float4*)&As[kk][ty * 8];
      float4 t1 = *(const float4*)&As[kk][ty * 8 + 4];
      float4 u0 = *(const float4*)&Bs[kk][tx * 8];
      float4 u1 = *(const float4*)&Bs[kk][tx * 8 + 4];
      a[0]=t0.x;a[1]=t0.y;a[2]=t0.z;a[3]=t0.w;a[4]=t1.x;a[5]=t1.y;a[6]=t1.z;a[7]=t1.w;
      b[0]=u0.x;b[1]=u0.y;b[2]=u0.z;b[3]=u0.w;b[4]=u1.x;b[5]=u1.y;b[6]=u1.z;b[7]=u1.w;
#pragma unroll
      for (int i = 0; i < 8; ++i)
#pragma unroll
        for (int j = 0; j < 8; ++j)
          acc[i][j] = fmaf(a[i], b[j], acc[i][j]);
    }
    __syncthreads();
  }
#pragma unroll
  for (int i = 0; i < 8; ++i) {
    int row = bm + ty * 8 + i;
    if (row >= M) continue;
    int colg = tx * 8;
    float* cp = C + (size_t)row * N + colg;
#pragma unroll
    for (int j = 0; j < 8; ++j) {
      int cc = colg + j;
      if (cc < N) {
        float val = acc[i][j];
        if (BIAS) val += bias[cc];
        cp[j] = val;
      }
    }
  }
}

// ===== generic transpose+convert (FFN / head weights) =====
__global__ void tc_k(const float* __restrict__ in, unsigned short* __restrict__ out,
                     int K, int N, int inStride, int outStride, int rowOff, int totK, int kOff)
{
  const int mat = blockIdx.y;
  const int idx = blockIdx.x * 256 + threadIdx.x;
  if (idx >= N * K) return;
  const int n = idx / K, k = idx - n * K;
  out[(size_t)mat * outStride + (size_t)(rowOff + n) * totK + kOff + k] =
      f2bf(in[(size_t)mat * inStride + (size_t)k * N + n]);
}

// ===== mega-QKV weight pack: 6 parts x 4 slots (l,side) =====
// slot = l*2+z. self = l*4+z; crossq = l*4+(z?2:3); crosskv = l*4+(z?3:2).
__global__ void tc_all_k(const float* __restrict__ Wq, const float* __restrict__ Wk,
                         const float* __restrict__ Wv, unsigned short* __restrict__ BTall)
{
  const int part = blockIdx.z;
  const int slot = blockIdx.y;
  const int l = slot >> 1, zz = slot & 1;
  const int self = l * 4 + zz;
  const int crossq = l * 4 + (zz ? 2 : 3);
  const int crosskv = l * 4 + (zz ? 3 : 2);
  const float* in; int mat, rowOff;
  switch (part) {
    case 0: in = Wq; mat = self;    rowOff = 0;    break;
    case 1: in = Wk; mat = self;    rowOff = 768;  break;
    case 2: in = Wv; mat = self;    rowOff = 1024; break;
    case 3: in = Wq; mat = crossq;  rowOff = 1280; break;
    case 4: in = Wk; mat = crosskv; rowOff = 2048; break;
    default:in = Wv; mat = crosskv; rowOff = 2304; break;
  }
  const int idx = blockIdx.x * 256 + threadIdx.x;
  const int n = idx >> 8, k = idx & 255;
  BTall[(size_t)slot * 655360 + (size_t)(rowOff + n) * 256 + k] =
      f2bf(in[(size_t)mat * 65536 + (size_t)k * 256 + n]);
}

// ===== fused T-weights inside BTall (self rows 256..767; cross rows 1536..2047) =====
__global__ __launch_bounds__(256)
void wqe2_k(unsigned short* __restrict__ BTall, const float* __restrict__ We)
{
  const int which = blockIdx.z;        // 0 self, 1 cross
  const int slot = blockIdx.y;
  const int l = slot >> 1, zz = slot & 1;
  const int mat = which ? (l * 4 + (zz ? 2 : 3)) : (l * 4 + zz);
  const int baseQ = which ? 1280 : 0;
  const int baseT = which ? 1536 : 256;
  const int oc = blockIdx.x;           // 0..511 = head*64 + c
  const int g = oc >> 6, cc = oc & 63;
  const int kin = threadIdx.x;         // 0..255
  const float* wrow = We + (size_t)mat * 16384 + (size_t)cc * 256 + g * 32;
  const unsigned short* bq = BTall + (size_t)slot * 655360 + (size_t)(baseQ + g * 32) * 256 + kin;
  float acc = 0.f;
#pragma unroll 8
  for (int d = 0; d < 32; ++d)
    acc += bf2f(bq[(size_t)d * 256]) * wrow[d];
  BTall[(size_t)slot * 655360 + (size_t)(baseT + oc) * 256 + kin] = f2bf(acc);
}

// ===== fused Wo pack: BTwoF[sl][n][base + k] = Wo[mat][k][n] =====
__global__ void wo_tc_k(const float* __restrict__ Wo, unsigned short* __restrict__ BTwoF)
{
  const int mat = blockIdx.y;          // 0..7 = l*4+i
  const int idx = blockIdx.x * 256 + threadIdx.x;
  const int n = idx >> 8, k = idx & 255;
  const int l = mat >> 2, i = mat & 3;
  const int side = (i == 1 || i == 2) ? 1 : 0;
  const int base = (i >= 2) ? 768 : 0;
  BTwoF[(size_t)(l * 2 + side) * 393216 + (size_t)n * 1536 + base + k] =
      f2bf(Wo[(size_t)mat * 65536 + (size_t)k * 256 + n]);
}

// ===== Wc fold: BTwoF[sl][n][base + 256 + h*64+c] = sum_d We[c,h*32+d]*Wo[h*32+d,n] =====
__global__ __launch_bounds__(256)
void wc_k(const float* __restrict__ We, const float* __restrict__ Wo,
          unsigned short* __restrict__ BTwoF)
{
  const int mat = blockIdx.y;          // 0..7 = l*4+i
  const int j = blockIdx.x;            // 0..511 = h*64+c
  const int h = j >> 6, c = j & 63;
  const int n = threadIdx.x;           // 0..255
  const float* wep = We + (size_t)mat * 16384 + (size_t)c * 256 + h * 32;
  const float* wop = Wo + (size_t)mat * 65536 + (size_t)(h * 32) * 256 + n;
  float acc = 0.f;
#pragma unroll 8
  for (int d = 0; d < 32; ++d)
    acc += wep[d] * wop[(size_t)d * 256];
  const int l = mat >> 2, i = mat & 3;
  const int side = (i == 1 || i == 2) ? 1 : 0;
  const int base = (i >= 2) ? 768 : 0;
  BTwoF[(size_t)(l * 2 + side) * 393216 + (size_t)n * 1536 + base + 256 + j] = f2bf(acc);
}

// ===== per-dst online-softmax edge aggregation, 4 contexts via blockIdx.y =====
// Reads q/T at qbase[wv*1536 .. +768), overwrites same region with attnV(256)+Gn(512).
// kv rows are interleaved: lane loads 16B = {k[4lane..+3], v[4lane..+3]}.
__global__ __launch_bounds__(256)
void edge4_k(const int* __restrict__ o0, const int* __restrict__ o1,
             const int* __restrict__ o2, const int* __restrict__ o3,
             const int2* __restrict__ p0, const int2* __restrict__ p1,
             const int2* __restrict__ p2, const int2* __restrict__ p3,
             const float* __restrict__ e0, const float* __restrict__ e1,
             const float* __restrict__ e2, const float* __restrict__ e3,
             unsigned short* q0, unsigned short* q1,
             unsigned short* q2, unsigned short* q3,
             const unsigned short* __restrict__ k0, const unsigned short* __restrict__ k1,
             const unsigned short* __restrict__ k2, const unsigned short* __restrict__ k3,
             int Nn)
{
  const int y = blockIdx.y;
  const int* offs = (y == 0) ? o0 : (y == 1) ? o1 : (y == 2) ? o2 : o3;
  const int2* pairs = (y == 0) ? p0 : (y == 1) ? p1 : (y == 2) ? p2 : p3;
  const float* ea = (y == 0) ? e0 : (y == 1) ? e1 : (y == 2) ? e2 : e3;
  unsigned short* qTmsg = (y == 0) ? q0 : (y == 1) ? q1 : (y == 2) ? q2 : q3;
  const unsigned short* kv = (y == 0) ? k0 : (y == 1) ? k1 : (y == 2) ? k2 : k3;
  const int wv = (blockIdx.x * blockDim.x + threadIdx.x) >> 6;
  if (wv >= Nn) return;
  const int lane = threadIdx.x & 63;
  const int g = lane >> 3, p = lane & 7;
  const float scale = 0.17677669529663687f;
  const ushort4 qu = *(const ushort4*)(qTmsg + (size_t)wv * 1536 + lane * 4);
  const float qx = bf2f(qu.x), qy = bf2f(qu.y), qz = bf2f(qu.z), qw = bf2f(qu.w);
  const unsigned short* Tp = qTmsg + (size_t)wv * 1536 + 256 + g * 64 + p * 8;
  const ushort4 tu0 = *(const ushort4*)Tp;
  const ushort4 tu1 = *(const ushort4*)(Tp + 4);
  const float Ta0 = bf2f(tu0.x), Ta1 = bf2f(tu0.y), Ta2 = bf2f(tu0.z), Ta3 = bf2f(tu0.w);
  const float Tc0 = bf2f(tu1.x), Tc1 = bf2f(tu1.y), Tc2 = bf2f(tu1.z), Tc3 = bf2f(tu1.w);
  float m = -INFINITY, den = 0.f;
  float ax = 0.f, ay = 0.f, az = 0.f, aw = 0.f;
  float G[8] = {0,0,0,0,0,0,0,0};
  const int e0i = __builtin_amdgcn_readfirstlane(offs[wv]);
  const int e1i = __builtin_amdgcn_readfirstlane(offs[wv + 1]);
  for (int j = e0i; j < e1i; j += 2) {
    const bool hasB = (j + 1) < e1i;
    const int2 prA = pairs[j];
    const int2 prB = hasB ? pairs[j + 1] : prA;
    const float* epA = ea + (size_t)prA.x * 64 + p * 8;
    const float* epB = ea + (size_t)prB.x * 64 + p * 8;
    const float4 a0 = *(const float4*)epA;
    const float4 a1 = *(const float4*)(epA + 4);
    const float4 b0 = *(const float4*)epB;
    const float4 b1 = *(const float4*)(epB + 4);
    const short8 kvA = *(const short8*)(kv + (size_t)prA.y * 512 + lane * 8);
    const short8 kvB = *(const short8*)(kv + (size_t)prB.y * 512 + lane * 8);
    float pA = qx * bf2f((unsigned short)kvA[0]) + qy * bf2f((unsigned short)kvA[1])
             + qz * bf2f((unsigned short)kvA[2]) + qw * bf2f((unsigned short)kvA[3]);
    pA += a0.x*Ta0 + a0.y*Ta1 + a0.z*Ta2 + a0.w*Ta3;
    pA += a1.x*Tc0 + a1.y*Tc1 + a1.z*Tc2 + a1.w*Tc3;
    float pB = qx * bf2f((unsigned short)kvB[0]) + qy * bf2f((unsigned short)kvB[1])
             + qz * bf2f((unsigned short)kvB[2]) + qw * bf2f((unsigned short)kvB[3]);
    pB += b0.x*Ta0 + b0.y*Ta1 + b0.z*Ta2 + b0.w*Ta3;
    pB += b1.x*Tc0 + b1.y*Tc1 + b1.z*Tc2 + b1.w*Tc3;
    pA += __shfl_xor(pA, 1, 64); pA += __shfl_xor(pA, 2, 64); pA += __shfl_xor(pA, 4, 64);
    pB += __shfl_xor(pB, 1, 64); pB += __shfl_xor(pB, 2, 64); pB += __shfl_xor(pB, 4, 64);
    const float sA = pA * scale;
    const float sB = hasB ? pB * scale : -INFINITY;
    const float mn = fmaxf(m, fmaxf(sA, sB));
    const float corr = __expf(m - mn);   // exp(-inf)=0 on first iteration
    const float wA = __expf(sA - mn);
    const float wB = __expf(sB - mn);
    m = mn;
    den = den * corr + wA + wB;
    ax = ax * corr + wA * bf2f((unsigned short)kvA[4]) + wB * bf2f((unsigned short)kvB[4]);
    ay = ay * corr + wA * bf2f((unsigned short)kvA[5]) + wB * bf2f((unsigned short)kvB[5]);
    az = az * corr + wA * bf2f((unsigned short)kvA[6]) + wB * bf2f((unsigned short)kvB[6]);
    aw = aw * corr + wA * bf2f((unsigned short)kvA[7]) + wB * bf2f((unsigned short)kvB[7]);
    G[0] = G[0] * corr + wA * a0.x + wB * b0.x;
    G[1] = G[1] * corr + wA * a0.y + wB * b0.y;
    G[2] = G[2] * corr + wA * a0.z + wB * b0.z;
    G[3] = G[3] * corr + wA * a0.w + wB * b0.w;
    G[4] = G[4] * corr + wA * a1.x + wB * b1.x;
    G[5] = G[5] * corr + wA * a1.y + wB * b1.y;
    G[6] = G[6] * corr + wA * a1.z + wB * b1.z;
    G[7] = G[7] * corr + wA * a1.w + wB * b1.w;
  }
  const float inv = 1.f / (den + 1e-9f);
  ushort4 o;
  o.x = f2bf(ax * inv); o.y = f2bf(ay * inv);
  o.z = f2bf(az * inv); o.w = f2bf(aw * inv);
  *(ushort4*)(qTmsg + (size_t)wv * 1536 + lane * 4) = o;
  short8 gn;
#pragma unroll
  for (int i = 0; i < 8; ++i) gn[i] = (short)f2bf(G[i] * inv);
  *(short8*)(qTmsg + (size_t)wv * 1536 + 256 + g * 64 + p * 8) = gn;
}

// ===== residual add + LayerNorm on bf16 carry (L/R via blockIdx.y); add is bf16 =====
__global__ __launch_bounds__(256)
void add_ln2_k(unsigned short* __restrict__ xbL, const unsigned short* __restrict__ addL,
               unsigned short* __restrict__ xbR, const unsigned short* __restrict__ addR, int Nn)
{
  unsigned short* xb = blockIdx.y ? xbR : xbL;
  const unsigned short* add = blockIdx.y ? addR : addL;
  const int wv = (blockIdx.x * blockDim.x + threadIdx.x) >> 6;
  if (wv >= Nn) return;
  const int lane = threadIdx.x & 63;
  ushort4 xu = *(const ushort4*)(xb + (size_t)wv * 256 + lane * 4);
  ushort4 au = *(const ushort4*)(add + (size_t)wv * 256 + lane * 4);
  float4 y;
  y.x = bf2f(xu.x) + bf2f(au.x); y.y = bf2f(xu.y) + bf2f(au.y);
  y.z = bf2f(xu.z) + bf2f(au.z); y.w = bf2f(xu.w) + bf2f(au.w);
  float s = y.x + y.y + y.z + y.w;
#pragma unroll
  for (int msk = 1; msk < 64; msk <<= 1) s += __shfl_xor(s, msk, 64);
  const float mean = s * (1.f / 256.f);
  float4 d;
  d.x = y.x - mean; d.y = y.y - mean; d.z = y.z - mean; d.w = y.w - mean;
  float sq = d.x*d.x + d.y*d.y + d.z*d.z + d.w*d.w;
#pragma unroll
  for (int msk = 1; msk < 64; msk <<= 1) sq += __shfl_xor(sq, msk, 64);
  const float r = rsqrtf(sq * (1.f / 256.f) + 1e-5f);
  ushort4 ob;
  ob.x = f2bf(d.x * r); ob.y = f2bf(d.y * r);
  ob.z = f2bf(d.z * r); ob.w = f2bf(d.w * r);
  *(ushort4*)(xb + (size_t)wv * 256 + lane * 4) = ob;
}

// ===== init: f32 input -> bf16 carry (L/R via blockIdx.y) =====
__global__ void cvt_x2_k(const float* __restrict__ aL, unsigned short* __restrict__ xbL,
                         const float* __restrict__ aR, unsigned short* __restrict__ xbR, int n4)
{
  const float* a = blockIdx.y ? aR : aL;
  unsigned short* xb = blockIdx.y ? xbR : xbL;
  int i = blockIdx.x * 256 + threadIdx.x;
  if (i >= n4) return;
  float4 v = ((const float4*)a)[i];
  ushort4 b;
  b.x = f2bf(v.x); b.y = f2bf(v.y); b.z = f2bf(v.z); b.w = f2bf(v.w);
  ((ushort4*)xb)[i] = b;
}

// ===== CSR kernels =====
__global__ void zero4_k(int* p, int n) {
  int i = blockIdx.x * 256 + threadIdx.x;
  if (i < n) p[i] = 0;
}
__global__ void hist4_k(const int* d0, const int* d1, const int* d2, const int* d3,
                        int E0, int E1, int E2, int E3, int* cnt, int Nn) {
  const int s = blockIdx.y;
  const int* d = (s == 0) ? d0 : (s == 1) ? d1 : (s == 2) ? d2 : d3;
  const int E = (s == 0) ? E0 : (s == 1) ? E1 : (s == 2) ? E2 : E3;
  int e = blockIdx.x * 256 + threadIdx.x;
  if (e < E) atomicAdd(&cnt[s * Nn + d[e]], 1);
}
__global__ __launch_bounds__(256)
void scan4_k(const int* __restrict__ cnt, int* __restrict__ offs, int* __restrict__ cursor, int Nn)
{
  __shared__ int sums[256];
  const int s = blockIdx.x;
  const int t = threadIdx.x;
  const int* c = cnt + (size_t)s * Nn;
  int* o = offs + (size_t)s * (Nn + 1);
  int* cur = cursor + (size_t)s * Nn;
  const int chunk = (Nn + 255) / 256;
  const int base = t * chunk;
  int sl = 0;
  for (int i = 0; i < chunk; ++i) {
    int idx = base + i;
    if (idx < Nn) sl += c[idx];
  }
  sums[t] = sl;
  __syncthreads();
  for (int off = 1; off < 256; off <<= 1) {
    int val = (t >= off) ? sums[t - off] : 0;
    __syncthreads();
    sums[t] += val;
    __syncthreads();
  }
  int run = (t == 0) ? 0 : sums[t - 1];
  for (int i = 0; i < chunk; ++i) {
    int idx = base + i;
    if (idx < Nn) { o[idx] = run; cur[idx] = run; run += c[idx]; }
  }
  if (t == 255) o[Nn] = run;
}
__global__ void scatter4_k(const int* e0p, const int* e1p, const int* e2p, const int* e3p,
                           int E0, int E1, int E2, int E3, int* cursor,
                           int2* p0, int2* p1, int2* p2, int2* p3, int Nn) {
  const int s = blockIdx.y;
  const int* ei = (s == 0) ? e0p : (s == 1) ? e1p : (s == 2) ? e2p : e3p;
  int2* po = (s == 0) ? p0 : (s == 1) ? p1 : (s == 2) ? p2 : p3;
  const int E = (s == 0) ? E0 : (s == 1) ? E1 : (s == 2) ? E2 : E3;
  int e = blockIdx.x * 256 + threadIdx.x;
  if (e < E) {
    int pos = atomicAdd(&cursor[s * Nn + ei[E + e]], 1);
    po[pos] = make_int2(e, ei[e]);
  }
}

// ===== host orchestration =====
extern "C" void kernel_launch(void* const* d_in, const int* in_sizes, int n_in,
                              void* d_out, int out_size, void* d_ws, size_t ws_size,
                              hipStream_t stream)
{
  (void)n_in; (void)ws_size;
  const float* afl = (const float*)d_in[0];
  const float* afr = (const float*)d_in[1];
  const float* eaA[4] = {(const float*)d_in[2], (const float*)d_in[3],
                         (const float*)d_in[4], (const float*)d_in[5]};
  const int* eiA[4] = {(const int*)d_in[6], (const int*)d_in[7],
                       (const int*)d_in[8], (const int*)d_in[9]};
  const float* Wq  = (const float*)d_in[10];
  const float* Wk  = (const float*)d_in[11];
  const float* Wv  = (const float*)d_in[12];
  const float* We  = (const float*)d_in[13];
  const float* Wo  = (const float*)d_in[14];
  const float* fw1 = (const float*)d_in[15];
  const float* fb1 = (const float*)d_in[16];
  const float* fw2 = (const float*)d_in[17];
  const float* fb2 = (const float*)d_in[18];
  const float* hw1 = (const float*)d_in[19];
  const float* hb1 = (const float*)d_in[20];
  const float* hw2 = (const float*)d_in[21];
  const float* hb2 = (const float*)d_in[22];

  const int Nn = in_sizes[0] / 256;
  const int E[4] = {in_sizes[2] / 64, in_sizes[3] / 64, in_sizes[4] / 64, in_sizes[5] / 64};
  const int Mh = out_size / 14;
  const int astart = Nn - Mh;
  float* out = (float*)d_out;

  // workspace ~244 MB: xb 19 + agg 19 + qTmsg 113 + kv(4) 76 + weights 11 + csr/pairs 7
  char* wsp = (char*)d_ws;
  auto alloc = [&](size_t bytes) -> void* {
    void* pp = (void*)wsp;
    wsp += (bytes + 255) & ~(size_t)255;
    return pp;
  };
  unsigned short* xlb = (unsigned short*)alloc((size_t)Nn * 256 * 2);
  unsigned short* xrb = (unsigned short*)alloc((size_t)Nn * 256 * 2);
  unsigned short* aggLb = (unsigned short*)alloc((size_t)Nn * 256 * 2);
  unsigned short* aggRb = (unsigned short*)alloc((size_t)Nn * 256 * 2);
  unsigned short* qTmsgA = (unsigned short*)alloc((size_t)Nn * 1536 * 2);
  unsigned short* qTmsgB = (unsigned short*)alloc((size_t)Nn * 1536 * 2);
  unsigned short* kvSA = (unsigned short*)alloc((size_t)Nn * 512 * 2);  // ll kv; FFN hidden; head f32 scratch
  unsigned short* kvSB = (unsigned short*)alloc((size_t)Nn * 512 * 2);
  unsigned short* kvXL = (unsigned short*)alloc((size_t)Nn * 512 * 2);  // lr kv (from xl)
  unsigned short* kvXR = (unsigned short*)alloc((size_t)Nn * 512 * 2);  // rl kv (from xr)
  unsigned short* BTall = (unsigned short*)alloc((size_t)4 * 655360 * 2);
  unsigned short* BTwoF = (unsigned short*)alloc((size_t)4 * 256 * 1536 * 2);
  unsigned short* BTf1  = (unsigned short*)alloc((size_t)4 * 512 * 256 * 2);
  unsigned short* BTf2  = (unsigned short*)alloc((size_t)4 * 256 * 512 * 2);
  unsigned short* BTh1  = (unsigned short*)alloc((size_t)256 * 256 * 2);
  int* offs4 = (int*)alloc((size_t)4 * (Nn + 1) * 4);
  int* cnt4  = (int*)alloc((size_t)4 * Nn * 4);
  int* cur4  = (int*)alloc((size_t)4 * Nn * 4);
  int2* pairs[4];
  for (int s = 0; s < 4; ++s) pairs[s] = (int2*)alloc((size_t)E[s] * 8);

  const dim3 B256(256);
  const int wgNodes = (Nn * 64 + 255) / 256;
  int maxE = E[0];
  for (int s = 1; s < 4; ++s) if (E[s] > maxE) maxE = E[s];

  // ---- init xb, CSR pair lists ----
  cvt_x2_k<<<dim3((Nn * 64 + 255) / 256, 2), B256, 0, stream>>>(afl, xlb, afr, xrb, Nn * 64);
  zero4_k<<<dim3((4 * Nn + 255) / 256), B256, 0, stream>>>(cnt4, 4 * Nn);
  {
    dim3 gh((maxE + 255) / 256, 4);
    hist4_k<<<gh, B256, 0, stream>>>(eiA[0] + E[0], eiA[1] + E[1], eiA[2] + E[2], eiA[3] + E[3],
                                     E[0], E[1], E[2], E[3], cnt4, Nn);
    scan4_k<<<dim3(4), B256, 0, stream>>>(cnt4, offs4, cur4, Nn);
    scatter4_k<<<gh, B256, 0, stream>>>(eiA[0], eiA[1], eiA[2], eiA[3],
                                        E[0], E[1], E[2], E[3], cur4,
                                        pairs[0], pairs[1], pairs[2], pairs[3], Nn);
  }
  // ---- weight conversion ----
  {
    tc_all_k<<<dim3(256, 4, 6), B256, 0, stream>>>(Wq, Wk, Wv, BTall);
    wqe2_k<<<dim3(512, 4, 2), B256, 0, stream>>>(BTall, We);
    wo_tc_k<<<dim3(256, 8), B256, 0, stream>>>(Wo, BTwoF);
    wc_k<<<dim3(512, 8), B256, 0, stream>>>(We, Wo, BTwoF);
    tc_k<<<dim3((131072 + 255) / 256, 4), B256, 0, stream>>>(fw1, BTf1, 256, 512, 131072, 131072, 0, 256, 0);
    tc_k<<<dim3((131072 + 255) / 256, 4), B256, 0, stream>>>(fw2, BTf2, 512, 256, 131072, 131072, 0, 512, 0);
    tc_k<<<dim3((65536 + 255) / 256, 1), B256, 0, stream>>>(hw1, BTh1, 256, 256, 0, 0, 0, 256, 0);
  }

  auto mfma2 = [&](const unsigned short* A0, const unsigned short* A1, int lda,
                   const unsigned short* BT0, const unsigned short* BT1,
                   const float* bias0, const float* bias1,
                   float* Cf0, float* Cf1, int Sf, int ldf,
                   unsigned short* Cb10, unsigned short* Cb11, int S2, int ldb1,
                   unsigned short* Cb20, unsigned short* Cb21, int ldb2,
                   int M, int N, int K, bool biasf, bool gelu) {
    dim3 g(M / 128, N / 128, 2);
    if (biasf && gelu)
      gemm_mfma2_k<true, true ><<<g, B256, 0, stream>>>(A0, A1, lda, BT0, BT1, bias0, bias1,
          Cf0, Cf1, Sf, ldf, Cb10, Cb11, S2, ldb1, Cb20, Cb21, ldb2, M, N, K);
    else if (biasf)
      gemm_mfma2_k<true, false><<<g, B256, 0, stream>>>(A0, A1, lda, BT0, BT1, bias0, bias1,
          Cf0, Cf1, Sf, ldf, Cb10, Cb11, S2, ldb1, Cb20, Cb21, ldb2, M, N, K);
    else
      gemm_mfma2_k<false, false><<<g, B256, 0, stream>>>(A0, A1, lda, BT0, BT1, bias0, bias1,
          Cf0, Cf1, Sf, ldf, Cb10, Cb11, S2, ldb1, Cb20, Cb21, ldb2, M, N, K);
  };

  for (int l = 0; l < 2; ++l) {
    // 1) mega QKV: everything derived from xl (z0) and xr (z1)
    gemm_qkv_k<<<dim3(Nn / 128, 20, 2), B256, 0, stream>>>(
        xlb, xrb,
        BTall + (size_t)(l * 2 + 0) * 655360, BTall + (size_t)(l * 2 + 1) * 655360,
        qTmsgA, qTmsgB, kvSA, kvSB, kvXL, kvXR, Nn);
    // 2) all four edge aggregations in one dispatch
    edge4_k<<<dim3(wgNodes, 4), B256, 0, stream>>>(
        offs4, offs4 + (size_t)(Nn + 1), offs4 + (size_t)3 * (Nn + 1), offs4 + (size_t)2 * (Nn + 1),
        pairs[0], pairs[1], pairs[3], pairs[2],
        eaA[0], eaA[1], eaA[3], eaA[2],
        qTmsgA, qTmsgB, qTmsgA + 768, qTmsgB + 768,
        kvSA, kvSB, kvXR, kvXL, Nn);
    // 3) fused Wo: agg = [selfV|selfGn|crossV|crossGn] @ [Wo_s|Wc_s|Wo_c|Wc_c], K=1536
    mfma2(qTmsgA, qTmsgB, 1536, BTwoF + (size_t)(l*2+0)*393216, BTwoF + (size_t)(l*2+1)*393216,
          nullptr, nullptr, nullptr, nullptr, 0, 0, aggLb, aggRb, 256, 256,
          nullptr, nullptr, 0, Nn, 256, 1536, false, false);
    add_ln2_k<<<dim3(wgNodes, 2), B256, 0, stream>>>(xlb, aggLb, xrb, aggRb, Nn);
    // 4) FFN (L/R combined); kvS buffers reused as hidden (plain layout)
    const int fL = l * 2 + 0, fR = l * 2 + 1;
    mfma2(xlb, xrb, 256, BTf1 + (size_t)fL*131072, BTf1 + (size_t)fR*131072,
          fb1 + (size_t)fL*512, fb1 + (size_t)fR*512, nullptr, nullptr, 0, 0,
          kvSA, kvSB, 512, 512, nullptr, nullptr, 0, Nn, 512, 256, true, true);
    mfma2(kvSA, kvSB, 512, BTf2 + (size_t)fL*131072, BTf2 + (size_t)fR*131072,
          fb2 + (size_t)fL*256, fb2 + (size_t)fR*256, nullptr, nullptr, 0, 0,
          aggLb, aggRb, 256, 256, nullptr, nullptr, 0, Nn, 256, 512, true, false);
    add_ln2_k<<<dim3(wgNodes, 2), B256, 0, stream>>>(xlb, aggLb, xrb, aggRb, Nn);
  }
  // heads: gelu(x@hw1+hb1) -> f32 scratch (kvS), then @ hw2 + hb2
  float* h1L = (float*)kvSA;
  float* h1R = (float*)kvSB;
  mfma2(xlb + (size_t)astart * 256, xrb + (size_t)astart * 256, 256, BTh1, BTh1,
        hb1, hb1, h1L, h1R, 256, 256, nullptr, nullptr, 0, 0, nullptr, nullptr, 0,
        Mh, 256, 256, true, true);
  gemm_k2<true><<<dim3(Mh / 128, 1, 2), B256, 0, stream>>>(h1L, h1R, hw2, hb2,
                                                           out, out + (size_t)Mh * 7, Mh, 7, 256);
}